// Round 1
// baseline (3816.653 us; speedup 1.0000x reference)
//
#include <hip/hip_runtime.h>

#define B_ 2
#define N_ 256
#define C_ 128
#define H_ 8
// positions = B*N*N = 131072

// ---------------- K0: mask dtype detection ----------------
// Reads only the first 131072 bytes of the mask buffer (safe for both uint8
// and int32 layouts). ~10% of elements are true. If bytes are the elements
// (uint8 bool), nonzero-byte fraction ~10%; if int32 0/1, ~2.5%.
__global__ void k_maskdetect(const unsigned char* __restrict__ m, int* __restrict__ flag)
{
  __shared__ int red[256];
  int tid = threadIdx.x;
  int cnt = 0;
  for (int idx = tid; idx < 131072; idx += 256) cnt += (m[idx] != 0) ? 1 : 0;
  red[tid] = cnt;
  __syncthreads();
  for (int s = 128; s > 0; s >>= 1) {
    if (tid < s) red[tid] += red[tid + s];
    __syncthreads();
  }
  if (tid == 0) *flag = (red[0] > 7864) ? 1 : 0;  // 1 = uint8 layout, 0 = int32
}

// ---------------- K1: fused projections (a1,a2,v1,v2) ----------------
__global__ __launch_bounds__(256) void k_proj(
    const float* __restrict__ h,
    const float* __restrict__ wa1, const float* __restrict__ wa2,
    const float* __restrict__ wv1, const float* __restrict__ wv2,
    float* __restrict__ a1, float* __restrict__ a2,
    float* __restrict__ v1, float* __restrict__ v2)
{
  __shared__ float hs[16*128];
  const int blk = blockIdx.x;
  const int tid = threadIdx.x;
  const int pos0 = blk * 16;
  {
    float4* hs4 = (float4*)hs;
    const float4* hg4 = (const float4*)(h + (size_t)pos0 * 128);
    hs4[tid*2+0] = hg4[tid*2+0];
    hs4[tid*2+1] = hg4[tid*2+1];
  }
  __syncthreads();

  const int o = tid;                      // 0..255: 0..127 -> v1 row, 128..255 -> v2 row
  const float* wrow = (o < 128) ? (wv1 + o*128) : (wv2 + (o-128)*128);
  float* dst = (o < 128) ? v1 : v2;
  const int oc = o & 127;
  const float4* wr4 = (const float4*)wrow;

  float acc[16];
  #pragma unroll
  for (int p = 0; p < 16; ++p) acc[p] = 0.f;

  #pragma unroll 4
  for (int c4 = 0; c4 < 32; ++c4) {
    float4 w4 = wr4[c4];
    #pragma unroll
    for (int p = 0; p < 16; ++p) {
      float4 x4 = ((const float4*)(hs + p*128))[c4];
      acc[p] += x4.x*w4.x + x4.y*w4.y + x4.z*w4.z + x4.w*w4.w;
    }
  }
  #pragma unroll
  for (int p = 0; p < 16; ++p)
    dst[(size_t)(pos0 + p)*128 + oc] = acc[p];

  // a1/a2: 16 output channels total, threads 0..15
  if (tid < 16) {
    const float* ar = (tid < 8) ? (wa1 + tid*128) : (wa2 + (tid-8)*128);
    float* ad = (tid < 8) ? a1 : a2;
    const int hh = tid & 7;
    const float4* ar4 = (const float4*)ar;
    for (int p = 0; p < 16; ++p) {
      float s = 0.f;
      for (int c4 = 0; c4 < 32; ++c4) {
        float4 w4 = ar4[c4];
        float4 x4 = ((const float4*)(hs + p*128))[c4];
        s += x4.x*w4.x + x4.y*w4.y + x4.z*w4.z + x4.w*w4.w;
      }
      ad[(size_t)(pos0 + p)*8 + hh] = s;
    }
  }
}

// ---------------- K2a: amax1[b,i,h] = max_j a1[b,i,j,h] ----------------
__global__ __launch_bounds__(64) void k_rowmax1(const float* __restrict__ a1,
                                                float* __restrict__ amax1)
{
  const int bi = blockIdx.x;            // b*N + i
  const int t = threadIdx.x;            // t = jgrp*8 + h
  const float* base = a1 + (size_t)bi * N_ * 8;
  float m = -1e30f;
  #pragma unroll 8
  for (int k = 0; k < 32; ++k) m = fmaxf(m, base[t + 64*k]);
  m = fmaxf(m, __shfl_xor(m, 8));
  m = fmaxf(m, __shfl_xor(m, 16));
  m = fmaxf(m, __shfl_xor(m, 32));
  if (t < 8) amax1[bi*8 + t] = m;
}

// ---------------- K2b: amax2[b,j,h] = max_i a2[b,i,j,h] ----------------
__global__ __launch_bounds__(64) void k_rowmax2(const float* __restrict__ a2,
                                                float* __restrict__ amax2)
{
  const int bj = blockIdx.x;            // b*N + j
  const int b = bj >> 8, j = bj & 255;
  const int t = threadIdx.x;
  const int hh = t & 7, igrp = t >> 3;
  float m = -1e30f;
  for (int k = 0; k < 32; ++k) {
    int i = igrp + 8*k;
    m = fmaxf(m, a2[((size_t)(b*N_ + i)*N_ + j)*8 + hh]);
  }
  m = fmaxf(m, __shfl_xor(m, 8));
  m = fmaxf(m, __shfl_xor(m, 16));
  m = fmaxf(m, __shfl_xor(m, 32));
  if (t < 8) amax2[bj*8 + t] = m;
}

// ---------------- K3: masked exp + scale v by e (in place) ----------------
__global__ __launch_bounds__(128) void k_expscale(
    const void* __restrict__ maskraw, const int* __restrict__ modep,
    float* __restrict__ e1, float* __restrict__ e2,
    const float* __restrict__ amax1, const float* __restrict__ amax2,
    float* __restrict__ v1, float* __restrict__ v2)
{
  const int pos = blockIdx.x;
  const int c = threadIdx.x;
  const int b = pos >> 16, ij = pos & 65535;
  const int i = ij >> 8, j = ij & 255;
  const int hh = c >> 4;

  const int mode = modep[0];
  int msk;
  if (mode) msk = ((const unsigned char*)maskraw)[pos];
  else      msk = ((const int*)maskraw)[pos];

  float x1 = e1[pos*8 + hh];
  float x2 = e2[pos*8 + hh];
  float m1 = amax1[(b*N_ + i)*8 + hh];
  float m2 = amax2[(b*N_ + j)*8 + hh];
  float ev1 = msk ? 0.f : __expf(x1 - m1);
  float ev2 = msk ? 0.f : __expf(x2 - m2);
  v1[(size_t)pos*128 + c] *= ev1;
  v2[(size_t)pos*128 + c] *= ev2;
  __syncthreads();   // all raw a reads done before in-place e writes
  if (c < 8) {
    float xa = e1[pos*8 + c], xb = e2[pos*8 + c];
    float ma = amax1[(b*N_ + i)*8 + c], mb = amax2[(b*N_ + j)*8 + c];
    e1[pos*8 + c] = msk ? 0.f : __expf(xa - ma);
    e2[pos*8 + c] = msk ? 0.f : __expf(xb - mb);
  }
}

// ---------------- K4: triangle contraction ----------------
// out[b,i,j,c] = sum_l p1[b,i,l,c] * p2[b,l,j,c]
__global__ __launch_bounds__(256, 2) void k_tri(
    const float* __restrict__ p1, const float* __restrict__ p2,
    float* __restrict__ out)
{
  const int jt = blockIdx.x, it = blockIdx.y, b = blockIdx.z;
  const int tid = threadIdx.x;
  const int c = tid & 127;
  const int half = tid >> 7;
  const int i0 = it*16 + half*8;
  const int j0 = jt*16;

  const float* p1b = p1 + ((size_t)(b*N_ + i0)*N_)*128 + c;
  const float* p2b = p2 + ((size_t)b*N_*N_ + j0)*128 + c;

  float acc[8][16];
  #pragma unroll
  for (int ii = 0; ii < 8; ++ii)
    #pragma unroll
    for (int jj = 0; jj < 16; ++jj) acc[ii][jj] = 0.f;

  #pragma unroll 2
  for (int l = 0; l < N_; ++l) {
    float va[8], vb[16];
    #pragma unroll
    for (int ii = 0; ii < 8; ++ii) va[ii] = p1b[((size_t)ii*N_ + l)*128];
    #pragma unroll
    for (int jj = 0; jj < 16; ++jj) vb[jj] = p2b[((size_t)l*N_ + jj)*128];
    #pragma unroll
    for (int ii = 0; ii < 8; ++ii)
      #pragma unroll
      for (int jj = 0; jj < 16; ++jj)
        acc[ii][jj] += va[ii]*vb[jj];
  }

  #pragma unroll
  for (int ii = 0; ii < 8; ++ii)
    #pragma unroll
    for (int jj = 0; jj < 16; ++jj)
      out[((size_t)(b*N_ + i0 + ii)*N_ + (j0 + jj))*128 + c] = acc[ii][jj];
}

// ---------------- K4b: denom[b,i,j,h] = sum_l e1[b,i,l,h]*e2[b,l,j,h] ----------------
__global__ __launch_bounds__(256) void k_denom(
    const float* __restrict__ e1, const float* __restrict__ e2,
    float* __restrict__ denom)
{
  const int jt = blockIdx.x;   // 8 tiles of 32 j
  const int it = blockIdx.y;   // 16 tiles of 16 i
  const int b = blockIdx.z;
  const int tid = threadIdx.x;
  const int hh = tid & 7;
  const int jl = tid >> 3;     // 0..31
  const int i0 = it*16, j0 = jt*32;

  float acc[16];
  #pragma unroll
  for (int ii = 0; ii < 16; ++ii) acc[ii] = 0.f;

  const float* e1b = e1 + ((size_t)(b*N_ + i0)*N_)*8 + hh;
  for (int l = 0; l < N_; ++l) {
    float b2 = e2[((size_t)(b*N_ + l)*N_ + j0 + jl)*8 + hh];
    #pragma unroll
    for (int ii = 0; ii < 16; ++ii) {
      float a1v = e1b[((size_t)ii*N_ + l)*8];
      acc[ii] += a1v * b2;
    }
  }
  #pragma unroll
  for (int ii = 0; ii < 16; ++ii)
    denom[((size_t)(b*N_ + i0 + ii)*N_ + j0 + jl)*8 + hh] = acc[ii];
}

// ---------------- K5: x = t/denom ; y = x@wo^T ; hn = LN1(h + y) ----------------
__global__ __launch_bounds__(256) void k_wo_ln(
    const float* __restrict__ t, const float* __restrict__ denom,
    const float* __restrict__ h, const float* __restrict__ wo,
    const float* __restrict__ g1, const float* __restrict__ bb1,
    float* __restrict__ hn)
{
  __shared__ float xs[16*128];
  __shared__ float part[4][8][2];
  const int blk = blockIdx.x, tid = threadIdx.x;
  const size_t pbase = (size_t)blk * 16;

  {
    int flat = tid * 8;
    #pragma unroll
    for (int k = 0; k < 8; ++k) {
      int f = flat + k;
      int pp = f >> 7, cc = f & 127;
      float dv = denom[(pbase + pp)*8 + (cc >> 4)];
      xs[f] = t[pbase*128 + f] / (dv + 1e-6f);
    }
  }
  __syncthreads();

  const int o = tid & 127, pg = tid >> 7, wave = tid >> 6, lane = tid & 63;
  const float4* wr4 = (const float4*)(wo + o*128);
  float r[8];
  #pragma unroll
  for (int p = 0; p < 8; ++p) {
    int pp = pg*8 + p;
    float s = 0.f;
    #pragma unroll 4
    for (int c4 = 0; c4 < 32; ++c4) {
      float4 w4 = wr4[c4];
      float4 x4 = ((const float4*)(xs + pp*128))[c4];
      s += x4.x*w4.x + x4.y*w4.y + x4.z*w4.z + x4.w*w4.w;
    }
    r[p] = h[(pbase + pp)*128 + o] + s;
  }

  #pragma unroll
  for (int p = 0; p < 8; ++p) {
    float a = r[p], sq = a*a;
    for (int m = 1; m < 64; m <<= 1) { a += __shfl_xor(a, m); sq += __shfl_xor(sq, m); }
    if (lane == 0) { part[wave][p][0] = a; part[wave][p][1] = sq; }
  }
  __syncthreads();
  #pragma unroll
  for (int p = 0; p < 8; ++p) {
    int pp = pg*8 + p;
    float s  = part[pg*2][p][0] + part[pg*2+1][p][0];
    float sq = part[pg*2][p][1] + part[pg*2+1][p][1];
    float mu = s * (1.f/128.f);
    float var = sq * (1.f/128.f) - mu*mu;
    float rstd = rsqrtf(var + 1e-5f);
    hn[(pbase + pp)*128 + o] = (r[p] - mu)*rstd*g1[o] + bb1[o];
  }
}

// ---------------- K6: FFN(silu) + residual + LN2 -> out ----------------
__global__ __launch_bounds__(256) void k_ffn_ln(
    const float* __restrict__ hn,
    const float* __restrict__ w1, const float* __restrict__ bias1,
    const float* __restrict__ w2, const float* __restrict__ bias2,
    const float* __restrict__ g2, const float* __restrict__ b2v,
    float* __restrict__ out)
{
  __shared__ float hs[16*128];
  __shared__ float us[16*128];
  __shared__ float part[4][8][2];
  const int blk = blockIdx.x, tid = threadIdx.x;
  const size_t pbase = (size_t)blk * 16;

  {
    float4* hs4 = (float4*)hs;
    const float4* hg4 = (const float4*)(hn + pbase*128);
    hs4[tid*2+0] = hg4[tid*2+0];
    hs4[tid*2+1] = hg4[tid*2+1];
  }
  __syncthreads();

  const int o = tid & 127, pg = tid >> 7, wave = tid >> 6, lane = tid & 63;
  const float4* w1r = (const float4*)(w1 + o*128);
  const float bi1 = bias1[o];
  #pragma unroll
  for (int p = 0; p < 8; ++p) {
    int pp = pg*8 + p;
    float s = bi1;
    #pragma unroll 4
    for (int c4 = 0; c4 < 32; ++c4) {
      float4 w4 = w1r[c4];
      float4 x4 = ((const float4*)(hs + pp*128))[c4];
      s += x4.x*w4.x + x4.y*w4.y + x4.z*w4.z + x4.w*w4.w;
    }
    us[pp*128 + o] = s / (1.f + __expf(-s));  // silu
  }
  __syncthreads();

  const float4* w2r = (const float4*)(w2 + o*128);
  const float bi2 = bias2[o];
  float r[8];
  #pragma unroll
  for (int p = 0; p < 8; ++p) {
    int pp = pg*8 + p;
    float s = bi2;
    #pragma unroll 4
    for (int c4 = 0; c4 < 32; ++c4) {
      float4 w4 = w2r[c4];
      float4 x4 = ((const float4*)(us + pp*128))[c4];
      s += x4.x*w4.x + x4.y*w4.y + x4.z*w4.z + x4.w*w4.w;
    }
    r[p] = hs[pp*128 + o] + s;
  }

  #pragma unroll
  for (int p = 0; p < 8; ++p) {
    float a = r[p], sq = a*a;
    for (int m = 1; m < 64; m <<= 1) { a += __shfl_xor(a, m); sq += __shfl_xor(sq, m); }
    if (lane == 0) { part[wave][p][0] = a; part[wave][p][1] = sq; }
  }
  __syncthreads();
  #pragma unroll
  for (int p = 0; p < 8; ++p) {
    int pp = pg*8 + p;
    float s  = part[pg*2][p][0] + part[pg*2+1][p][0];
    float sq = part[pg*2][p][1] + part[pg*2+1][p][1];
    float mu = s * (1.f/128.f);
    float var = sq * (1.f/128.f) - mu*mu;
    float rstd = rsqrtf(var + 1e-5f);
    out[(pbase + pp)*128 + o] = (r[p] - mu)*rstd*g2[o] + b2v[o];
  }
}

extern "C" void kernel_launch(void* const* d_in, const int* in_sizes, int n_in,
                              void* d_out, int out_size, void* d_ws, size_t ws_size,
                              hipStream_t stream)
{
  const float* h    = (const float*)d_in[0];
  const void*  mask = d_in[1];
  const float* wa1  = (const float*)d_in[2];
  const float* wa2  = (const float*)d_in[3];
  const float* wv1  = (const float*)d_in[4];
  const float* wv2  = (const float*)d_in[5];
  const float* wo   = (const float*)d_in[6];
  const float* ln1s = (const float*)d_in[7];
  const float* ln1b = (const float*)d_in[8];
  const float* ln2s = (const float*)d_in[9];
  const float* ln2b = (const float*)d_in[10];
  const float* wu1  = (const float*)d_in[11];
  const float* bu1  = (const float*)d_in[12];
  const float* wu2  = (const float*)d_in[13];
  const float* bu2  = (const float*)d_in[14];

  char* ws = (char*)d_ws;
  const size_t MB = 1024*1024;
  float* e1  = (float*)(ws + 0*MB);          // [B,N,N,8] raw a1 then exp
  float* e2  = (float*)(ws + 4*MB);          // [B,N,N,8]
  float* p1  = (float*)(ws + 8*MB);          // [B,N,N,128] v1 then v1*e1
  float* p2  = (float*)(ws + 72*MB);         // [B,N,N,128]
  float* dn  = (float*)(ws + 136*MB);        // [B,N,N,8]
  float* am1 = (float*)(ws + 140*MB);        // [B,N,8]
  float* am2 = (float*)(ws + 140*MB + 16384);
  int*   flg = (int*)  (ws + 140*MB + 32768);
  float* tbuf = (float*)d_out;               // scratch: triangle output pre-wo
  float* hn = p1;                            // alias: p1 dead after k_tri

  k_maskdetect<<<1, 256, 0, stream>>>((const unsigned char*)mask, flg);
  k_proj<<<8192, 256, 0, stream>>>(h, wa1, wa2, wv1, wv2, e1, e2, p1, p2);
  k_rowmax1<<<512, 64, 0, stream>>>(e1, am1);
  k_rowmax2<<<512, 64, 0, stream>>>(e2, am2);
  k_expscale<<<131072, 128, 0, stream>>>(mask, flg, e1, e2, am1, am2, p1, p2);
  k_tri<<<dim3(16,16,2), 256, 0, stream>>>(p1, p2, tbuf);
  k_denom<<<dim3(8,16,2), 256, 0, stream>>>(e1, e2, dn);
  k_wo_ln<<<8192, 256, 0, stream>>>(tbuf, dn, h, wo, ln1s, ln1b, hn);
  k_ffn_ln<<<8192, 256, 0, stream>>>(hn, wu1, bu1, wu2, bu2, ln2s, ln2b, (float*)d_out);
}

// Round 2
// 580.928 us; speedup vs baseline: 6.5699x; 6.5699x over previous
//
#include <hip/hip_runtime.h>

#define B_ 2
#define N_ 256
#define C_ 128
#define H_ 8

typedef __attribute__((ext_vector_type(8))) short bf16x8;
typedef __attribute__((ext_vector_type(4))) float f32x4;

__device__ __forceinline__ unsigned short f2bf(float f) {
  unsigned int u = __float_as_uint(f);
  unsigned int r = (u + 0x7FFFu + ((u >> 16) & 1u)) >> 16;
  return (unsigned short)r;
}

// B-fragment (16 rows x 32 k) from row-major f32 weight matrix [R][128]:
// lane l -> row = row0 + (l&15), k = k0 + 8*(l>>4) + j (j=0..7 contiguous)
__device__ __forceinline__ bf16x8 load_wfrag(const float* __restrict__ W,
                                             int row0, int k0, int lane) {
  const float* p = W + (size_t)(row0 + (lane & 15)) * 128 + k0 + 8 * (lane >> 4);
  float4 x = *(const float4*)p;
  float4 y = *(const float4*)(p + 4);
  bf16x8 f;
  f[0] = (short)f2bf(x.x); f[1] = (short)f2bf(x.y);
  f[2] = (short)f2bf(x.z); f[3] = (short)f2bf(x.w);
  f[4] = (short)f2bf(y.x); f[5] = (short)f2bf(y.y);
  f[6] = (short)f2bf(y.z); f[7] = (short)f2bf(y.w);
  return f;
}

// A-fragment from XOR-swizzled bf16 LDS tile [32 rows][128 cols] (256 B/row).
// swizzle: 16B-granule index ^= (row & 7)
__device__ __forceinline__ bf16x8 lds_afrag(const char* base, int row0, int k0, int lane) {
  int row = row0 + (lane & 15);
  int cb = (k0 + 8 * (lane >> 4)) * 2;                 // byte col, 16B aligned
  int byte = row * 256 + ((((cb >> 4) ^ (row & 7))) << 4);
  return *(const bf16x8*)(base + byte);
}

// swizzled 8-byte (4 bf16) store into the bf16 tile
__device__ __forceinline__ void lds_store4bf(char* base, int row, int cbyte,
                                             float a, float b, float c, float d) {
  int byte = row * 256 + ((((cbyte >> 4) ^ (row & 7))) << 4) + (cbyte & 15);
  ushort4 o4;
  o4.x = f2bf(a); o4.y = f2bf(b); o4.z = f2bf(c); o4.w = f2bf(d);
  *(ushort4*)(base + byte) = o4;
}

// ---------------- K0: mask dtype detection ----------------
__global__ void k_maskdetect(const unsigned char* __restrict__ m, int* __restrict__ flag)
{
  __shared__ int red[256];
  int tid = threadIdx.x;
  int cnt = 0;
  for (int idx = tid; idx < 131072; idx += 256) cnt += (m[idx] != 0) ? 1 : 0;
  red[tid] = cnt;
  __syncthreads();
  for (int s = 128; s > 0; s >>= 1) {
    if (tid < s) red[tid] += red[tid + s];
    __syncthreads();
  }
  if (tid == 0) *flag = (red[0] > 7864) ? 1 : 0;  // 1 = uint8 layout, 0 = int32
}

// ---------------- K1: fused projections via MFMA ----------------
// outputs: a1,a2 raw scores [pos][8]; v1,v2 [pos][128] f32
__global__ __launch_bounds__(256) void k_proj_mfma(
    const float* __restrict__ h,
    const float* __restrict__ wa1, const float* __restrict__ wa2,
    const float* __restrict__ wv1, const float* __restrict__ wv2,
    float* __restrict__ a1, float* __restrict__ a2,
    float* __restrict__ v1, float* __restrict__ v2)
{
  __shared__ __align__(16) char hb[32 * 256];      // bf16 swizzled [32][128]
  __shared__ __align__(16) float stage[32 * 132];
  const int tid = threadIdx.x, lane = tid & 63, w = tid >> 6;
  const size_t pos0 = (size_t)blockIdx.x * 32;

  // preload weight fragments (L2-resident, once per wave)
  const float* wv = (w < 2) ? wv1 : wv2;
  const int colbase = (w & 1) * 64;
  bf16x8 bfr[4][4];                                 // [colfrag][kstep]
  #pragma unroll
  for (int cf = 0; cf < 4; ++cf)
    #pragma unroll
    for (int ks = 0; ks < 4; ++ks)
      bfr[cf][ks] = load_wfrag(wv, colbase + cf * 16, ks * 32, lane);

  bf16x8 af[4];
  if (w == 0) {
    int r = lane & 15;
    const float* ar = (r < 8) ? (wa1 + (size_t)r * 128) : (wa2 + (size_t)(r - 8) * 128);
    #pragma unroll
    for (int ks = 0; ks < 4; ++ks) {
      const float* p = ar + ks * 32 + 8 * (lane >> 4);
      float4 x = *(const float4*)p;
      float4 y = *(const float4*)(p + 4);
      bf16x8 f;
      f[0]=(short)f2bf(x.x); f[1]=(short)f2bf(x.y); f[2]=(short)f2bf(x.z); f[3]=(short)f2bf(x.w);
      f[4]=(short)f2bf(y.x); f[5]=(short)f2bf(y.y); f[6]=(short)f2bf(y.z); f[7]=(short)f2bf(y.w);
      af[ks] = f;
    }
  }

  // stage h tile -> bf16 swizzled
  {
    const float4* hg4 = (const float4*)(h + pos0 * 128);
    #pragma unroll
    for (int q = 0; q < 4; ++q) {
      int f4i = tid + 256 * q;
      float4 x = hg4[f4i];
      int row = f4i >> 5;
      int cb = (f4i & 31) * 8;
      lds_store4bf(hb, row, cb, x.x, x.y, x.z, x.w);
    }
  }
  __syncthreads();

  f32x4 acc[2][4];
  #pragma unroll
  for (int rf = 0; rf < 2; ++rf)
    #pragma unroll
    for (int cf = 0; cf < 4; ++cf) acc[rf][cf] = (f32x4){0.f,0.f,0.f,0.f};
  f32x4 acca[2]; acca[0] = (f32x4){0.f,0.f,0.f,0.f}; acca[1] = acca[0];

  #pragma unroll
  for (int ks = 0; ks < 4; ++ks) {
    bf16x8 a0 = lds_afrag(hb, 0, ks * 32, lane);
    bf16x8 a1f = lds_afrag(hb, 16, ks * 32, lane);
    #pragma unroll
    for (int cf = 0; cf < 4; ++cf) {
      acc[0][cf] = __builtin_amdgcn_mfma_f32_16x16x32_bf16(a0,  bfr[cf][ks], acc[0][cf], 0, 0, 0);
      acc[1][cf] = __builtin_amdgcn_mfma_f32_16x16x32_bf16(a1f, bfr[cf][ks], acc[1][cf], 0, 0, 0);
    }
    if (w == 0) {
      acca[0] = __builtin_amdgcn_mfma_f32_16x16x32_bf16(a0,  af[ks], acca[0], 0, 0, 0);
      acca[1] = __builtin_amdgcn_mfma_f32_16x16x32_bf16(a1f, af[ks], acca[1], 0, 0, 0);
    }
  }

  const int lg = lane >> 4, lc = lane & 15;
  // v1 out
  if (w < 2) {
    #pragma unroll
    for (int rf = 0; rf < 2; ++rf)
      #pragma unroll
      for (int cf = 0; cf < 4; ++cf)
        #pragma unroll
        for (int r = 0; r < 4; ++r)
          stage[(rf*16 + 4*lg + r) * 132 + colbase + cf*16 + lc] = acc[rf][cf][r];
  }
  __syncthreads();
  {
    float4* dst = (float4*)(v1 + pos0 * 128);
    #pragma unroll
    for (int q = 0; q < 4; ++q) {
      int f4i = tid + 256 * q;
      int row = f4i >> 5, c4 = f4i & 31;
      dst[f4i] = *(const float4*)&stage[row * 132 + c4 * 4];
    }
  }
  __syncthreads();
  if (w >= 2) {
    #pragma unroll
    for (int rf = 0; rf < 2; ++rf)
      #pragma unroll
      for (int cf = 0; cf < 4; ++cf)
        #pragma unroll
        for (int r = 0; r < 4; ++r)
          stage[(rf*16 + 4*lg + r) * 132 + colbase + cf*16 + lc] = acc[rf][cf][r];
  }
  __syncthreads();
  {
    float4* dst = (float4*)(v2 + pos0 * 128);
    #pragma unroll
    for (int q = 0; q < 4; ++q) {
      int f4i = tid + 256 * q;
      int row = f4i >> 5, c4 = f4i & 31;
      dst[f4i] = *(const float4*)&stage[row * 132 + c4 * 4];
    }
  }
  if (w == 0) {
    #pragma unroll
    for (int rf = 0; rf < 2; ++rf)
      #pragma unroll
      for (int r = 0; r < 4; ++r) {
        int row = rf*16 + 4*lg + r;
        float val = acca[rf][r];
        if (lc < 8) a1[(pos0 + row) * 8 + lc] = val;
        else        a2[(pos0 + row) * 8 + (lc - 8)] = val;
      }
  }
}

// ---------------- K2a/K2b: row maxes ----------------
__global__ __launch_bounds__(64) void k_rowmax1(const float* __restrict__ a1,
                                                float* __restrict__ amax1)
{
  const int bi = blockIdx.x;
  const int t = threadIdx.x;
  const float* base = a1 + (size_t)bi * N_ * 8;
  float m = -1e30f;
  #pragma unroll 8
  for (int k = 0; k < 32; ++k) m = fmaxf(m, base[t + 64*k]);
  m = fmaxf(m, __shfl_xor(m, 8));
  m = fmaxf(m, __shfl_xor(m, 16));
  m = fmaxf(m, __shfl_xor(m, 32));
  if (t < 8) amax1[bi*8 + t] = m;
}

__global__ __launch_bounds__(64) void k_rowmax2(const float* __restrict__ a2,
                                                float* __restrict__ amax2)
{
  const int bj = blockIdx.x;
  const int b = bj >> 8, j = bj & 255;
  const int t = threadIdx.x;
  const int hh = t & 7, igrp = t >> 3;
  float m = -1e30f;
  for (int k = 0; k < 32; ++k) {
    int i = igrp + 8*k;
    m = fmaxf(m, a2[((size_t)(b*N_ + i)*N_ + j)*8 + hh]);
  }
  m = fmaxf(m, __shfl_xor(m, 8));
  m = fmaxf(m, __shfl_xor(m, 16));
  m = fmaxf(m, __shfl_xor(m, 32));
  if (t < 8) amax2[bj*8 + t] = m;
}

// ---------------- K3: masked exp + scale v by e (in place) ----------------
__global__ __launch_bounds__(128) void k_expscale(
    const void* __restrict__ maskraw, const int* __restrict__ modep,
    float* __restrict__ e1, float* __restrict__ e2,
    const float* __restrict__ amax1, const float* __restrict__ amax2,
    float* __restrict__ v1, float* __restrict__ v2)
{
  const int pos = blockIdx.x;
  const int c = threadIdx.x;
  const int b = pos >> 16, ij = pos & 65535;
  const int i = ij >> 8, j = ij & 255;
  const int hh = c >> 4;

  const int mode = modep[0];
  int msk;
  if (mode) msk = ((const unsigned char*)maskraw)[pos];
  else      msk = ((const int*)maskraw)[pos];

  float x1 = e1[pos*8 + hh];
  float x2 = e2[pos*8 + hh];
  float m1 = amax1[(b*N_ + i)*8 + hh];
  float m2 = amax2[(b*N_ + j)*8 + hh];
  float ev1 = msk ? 0.f : __expf(x1 - m1);
  float ev2 = msk ? 0.f : __expf(x2 - m2);
  v1[(size_t)pos*128 + c] *= ev1;
  v2[(size_t)pos*128 + c] *= ev2;
  __syncthreads();
  if (c < 8) {
    float xa = e1[pos*8 + c], xb = e2[pos*8 + c];
    float ma = amax1[(b*N_ + i)*8 + c], mb = amax2[(b*N_ + j)*8 + c];
    e1[pos*8 + c] = msk ? 0.f : __expf(xa - ma);
    e2[pos*8 + c] = msk ? 0.f : __expf(xb - mb);
  }
}

// ---------------- K4: triangle contraction ----------------
__global__ __launch_bounds__(256, 2) void k_tri(
    const float* __restrict__ p1, const float* __restrict__ p2,
    float* __restrict__ out)
{
  const int jt = blockIdx.x, it = blockIdx.y, b = blockIdx.z;
  const int tid = threadIdx.x;
  const int c = tid & 127;
  const int half = tid >> 7;
  const int i0 = it*16 + half*8;
  const int j0 = jt*16;

  const float* p1b = p1 + ((size_t)(b*N_ + i0)*N_)*128 + c;
  const float* p2b = p2 + ((size_t)b*N_*N_ + j0)*128 + c;

  float acc[8][16];
  #pragma unroll
  for (int ii = 0; ii < 8; ++ii)
    #pragma unroll
    for (int jj = 0; jj < 16; ++jj) acc[ii][jj] = 0.f;

  #pragma unroll 2
  for (int l = 0; l < N_; ++l) {
    float va[8], vb[16];
    #pragma unroll
    for (int ii = 0; ii < 8; ++ii) va[ii] = p1b[((size_t)ii*N_ + l)*128];
    #pragma unroll
    for (int jj = 0; jj < 16; ++jj) vb[jj] = p2b[((size_t)l*N_ + jj)*128];
    #pragma unroll
    for (int ii = 0; ii < 8; ++ii)
      #pragma unroll
      for (int jj = 0; jj < 16; ++jj)
        acc[ii][jj] += va[ii]*vb[jj];
  }

  #pragma unroll
  for (int ii = 0; ii < 8; ++ii)
    #pragma unroll
    for (int jj = 0; jj < 16; ++jj)
      out[((size_t)(b*N_ + i0 + ii)*N_ + (j0 + jj))*128 + c] = acc[ii][jj];
}

// ---------------- K4b: denom ----------------
__global__ __launch_bounds__(256) void k_denom(
    const float* __restrict__ e1, const float* __restrict__ e2,
    float* __restrict__ denom)
{
  const int jt = blockIdx.x;
  const int it = blockIdx.y;
  const int b = blockIdx.z;
  const int tid = threadIdx.x;
  const int hh = tid & 7;
  const int jl = tid >> 3;
  const int i0 = it*16, j0 = jt*32;

  float acc[16];
  #pragma unroll
  for (int ii = 0; ii < 16; ++ii) acc[ii] = 0.f;

  const float* e1b = e1 + ((size_t)(b*N_ + i0)*N_)*8 + hh;
  for (int l = 0; l < N_; ++l) {
    float b2 = e2[((size_t)(b*N_ + l)*N_ + j0 + jl)*8 + hh];
    #pragma unroll
    for (int ii = 0; ii < 16; ++ii) {
      float a1v = e1b[((size_t)ii*N_ + l)*8];
      acc[ii] += a1v * b2;
    }
  }
  #pragma unroll
  for (int ii = 0; ii < 16; ++ii)
    denom[((size_t)(b*N_ + i0 + ii)*N_ + j0 + jl)*8 + hh] = acc[ii];
}

// ---------------- K5: x = t/denom ; y = x@wo^T ; hn = LN1(h + y) ----------------
__global__ __launch_bounds__(256) void k_wo_ln_mfma(
    const float* __restrict__ t, const float* __restrict__ dn,
    const float* __restrict__ h, const float* __restrict__ wo,
    const float* __restrict__ g1, const float* __restrict__ bb1,
    float* __restrict__ hn)
{
  __shared__ __align__(16) char xb[32 * 256];
  __shared__ __align__(16) float stage[32 * 132];
  const int tid = threadIdx.x, lane = tid & 63, w = tid >> 6;
  const size_t pos0 = (size_t)blockIdx.x * 32;

  bf16x8 bfr[2][4];
  #pragma unroll
  for (int cf = 0; cf < 2; ++cf)
    #pragma unroll
    for (int ks = 0; ks < 4; ++ks)
      bfr[cf][ks] = load_wfrag(wo, w * 32 + cf * 16, ks * 32, lane);

  {
    const float4* tg = (const float4*)(t + pos0 * 128);
    #pragma unroll
    for (int q = 0; q < 4; ++q) {
      int f4i = tid + 256 * q;
      float4 x = tg[f4i];
      int row = f4i >> 5, c4 = f4i & 31;
      float d = dn[(pos0 + row) * 8 + (c4 >> 2)] + 1e-6f;
      float inv = 1.0f / d;
      lds_store4bf(xb, row, c4 * 8, x.x * inv, x.y * inv, x.z * inv, x.w * inv);
    }
  }
  __syncthreads();

  f32x4 acc[2][2];
  #pragma unroll
  for (int rf = 0; rf < 2; ++rf)
    #pragma unroll
    for (int cf = 0; cf < 2; ++cf) acc[rf][cf] = (f32x4){0.f,0.f,0.f,0.f};

  #pragma unroll
  for (int ks = 0; ks < 4; ++ks) {
    bf16x8 a0 = lds_afrag(xb, 0, ks * 32, lane);
    bf16x8 a1f = lds_afrag(xb, 16, ks * 32, lane);
    #pragma unroll
    for (int cf = 0; cf < 2; ++cf) {
      acc[0][cf] = __builtin_amdgcn_mfma_f32_16x16x32_bf16(a0,  bfr[cf][ks], acc[0][cf], 0, 0, 0);
      acc[1][cf] = __builtin_amdgcn_mfma_f32_16x16x32_bf16(a1f, bfr[cf][ks], acc[1][cf], 0, 0, 0);
    }
  }

  const int lg = lane >> 4, lc = lane & 15;
  #pragma unroll
  for (int rf = 0; rf < 2; ++rf)
    #pragma unroll
    for (int cf = 0; cf < 2; ++cf)
      #pragma unroll
      for (int r = 0; r < 4; ++r)
        stage[(rf*16 + 4*lg + r) * 132 + w*32 + cf*16 + lc] = acc[rf][cf][r];
  __syncthreads();

  const float ga = g1[lane], gb = g1[64 + lane];
  const float ba = bb1[lane], bbv = bb1[64 + lane];
  for (int rr = 0; rr < 8; ++rr) {
    int row = w * 8 + rr;
    float y0 = stage[row * 132 + lane];
    float y1 = stage[row * 132 + 64 + lane];
    float r0 = h[(pos0 + row) * 128 + lane] + y0;
    float r1 = h[(pos0 + row) * 128 + 64 + lane] + y1;
    float s = r0 + r1, sq = r0*r0 + r1*r1;
    #pragma unroll
    for (int m = 1; m < 64; m <<= 1) { s += __shfl_xor(s, m); sq += __shfl_xor(sq, m); }
    float mu = s * (1.f/128.f);
    float var = sq * (1.f/128.f) - mu*mu;
    float rstd = rsqrtf(var + 1e-5f);
    hn[(pos0 + row) * 128 + lane]      = (r0 - mu) * rstd * ga + ba;
    hn[(pos0 + row) * 128 + 64 + lane] = (r1 - mu) * rstd * gb + bbv;
  }
}

// ---------------- K6: FFN(silu) + residual + LN2 -> out ----------------
__global__ __launch_bounds__(256) void k_ffn_ln_mfma(
    const float* __restrict__ hnp,
    const float* __restrict__ w1, const float* __restrict__ bias1,
    const float* __restrict__ w2, const float* __restrict__ bias2,
    const float* __restrict__ g2, const float* __restrict__ b2v,
    float* __restrict__ out)
{
  __shared__ __align__(16) char xb[32 * 256];      // x bf16; reused for u
  __shared__ __align__(16) float stage[32 * 132];
  const int tid = threadIdx.x, lane = tid & 63, w = tid >> 6;
  const size_t pos0 = (size_t)blockIdx.x * 32;

  bf16x8 bf1[2][4], bf2[2][4];
  #pragma unroll
  for (int cf = 0; cf < 2; ++cf)
    #pragma unroll
    for (int ks = 0; ks < 4; ++ks) {
      bf1[cf][ks] = load_wfrag(w1, w * 32 + cf * 16, ks * 32, lane);
      bf2[cf][ks] = load_wfrag(w2, w * 32 + cf * 16, ks * 32, lane);
    }

  {
    const float4* hg4 = (const float4*)(hnp + pos0 * 128);
    #pragma unroll
    for (int q = 0; q < 4; ++q) {
      int f4i = tid + 256 * q;
      float4 x = hg4[f4i];
      lds_store4bf(xb, f4i >> 5, (f4i & 31) * 8, x.x, x.y, x.z, x.w);
    }
  }
  __syncthreads();

  f32x4 acc[2][2];
  #pragma unroll
  for (int rf = 0; rf < 2; ++rf)
    #pragma unroll
    for (int cf = 0; cf < 2; ++cf) acc[rf][cf] = (f32x4){0.f,0.f,0.f,0.f};

  #pragma unroll
  for (int ks = 0; ks < 4; ++ks) {
    bf16x8 a0 = lds_afrag(xb, 0, ks * 32, lane);
    bf16x8 a1f = lds_afrag(xb, 16, ks * 32, lane);
    #pragma unroll
    for (int cf = 0; cf < 2; ++cf) {
      acc[0][cf] = __builtin_amdgcn_mfma_f32_16x16x32_bf16(a0,  bf1[cf][ks], acc[0][cf], 0, 0, 0);
      acc[1][cf] = __builtin_amdgcn_mfma_f32_16x16x32_bf16(a1f, bf1[cf][ks], acc[1][cf], 0, 0, 0);
    }
  }
  __syncthreads();   // all xb reads done before overwrite with u

  const int lg = lane >> 4, lc = lane & 15;
  {
    float bc0 = bias1[w*32 + lc];
    float bc1 = bias1[w*32 + 16 + lc];
    #pragma unroll
    for (int rf = 0; rf < 2; ++rf)
      #pragma unroll
      for (int cf = 0; cf < 2; ++cf) {
        float bc = cf ? bc1 : bc0;
        #pragma unroll
        for (int r = 0; r < 4; ++r) {
          int row = rf*16 + 4*lg + r;
          int col = w*32 + cf*16 + lc;
          float s = acc[rf][cf][r] + bc;
          float u = s / (1.f + __expf(-s));
          int cbyte = col * 2;
          int byte = row * 256 + ((((cbyte >> 4) ^ (row & 7))) << 4) + (cbyte & 15);
          *(unsigned short*)(xb + byte) = f2bf(u);
        }
      }
  }
  __syncthreads();

  f32x4 acc2[2][2];
  #pragma unroll
  for (int rf = 0; rf < 2; ++rf)
    #pragma unroll
    for (int cf = 0; cf < 2; ++cf) acc2[rf][cf] = (f32x4){0.f,0.f,0.f,0.f};

  #pragma unroll
  for (int ks = 0; ks < 4; ++ks) {
    bf16x8 a0 = lds_afrag(xb, 0, ks * 32, lane);
    bf16x8 a1f = lds_afrag(xb, 16, ks * 32, lane);
    #pragma unroll
    for (int cf = 0; cf < 2; ++cf) {
      acc2[0][cf] = __builtin_amdgcn_mfma_f32_16x16x32_bf16(a0,  bf2[cf][ks], acc2[0][cf], 0, 0, 0);
      acc2[1][cf] = __builtin_amdgcn_mfma_f32_16x16x32_bf16(a1f, bf2[cf][ks], acc2[1][cf], 0, 0, 0);
    }
  }

  {
    float bc0 = bias2[w*32 + lc];
    float bc1 = bias2[w*32 + 16 + lc];
    #pragma unroll
    for (int rf = 0; rf < 2; ++rf)
      #pragma unroll
      for (int cf = 0; cf < 2; ++cf) {
        float bc = cf ? bc1 : bc0;
        #pragma unroll
        for (int r = 0; r < 4; ++r)
          stage[(rf*16 + 4*lg + r) * 132 + w*32 + cf*16 + lc] = acc2[rf][cf][r] + bc;
      }
  }
  __syncthreads();

  const float ga = g2[lane], gb = g2[64 + lane];
  const float ba = b2v[lane], bbv = b2v[64 + lane];
  for (int rr = 0; rr < 8; ++rr) {
    int row = w * 8 + rr;
    float y0 = stage[row * 132 + lane];
    float y1 = stage[row * 132 + 64 + lane];
    float r0 = hnp[(pos0 + row) * 128 + lane] + y0;
    float r1 = hnp[(pos0 + row) * 128 + 64 + lane] + y1;
    float s = r0 + r1, sq = r0*r0 + r1*r1;
    #pragma unroll
    for (int m = 1; m < 64; m <<= 1) { s += __shfl_xor(s, m); sq += __shfl_xor(sq, m); }
    float mu = s * (1.f/128.f);
    float var = sq * (1.f/128.f) - mu*mu;
    float rstd = rsqrtf(var + 1e-5f);
    out[(pos0 + row) * 128 + lane]      = (r0 - mu) * rstd * ga + ba;
    out[(pos0 + row) * 128 + 64 + lane] = (r1 - mu) * rstd * gb + bbv;
  }
}

extern "C" void kernel_launch(void* const* d_in, const int* in_sizes, int n_in,
                              void* d_out, int out_size, void* d_ws, size_t ws_size,
                              hipStream_t stream)
{
  const float* h    = (const float*)d_in[0];
  const void*  mask = d_in[1];
  const float* wa1  = (const float*)d_in[2];
  const float* wa2  = (const float*)d_in[3];
  const float* wv1  = (const float*)d_in[4];
  const float* wv2  = (const float*)d_in[5];
  const float* wo   = (const float*)d_in[6];
  const float* ln1s = (const float*)d_in[7];
  const float* ln1b = (const float*)d_in[8];
  const float* ln2s = (const float*)d_in[9];
  const float* ln2b = (const float*)d_in[10];
  const float* wu1  = (const float*)d_in[11];
  const float* bu1  = (const float*)d_in[12];
  const float* wu2  = (const float*)d_in[13];
  const float* bu2  = (const float*)d_in[14];

  char* ws = (char*)d_ws;
  const size_t MB = 1024*1024;
  float* e1  = (float*)(ws + 0*MB);
  float* e2  = (float*)(ws + 4*MB);
  float* p1  = (float*)(ws + 8*MB);
  float* p2  = (float*)(ws + 72*MB);
  float* dn  = (float*)(ws + 136*MB);
  float* am1 = (float*)(ws + 140*MB);
  float* am2 = (float*)(ws + 140*MB + 16384);
  int*   flg = (int*)  (ws + 140*MB + 32768);
  float* tbuf = (float*)d_out;
  float* hn = p1;

  k_maskdetect<<<1, 256, 0, stream>>>((const unsigned char*)mask, flg);
  k_proj_mfma<<<4096, 256, 0, stream>>>(h, wa1, wa2, wv1, wv2, e1, e2, p1, p2);
  k_rowmax1<<<512, 64, 0, stream>>>(e1, am1);
  k_rowmax2<<<512, 64, 0, stream>>>(e2, am2);
  k_expscale<<<131072, 128, 0, stream>>>(mask, flg, e1, e2, am1, am2, p1, p2);
  k_tri<<<dim3(16,16,2), 256, 0, stream>>>(p1, p2, tbuf);
  k_denom<<<dim3(8,16,2), 256, 0, stream>>>(e1, e2, dn);
  k_wo_ln_mfma<<<4096, 256, 0, stream>>>(tbuf, dn, h, wo, ln1s, ln1b, hn);
  k_ffn_ln_mfma<<<4096, 256, 0, stream>>>(hn, wu1, bu1, wu2, bu2, ln2s, ln2b, (float*)d_out);
}

// Round 3
// 348.678 us; speedup vs baseline: 10.9461x; 1.6661x over previous
//
#include <hip/hip_runtime.h>

#define B_ 2
#define N_ 256
#define C_ 128
#define H_ 8

typedef __attribute__((ext_vector_type(8))) short bf16x8;
typedef __attribute__((ext_vector_type(8))) unsigned short u16x8;
typedef __attribute__((ext_vector_type(4))) float f32x4;

__device__ __forceinline__ unsigned short f2bf(float f) {
  unsigned int u = __float_as_uint(f);
  unsigned int r = (u + 0x7FFFu + ((u >> 16) & 1u)) >> 16;
  return (unsigned short)r;
}
__device__ __forceinline__ float bf2f(unsigned short u) {
  return __uint_as_float(((unsigned int)u) << 16);
}

// B-fragment (16 rows x 32 k) from row-major f32 weight matrix [R][128]
__device__ __forceinline__ bf16x8 load_wfrag(const float* __restrict__ W,
                                             int row0, int k0, int lane) {
  const float* p = W + (size_t)(row0 + (lane & 15)) * 128 + k0 + 8 * (lane >> 4);
  float4 x = *(const float4*)p;
  float4 y = *(const float4*)(p + 4);
  bf16x8 f;
  f[0] = (short)f2bf(x.x); f[1] = (short)f2bf(x.y);
  f[2] = (short)f2bf(x.z); f[3] = (short)f2bf(x.w);
  f[4] = (short)f2bf(y.x); f[5] = (short)f2bf(y.y);
  f[6] = (short)f2bf(y.z); f[7] = (short)f2bf(y.w);
  return f;
}

// A-fragment from XOR-swizzled bf16 LDS tile [32 rows][128 cols] (256 B/row)
__device__ __forceinline__ bf16x8 lds_afrag(const char* base, int row0, int k0, int lane) {
  int row = row0 + (lane & 15);
  int cb = (k0 + 8 * (lane >> 4)) * 2;
  int byte = row * 256 + ((((cb >> 4) ^ (row & 7))) << 4);
  return *(const bf16x8*)(base + byte);
}

__device__ __forceinline__ void lds_store4bf(char* base, int row, int cbyte,
                                             float a, float b, float c, float d) {
  int byte = row * 256 + ((((cbyte >> 4) ^ (row & 7))) << 4) + (cbyte & 15);
  ushort4 o4;
  o4.x = f2bf(a); o4.y = f2bf(b); o4.z = f2bf(c); o4.w = f2bf(d);
  *(ushort4*)(base + byte) = o4;
}

// ---------------- K0: mask dtype detection ----------------
__global__ void k_maskdetect(const unsigned char* __restrict__ m, int* __restrict__ flag)
{
  __shared__ int red[256];
  int tid = threadIdx.x;
  int cnt = 0;
  for (int idx = tid; idx < 131072; idx += 256) cnt += (m[idx] != 0) ? 1 : 0;
  red[tid] = cnt;
  __syncthreads();
  for (int s = 128; s > 0; s >>= 1) {
    if (tid < s) red[tid] += red[tid + s];
    __syncthreads();
  }
  if (tid == 0) *flag = (red[0] > 7864) ? 1 : 0;
}

// ---------------- K1: fused projections via MFMA (v out = bf16) ----------------
__global__ __launch_bounds__(256) void k_proj_mfma(
    const float* __restrict__ h,
    const float* __restrict__ wa1, const float* __restrict__ wa2,
    const float* __restrict__ wv1, const float* __restrict__ wv2,
    float* __restrict__ a1, float* __restrict__ a2,
    unsigned short* __restrict__ v1, unsigned short* __restrict__ v2)
{
  __shared__ __align__(16) char hb[32 * 256];
  __shared__ __align__(16) float stage[32 * 132];
  const int tid = threadIdx.x, lane = tid & 63, w = tid >> 6;
  const size_t pos0 = (size_t)blockIdx.x * 32;

  const float* wv = (w < 2) ? wv1 : wv2;
  const int colbase = (w & 1) * 64;
  bf16x8 bfr[4][4];
  #pragma unroll
  for (int cf = 0; cf < 4; ++cf)
    #pragma unroll
    for (int ks = 0; ks < 4; ++ks)
      bfr[cf][ks] = load_wfrag(wv, colbase + cf * 16, ks * 32, lane);

  bf16x8 af[4];
  if (w == 0) {
    int r = lane & 15;
    const float* ar = (r < 8) ? (wa1 + (size_t)r * 128) : (wa2 + (size_t)(r - 8) * 128);
    #pragma unroll
    for (int ks = 0; ks < 4; ++ks) {
      const float* p = ar + ks * 32 + 8 * (lane >> 4);
      float4 x = *(const float4*)p;
      float4 y = *(const float4*)(p + 4);
      bf16x8 f;
      f[0]=(short)f2bf(x.x); f[1]=(short)f2bf(x.y); f[2]=(short)f2bf(x.z); f[3]=(short)f2bf(x.w);
      f[4]=(short)f2bf(y.x); f[5]=(short)f2bf(y.y); f[6]=(short)f2bf(y.z); f[7]=(short)f2bf(y.w);
      af[ks] = f;
    }
  }

  {
    const float4* hg4 = (const float4*)(h + pos0 * 128);
    #pragma unroll
    for (int q = 0; q < 4; ++q) {
      int f4i = tid + 256 * q;
      float4 x = hg4[f4i];
      lds_store4bf(hb, f4i >> 5, (f4i & 31) * 8, x.x, x.y, x.z, x.w);
    }
  }
  __syncthreads();

  f32x4 acc[2][4];
  #pragma unroll
  for (int rf = 0; rf < 2; ++rf)
    #pragma unroll
    for (int cf = 0; cf < 4; ++cf) acc[rf][cf] = (f32x4){0.f,0.f,0.f,0.f};
  f32x4 acca[2]; acca[0] = (f32x4){0.f,0.f,0.f,0.f}; acca[1] = acca[0];

  #pragma unroll
  for (int ks = 0; ks < 4; ++ks) {
    bf16x8 a0 = lds_afrag(hb, 0, ks * 32, lane);
    bf16x8 a1f = lds_afrag(hb, 16, ks * 32, lane);
    #pragma unroll
    for (int cf = 0; cf < 4; ++cf) {
      acc[0][cf] = __builtin_amdgcn_mfma_f32_16x16x32_bf16(a0,  bfr[cf][ks], acc[0][cf], 0, 0, 0);
      acc[1][cf] = __builtin_amdgcn_mfma_f32_16x16x32_bf16(a1f, bfr[cf][ks], acc[1][cf], 0, 0, 0);
    }
    if (w == 0) {
      acca[0] = __builtin_amdgcn_mfma_f32_16x16x32_bf16(a0,  af[ks], acca[0], 0, 0, 0);
      acca[1] = __builtin_amdgcn_mfma_f32_16x16x32_bf16(a1f, af[ks], acca[1], 0, 0, 0);
    }
  }

  const int lg = lane >> 4, lc = lane & 15;
  if (w < 2) {
    #pragma unroll
    for (int rf = 0; rf < 2; ++rf)
      #pragma unroll
      for (int cf = 0; cf < 4; ++cf)
        #pragma unroll
        for (int r = 0; r < 4; ++r)
          stage[(rf*16 + 4*lg + r) * 132 + colbase + cf*16 + lc] = acc[rf][cf][r];
  }
  __syncthreads();
  {
    #pragma unroll
    for (int q = 0; q < 4; ++q) {
      int f4i = tid + 256 * q;
      int row = f4i >> 5, c4 = f4i & 31;
      const float* sp = &stage[row * 132 + c4 * 4];
      ushort4 o; o.x = f2bf(sp[0]); o.y = f2bf(sp[1]); o.z = f2bf(sp[2]); o.w = f2bf(sp[3]);
      *(ushort4*)(v1 + (pos0 + row) * 128 + c4 * 4) = o;
    }
  }
  __syncthreads();
  if (w >= 2) {
    #pragma unroll
    for (int rf = 0; rf < 2; ++rf)
      #pragma unroll
      for (int cf = 0; cf < 4; ++cf)
        #pragma unroll
        for (int r = 0; r < 4; ++r)
          stage[(rf*16 + 4*lg + r) * 132 + colbase + cf*16 + lc] = acc[rf][cf][r];
  }
  __syncthreads();
  {
    #pragma unroll
    for (int q = 0; q < 4; ++q) {
      int f4i = tid + 256 * q;
      int row = f4i >> 5, c4 = f4i & 31;
      const float* sp = &stage[row * 132 + c4 * 4];
      ushort4 o; o.x = f2bf(sp[0]); o.y = f2bf(sp[1]); o.z = f2bf(sp[2]); o.w = f2bf(sp[3]);
      *(ushort4*)(v2 + (pos0 + row) * 128 + c4 * 4) = o;
    }
  }
  if (w == 0) {
    #pragma unroll
    for (int rf = 0; rf < 2; ++rf)
      #pragma unroll
      for (int r = 0; r < 4; ++r) {
        int row = rf*16 + 4*lg + r;
        float val = acca[rf][r];
        if (lc < 8) a1[(pos0 + row) * 8 + lc] = val;
        else        a2[(pos0 + row) * 8 + (lc - 8)] = val;
      }
  }
}

// ---------------- K2a/K2b: row maxes ----------------
__global__ __launch_bounds__(64) void k_rowmax1(const float* __restrict__ a1,
                                                float* __restrict__ amax1)
{
  const int bi = blockIdx.x;
  const int t = threadIdx.x;
  const float* base = a1 + (size_t)bi * N_ * 8;
  float m = -1e30f;
  #pragma unroll 8
  for (int k = 0; k < 32; ++k) m = fmaxf(m, base[t + 64*k]);
  m = fmaxf(m, __shfl_xor(m, 8));
  m = fmaxf(m, __shfl_xor(m, 16));
  m = fmaxf(m, __shfl_xor(m, 32));
  if (t < 8) amax1[bi*8 + t] = m;
}

__global__ __launch_bounds__(64) void k_rowmax2(const float* __restrict__ a2,
                                                float* __restrict__ amax2)
{
  const int bj = blockIdx.x;
  const int b = bj >> 8, j = bj & 255;
  const int t = threadIdx.x;
  const int hh = t & 7, igrp = t >> 3;
  float m = -1e30f;
  for (int k = 0; k < 32; ++k) {
    int i = igrp + 8*k;
    m = fmaxf(m, a2[((size_t)(b*N_ + i)*N_ + j)*8 + hh]);
  }
  m = fmaxf(m, __shfl_xor(m, 8));
  m = fmaxf(m, __shfl_xor(m, 16));
  m = fmaxf(m, __shfl_xor(m, 32));
  if (t < 8) amax2[bj*8 + t] = m;
}

// ---------------- K3: exp (masked); e2 f32 natural; eb1 bf16 -> Abuf ch128+ ----------------
__global__ __launch_bounds__(256) void k_e(
    const void* __restrict__ maskraw, const int* __restrict__ modep,
    const float* __restrict__ a1, const float* __restrict__ a2,
    const float* __restrict__ am1, const float* __restrict__ am2,
    float* __restrict__ e2out, unsigned short* __restrict__ Abuf)
{
  __shared__ unsigned short eb[8 * 256];   // [h][p] bf16
  const int tid = threadIdx.x;
  const size_t pos0 = (size_t)blockIdx.x * 256;
  const size_t p = pos0 + tid;
  const int b = (int)(p >> 16), ij = (int)(p & 65535);
  const int i = ij >> 8, j = ij & 255;
  const int msk = modep[0] ? (int)((const unsigned char*)maskraw)[p]
                           : ((const int*)maskraw)[p];
  float4 x0 = *(const float4*)(a1 + p*8);
  float4 x1 = *(const float4*)(a1 + p*8 + 4);
  float4 m0 = *(const float4*)(am1 + ((size_t)(b*256 + i))*8);
  float4 m1 = *(const float4*)(am1 + ((size_t)(b*256 + i))*8 + 4);
  eb[0*256 + tid] = msk ? 0 : f2bf(__expf(x0.x - m0.x));
  eb[1*256 + tid] = msk ? 0 : f2bf(__expf(x0.y - m0.y));
  eb[2*256 + tid] = msk ? 0 : f2bf(__expf(x0.z - m0.z));
  eb[3*256 + tid] = msk ? 0 : f2bf(__expf(x0.w - m0.w));
  eb[4*256 + tid] = msk ? 0 : f2bf(__expf(x1.x - m1.x));
  eb[5*256 + tid] = msk ? 0 : f2bf(__expf(x1.y - m1.y));
  eb[6*256 + tid] = msk ? 0 : f2bf(__expf(x1.z - m1.z));
  eb[7*256 + tid] = msk ? 0 : f2bf(__expf(x1.w - m1.w));

  float4 y0 = *(const float4*)(a2 + p*8);
  float4 y1 = *(const float4*)(a2 + p*8 + 4);
  float4 n0 = *(const float4*)(am2 + ((size_t)(b*256 + j))*8);
  float4 n1 = *(const float4*)(am2 + ((size_t)(b*256 + j))*8 + 4);
  float4 o0, o1;
  o0.x = msk ? 0.f : __expf(y0.x - n0.x);
  o0.y = msk ? 0.f : __expf(y0.y - n0.y);
  o0.z = msk ? 0.f : __expf(y0.z - n0.z);
  o0.w = msk ? 0.f : __expf(y0.w - n0.w);
  o1.x = msk ? 0.f : __expf(y1.x - n1.x);
  o1.y = msk ? 0.f : __expf(y1.y - n1.y);
  o1.z = msk ? 0.f : __expf(y1.z - n1.z);
  o1.w = msk ? 0.f : __expf(y1.w - n1.w);
  *(float4*)(e2out + p*8) = o0;
  *(float4*)(e2out + p*8 + 4) = o1;

  __syncthreads();
  {
    int hh = tid >> 5, seg = tid & 31;
    int4 v = *(const int4*)((const char*)eb + hh*512 + seg*16);
    *(int4*)(Abuf + (((size_t)(b*136 + 128 + hh)) << 16) + (int)(pos0 & 65535) + seg*8) = v;
  }
}

// ---------------- K4a: pc1[c][i][l] = vb1[pos][c] * e1 (channel transpose) ----------------
__global__ __launch_bounds__(256) void k_prep1(
    const unsigned short* __restrict__ vb1, unsigned short* __restrict__ Abuf)
{
  __shared__ __align__(16) char lds[36864];  // xt [128][272B] + et [8][256B]
  char* xt = lds;
  unsigned short* et = (unsigned short*)(lds + 34816);
  const int tid = threadIdx.x;
  const size_t pos0 = (size_t)blockIdx.x * 128;
  const int b = (int)(pos0 >> 16);
  const int posl0 = (int)(pos0 & 65535);

  if (tid < 128) {
    int hh = tid >> 4, seg = tid & 15;
    int4 v = *(const int4*)(Abuf + (((size_t)(b*136 + 128 + hh)) << 16) + posl0 + seg*8);
    *(int4*)((char*)et + hh*256 + seg*16) = v;
  }
  #pragma unroll
  for (int q = 0; q < 8; ++q) {
    int s = q*256 + tid;
    int rec = s >> 4, g = s & 15;
    int4 v = *(const int4*)(vb1 + (pos0 + rec)*128 + g*8);
    *(int4*)(xt + rec*272 + g*16) = v;
  }
  __syncthreads();
  #pragma unroll
  for (int q = 0; q < 8; ++q) {
    int c = q*16 + (tid & 15);
    int pg = tid >> 4;
    int hh = c >> 4;
    u16x8 t;
    #pragma unroll
    for (int k = 0; k < 8; ++k) {
      int p = pg*8 + k;
      float xv = bf2f(*(const unsigned short*)(xt + p*272 + c*2));
      float ev = bf2f(et[hh*128 + p]);
      t[k] = f2bf(xv * ev);
    }
    *(int4*)(Abuf + (((size_t)(b*136 + c)) << 16) + posl0 + pg*8) = *(int4*)&t;
  }
}

// ---------------- K4b: pc2t[c][j][l] = vb2[(l,j)][c]*e2 ; eb2t[h][j][l] ----------------
__global__ __launch_bounds__(256) void k_prep2(
    const unsigned short* __restrict__ vb2, const float* __restrict__ e2,
    unsigned short* __restrict__ Bbuf)
{
  __shared__ __align__(16) char lds[49152];  // vt [512][80B] + et [512][16B]
  char* vt = lds;
  unsigned short* et = (unsigned short*)(lds + 40960);  // [rec][8 h] bf16
  const int tid = threadIdx.x;
  const int lt = blockIdx.x, jt = blockIdx.y, b = blockIdx.z;
  const int l0 = lt*32, j0 = jt*16;

  #pragma unroll
  for (int q = 0; q < 4; ++q) {
    int s = q*256 + tid;
    int rec = s >> 1, hf = (s & 1)*4;
    int l = rec >> 4, j = rec & 15;
    size_t pos = ((size_t)b << 16) + (size_t)(l0 + l)*256 + (j0 + j);
    float4 ev = *(const float4*)(e2 + pos*8 + hf);
    ushort4 o; o.x = f2bf(ev.x); o.y = f2bf(ev.y); o.z = f2bf(ev.z); o.w = f2bf(ev.w);
    *(ushort4*)(et + rec*8 + hf) = o;
  }

  for (int cw = 0; cw < 4; ++cw) {
    __syncthreads();
    #pragma unroll
    for (int q = 0; q < 8; ++q) {
      int s = q*256 + tid;
      int rec = s >> 2, g = s & 3;
      int l = rec >> 4, j = rec & 15;
      size_t pos = ((size_t)b << 16) + (size_t)(l0 + l)*256 + (j0 + j);
      int4 v = *(const int4*)(vb2 + pos*128 + cw*32 + g*8);
      *(int4*)(vt + rec*80 + g*16) = v;
    }
    __syncthreads();
    #pragma unroll
    for (int q = 0; q < 8; ++q) {
      int loff = tid & 3, j = (tid >> 2) & 15, cs = tid >> 6;
      int cl = q*4 + cs;
      int c = cw*32 + cl;
      int hh = c >> 4;
      u16x8 t;
      #pragma unroll
      for (int k = 0; k < 8; ++k) {
        int l = loff*8 + k;
        int rec = l*16 + j;
        float xv = bf2f(*(const unsigned short*)(vt + rec*80 + cl*2));
        float ev = bf2f(et[rec*8 + hh]);
        t[k] = f2bf(xv * ev);
      }
      *(int4*)(Bbuf + (((size_t)(b*136 + c)) << 16) + (size_t)(j0 + j)*256 + l0 + loff*8) = *(int4*)&t;
    }
  }
  __syncthreads();
  #pragma unroll
  for (int q = 0; q < 2; ++q) {
    int s = q*256 + tid;
    int loff = s & 3, j = (s >> 2) & 15, hh = s >> 6;
    u16x8 t;
    #pragma unroll
    for (int k = 0; k < 8; ++k) {
      int l = loff*8 + k;
      int rec = l*16 + j;
      t[k] = et[rec*8 + hh];
    }
    *(int4*)(Bbuf + (((size_t)(b*136 + 128 + hh)) << 16) + (size_t)(j0 + j)*256 + l0 + loff*8) = *(int4*)&t;
  }
}

// ---------------- K5: batched 256^3 GEMM over 272 channels (tri + denom) ----------------
__global__ __launch_bounds__(256) void k_tri_mfma(
    const unsigned short* __restrict__ Ab, const unsigned short* __restrict__ Bb,
    unsigned short* __restrict__ outT)
{
  __shared__ __align__(16) char lds[34816];
  char* lA = lds;
  char* lB = lds + 10240;
  const int tid = threadIdx.x, lane = tid & 63, w = tid >> 6;
  const int jt = blockIdx.x, it = blockIdx.y, z = blockIdx.z;
  const int b = z / 136, ch = z - b*136;
  const size_t mbase = ((size_t)(b*136 + ch)) << 16;
  const int i0 = it*128, j0 = jt*128;
  const int r4 = tid >> 2, g4 = tid & 3;

  const unsigned short* gA0 = Ab + mbase + (size_t)(i0 + r4)*256 + g4*8;
  const unsigned short* gA1 = gA0 + 64*256;
  const unsigned short* gB0 = Bb + mbase + (size_t)(j0 + r4)*256 + g4*8;
  const unsigned short* gB1 = gB0 + 64*256;
  char* sA0 = lA + r4*80 + g4*16;
  char* sA1 = sA0 + 64*80;
  char* sB0 = lB + r4*80 + g4*16;
  char* sB1 = sB0 + 64*80;

  const int wr = w >> 1, wc = w & 1;
  const char* fA = lA + (wr*64 + (lane & 15))*80 + (lane >> 4)*16;
  const char* fB = lB + (wc*64 + (lane & 15))*80 + (lane >> 4)*16;

  f32x4 acc[4][4];
  #pragma unroll
  for (int rf = 0; rf < 4; ++rf)
    #pragma unroll
    for (int cf = 0; cf < 4; ++cf) acc[rf][cf] = (f32x4){0.f,0.f,0.f,0.f};

  int4 ra0 = *(const int4*)gA0;
  int4 ra1 = *(const int4*)gA1;
  int4 rb0 = *(const int4*)gB0;
  int4 rb1 = *(const int4*)gB1;

  for (int ks = 0; ks < 8; ++ks) {
    __syncthreads();
    *(int4*)sA0 = ra0; *(int4*)sA1 = ra1;
    *(int4*)sB0 = rb0; *(int4*)sB1 = rb1;
    __syncthreads();
    if (ks < 7) {
      const int off = (ks + 1)*32;
      ra0 = *(const int4*)(gA0 + off);
      ra1 = *(const int4*)(gA1 + off);
      rb0 = *(const int4*)(gB0 + off);
      rb1 = *(const int4*)(gB1 + off);
    }
    bf16x8 af[4], bfv[4];
    #pragma unroll
    for (int rf = 0; rf < 4; ++rf) af[rf] = *(const bf16x8*)(fA + rf*16*80);
    #pragma unroll
    for (int cf = 0; cf < 4; ++cf) bfv[cf] = *(const bf16x8*)(fB + cf*16*80);
    #pragma unroll
    for (int rf = 0; rf < 4; ++rf)
      #pragma unroll
      for (int cf = 0; cf < 4; ++cf)
        acc[rf][cf] = __builtin_amdgcn_mfma_f32_16x16x32_bf16(af[rf], bfv[cf], acc[rf][cf], 0, 0, 0);
  }

  __syncthreads();
  #pragma unroll
  for (int rf = 0; rf < 4; ++rf)
    #pragma unroll
    for (int cf = 0; cf < 4; ++cf)
      #pragma unroll
      for (int r = 0; r < 4; ++r) {
        int il = wr*64 + rf*16 + 4*(lane >> 4) + r;
        int jl = wc*64 + cf*16 + (lane & 15);
        *(unsigned short*)(lds + il*272 + jl*2) = f2bf(acc[rf][cf][r]);
      }
  __syncthreads();
  #pragma unroll
  for (int q = 0; q < 8; ++q) {
    int row = q*16 + (tid >> 4), seg = tid & 15;
    int4 v = *(const int4*)(lds + row*272 + seg*16);
    *(int4*)(outT + mbase + (size_t)(i0 + row)*256 + j0 + seg*8) = v;
  }
}

// ---------------- K6: x = t/denom ; y = x@wo^T ; hn = bf16(LN1(h + y)) ----------------
__global__ __launch_bounds__(256) void k_wo_ln_mfma(
    const unsigned short* __restrict__ tT,
    const float* __restrict__ h, const float* __restrict__ wo,
    const float* __restrict__ g1, const float* __restrict__ bb1,
    unsigned short* __restrict__ hn)
{
  __shared__ __align__(16) char xb[32 * 256];
  __shared__ __align__(16) float stage[32 * 132];
  const int tid = threadIdx.x, lane = tid & 63, w = tid >> 6;
  const size_t pos0 = (size_t)blockIdx.x * 32;
  const int b = (int)(pos0 >> 16);
  const int posl0 = (int)(pos0 & 65535);

  bf16x8 bfr[2][4];
  #pragma unroll
  for (int cf = 0; cf < 2; ++cf)
    #pragma unroll
    for (int ks = 0; ks < 4; ++ks)
      bfr[cf][ks] = load_wfrag(wo, w * 32 + cf * 16, ks * 32, lane);

  #pragma unroll
  for (int it2 = 0; it2 < 2; ++it2) {
    int c = it2*64 + (tid >> 2);
    int poff = (tid & 3)*8;
    u16x8 tv = *(const u16x8*)(tT + (((size_t)(b*136 + c)) << 16) + posl0 + poff);
    u16x8 dv = *(const u16x8*)(tT + (((size_t)(b*136 + 128 + (c >> 4))) << 16) + posl0 + poff);
    int cb = c*2;
    #pragma unroll
    for (int k = 0; k < 8; ++k) {
      float x = bf2f(tv[k]) / (bf2f(dv[k]) + 1e-6f);
      int p = poff + k;
      int byte = p*256 + ((((cb >> 4) ^ (p & 7))) << 4) + (cb & 15);
      *(unsigned short*)(xb + byte) = f2bf(x);
    }
  }
  __syncthreads();

  f32x4 acc[2][2];
  #pragma unroll
  for (int rf = 0; rf < 2; ++rf)
    #pragma unroll
    for (int cf = 0; cf < 2; ++cf) acc[rf][cf] = (f32x4){0.f,0.f,0.f,0.f};

  #pragma unroll
  for (int ks = 0; ks < 4; ++ks) {
    bf16x8 a0 = lds_afrag(xb, 0, ks * 32, lane);
    bf16x8 a1f = lds_afrag(xb, 16, ks * 32, lane);
    #pragma unroll
    for (int cf = 0; cf < 2; ++cf) {
      acc[0][cf] = __builtin_amdgcn_mfma_f32_16x16x32_bf16(a0,  bfr[cf][ks], acc[0][cf], 0, 0, 0);
      acc[1][cf] = __builtin_amdgcn_mfma_f32_16x16x32_bf16(a1f, bfr[cf][ks], acc[1][cf], 0, 0, 0);
    }
  }

  const int lg = lane >> 4, lc = lane & 15;
  #pragma unroll
  for (int rf = 0; rf < 2; ++rf)
    #pragma unroll
    for (int cf = 0; cf < 2; ++cf)
      #pragma unroll
      for (int r = 0; r < 4; ++r)
        stage[(rf*16 + 4*lg + r) * 132 + w*32 + cf*16 + lc] = acc[rf][cf][r];
  __syncthreads();

  const float ga = g1[lane], gb = g1[64 + lane];
  const float ba = bb1[lane], bbv = bb1[64 + lane];
  for (int rr = 0; rr < 8; ++rr) {
    int row = w * 8 + rr;
    float y0 = stage[row * 132 + lane];
    float y1 = stage[row * 132 + 64 + lane];
    float r0 = h[(pos0 + row) * 128 + lane] + y0;
    float r1 = h[(pos0 + row) * 128 + 64 + lane] + y1;
    float s = r0 + r1, sq = r0*r0 + r1*r1;
    #pragma unroll
    for (int m = 1; m < 64; m <<= 1) { s += __shfl_xor(s, m); sq += __shfl_xor(sq, m); }
    float mu = s * (1.f/128.f);
    float var = sq * (1.f/128.f) - mu*mu;
    float rstd = rsqrtf(var + 1e-5f);
    hn[(pos0 + row) * 128 + lane]      = f2bf((r0 - mu) * rstd * ga + ba);
    hn[(pos0 + row) * 128 + 64 + lane] = f2bf((r1 - mu) * rstd * gb + bbv);
  }
}

// ---------------- K7: FFN(silu) + residual + LN2 -> out (hn bf16 in) ----------------
__global__ __launch_bounds__(256) void k_ffn_ln_mfma(
    const unsigned short* __restrict__ hnp,
    const float* __restrict__ w1, const float* __restrict__ bias1,
    const float* __restrict__ w2, const float* __restrict__ bias2,
    const float* __restrict__ g2, const float* __restrict__ b2v,
    float* __restrict__ out)
{
  __shared__ __align__(16) char xb[32 * 256];
  __shared__ __align__(16) float stage[32 * 132];
  const int tid = threadIdx.x, lane = tid & 63, w = tid >> 6;
  const size_t pos0 = (size_t)blockIdx.x * 32;

  bf16x8 bf1[2][4], bf2v[2][4];
  #pragma unroll
  for (int cf = 0; cf < 2; ++cf)
    #pragma unroll
    for (int ks = 0; ks < 4; ++ks) {
      bf1[cf][ks]  = load_wfrag(w1, w * 32 + cf * 16, ks * 32, lane);
      bf2v[cf][ks] = load_wfrag(w2, w * 32 + cf * 16, ks * 32, lane);
    }

  #pragma unroll
  for (int q = 0; q < 2; ++q) {
    int s = q*256 + tid;
    int row = s >> 4, g = s & 15;
    int4 v = *(const int4*)(hnp + (pos0 + row)*128 + g*8);
    *(int4*)(xb + row*256 + (((g ^ (row & 7))) << 4)) = v;
  }
  __syncthreads();

  f32x4 acc[2][2];
  #pragma unroll
  for (int rf = 0; rf < 2; ++rf)
    #pragma unroll
    for (int cf = 0; cf < 2; ++cf) acc[rf][cf] = (f32x4){0.f,0.f,0.f,0.f};

  #pragma unroll
  for (int ks = 0; ks < 4; ++ks) {
    bf16x8 a0 = lds_afrag(xb, 0, ks * 32, lane);
    bf16x8 a1f = lds_afrag(xb, 16, ks * 32, lane);
    #pragma unroll
    for (int cf = 0; cf < 2; ++cf) {
      acc[0][cf] = __builtin_amdgcn_mfma_f32_16x16x32_bf16(a0,  bf1[cf][ks], acc[0][cf], 0, 0, 0);
      acc[1][cf] = __builtin_amdgcn_mfma_f32_16x16x32_bf16(a1f, bf1[cf][ks], acc[1][cf], 0, 0, 0);
    }
  }
  __syncthreads();

  const int lg = lane >> 4, lc = lane & 15;
  {
    float bc0 = bias1[w*32 + lc];
    float bc1 = bias1[w*32 + 16 + lc];
    #pragma unroll
    for (int rf = 0; rf < 2; ++rf)
      #pragma unroll
      for (int cf = 0; cf < 2; ++cf) {
        float bc = cf ? bc1 : bc0;
        #pragma unroll
        for (int r = 0; r < 4; ++r) {
          int row = rf*16 + 4*lg + r;
          int col = w*32 + cf*16 + lc;
          float s = acc[rf][cf][r] + bc;
          float u = s / (1.f + __expf(-s));
          int cbyte = col * 2;
          int byte = row * 256 + ((((cbyte >> 4) ^ (row & 7))) << 4) + (cbyte & 15);
          *(unsigned short*)(xb + byte) = f2bf(u);
        }
      }
  }
  __syncthreads();

  f32x4 acc2[2][2];
  #pragma unroll
  for (int rf = 0; rf < 2; ++rf)
    #pragma unroll
    for (int cf = 0; cf < 2; ++cf) acc2[rf][cf] = (f32x4){0.f,0.f,0.f,0.f};

  #pragma unroll
  for (int ks = 0; ks < 4; ++ks) {
    bf16x8 a0 = lds_afrag(xb, 0, ks * 32, lane);
    bf16x8 a1f = lds_afrag(xb, 16, ks * 32, lane);
    #pragma unroll
    for (int cf = 0; cf < 2; ++cf) {
      acc2[0][cf] = __builtin_amdgcn_mfma_f32_16x16x32_bf16(a0,  bf2v[cf][ks], acc2[0][cf], 0, 0, 0);
      acc2[1][cf] = __builtin_amdgcn_mfma_f32_16x16x32_bf16(a1f, bf2v[cf][ks], acc2[1][cf], 0, 0, 0);
    }
  }

  {
    float bc0 = bias2[w*32 + lc];
    float bc1 = bias2[w*32 + 16 + lc];
    #pragma unroll
    for (int rf = 0; rf < 2; ++rf)
      #pragma unroll
      for (int cf = 0; cf < 2; ++cf) {
        float bc = cf ? bc1 : bc0;
        #pragma unroll
        for (int r = 0; r < 4; ++r)
          stage[(rf*16 + 4*lg + r) * 132 + w*32 + cf*16 + lc] = acc2[rf][cf][r] + bc;
      }
  }
  __syncthreads();

  const float ga = g2[lane], gb = g2[64 + lane];
  const float ba = b2v[lane], bbv = b2v[64 + lane];
  for (int rr = 0; rr < 8; ++rr) {
    int row = w * 8 + rr;
    float y0 = stage[row * 132 + lane];
    float y1 = stage[row * 132 + 64 + lane];
    float r0 = bf2f(hnp[(pos0 + row) * 128 + lane]) + y0;
    float r1 = bf2f(hnp[(pos0 + row) * 128 + 64 + lane]) + y1;
    float s = r0 + r1, sq = r0*r0 + r1*r1;
    #pragma unroll
    for (int m = 1; m < 64; m <<= 1) { s += __shfl_xor(s, m); sq += __shfl_xor(sq, m); }
    float mu = s * (1.f/128.f);
    float var = sq * (1.f/128.f) - mu*mu;
    float rstd = rsqrtf(var + 1e-5f);
    out[(pos0 + row) * 128 + lane]      = (r0 - mu) * rstd * ga + ba;
    out[(pos0 + row) * 128 + 64 + lane] = (r1 - mu) * rstd * gb + bbv;
  }
}

extern "C" void kernel_launch(void* const* d_in, const int* in_sizes, int n_in,
                              void* d_out, int out_size, void* d_ws, size_t ws_size,
                              hipStream_t stream)
{
  const float* h    = (const float*)d_in[0];
  const void*  mask = d_in[1];
  const float* wa1  = (const float*)d_in[2];
  const float* wa2  = (const float*)d_in[3];
  const float* wv1  = (const float*)d_in[4];
  const float* wv2  = (const float*)d_in[5];
  const float* wo   = (const float*)d_in[6];
  const float* ln1s = (const float*)d_in[7];
  const float* ln1b = (const float*)d_in[8];
  const float* ln2s = (const float*)d_in[9];
  const float* ln2b = (const float*)d_in[10];
  const float* wu1  = (const float*)d_in[11];
  const float* bu1  = (const float*)d_in[12];
  const float* wu2  = (const float*)d_in[13];
  const float* bu2  = (const float*)d_in[14];

  char* ws = (char*)d_ws;
  const size_t MB = 1024*1024;
  unsigned short* vb1   = (unsigned short*)(ws + 0);        // 32 MB
  unsigned short* tbufT = (unsigned short*)(ws + 0);        // 35.7 MB (aliases vb1)
  unsigned short* vb2   = (unsigned short*)(ws + 36*MB);    // 32 MB
  unsigned short* hn    = (unsigned short*)(ws + 36*MB);    // 32 MB (aliases vb2)
  unsigned short* Bbuf  = (unsigned short*)(ws + 68*MB);    // 35.7 MB
  float* a1  = (float*)(ws + 104*MB);                       // 4 MB
  float* a2  = (float*)(ws + 108*MB);                       // 4 MB
  float* e2  = (float*)(ws + 112*MB);                       // 4 MB
  float* am1 = (float*)(ws + 116*MB);
  float* am2 = (float*)(ws + 116*MB + 16384);
  int*   flg = (int*)  (ws + 116*MB + 32768);
  unsigned short* Abuf = (unsigned short*)d_out;            // 35.7 MB in 64 MB out

  k_maskdetect<<<1, 256, 0, stream>>>((const unsigned char*)mask, flg);
  k_proj_mfma<<<4096, 256, 0, stream>>>(h, wa1, wa2, wv1, wv2, a1, a2, vb1, vb2);
  k_rowmax1<<<512, 64, 0, stream>>>(a1, am1);
  k_rowmax2<<<512, 64, 0, stream>>>(a2, am2);
  k_e<<<512, 256, 0, stream>>>(mask, flg, a1, a2, am1, am2, e2, Abuf);
  k_prep1<<<1024, 256, 0, stream>>>(vb1, Abuf);
  k_prep2<<<dim3(8,16,2), 256, 0, stream>>>(vb2, e2, Bbuf);
  k_tri_mfma<<<dim3(2,2,272), 256, 0, stream>>>(Abuf, Bbuf, tbufT);
  k_wo_ln_mfma<<<4096, 256, 0, stream>>>(tbufT, h, wo, ln1s, ln1b, hn);
  k_ffn_ln_mfma<<<4096, 256, 0, stream>>>(hn, wu1, bu1, wu2, bu2, ln2s, ln2b, (float*)d_out);
}

// Round 4
// 316.525 us; speedup vs baseline: 12.0580x; 1.1016x over previous
//
#include <hip/hip_runtime.h>

#define B_ 2
#define N_ 256
#define C_ 128
#define H_ 8

typedef __attribute__((ext_vector_type(8))) short bf16x8;
typedef __attribute__((ext_vector_type(8))) unsigned short u16x8;
typedef __attribute__((ext_vector_type(4))) float f32x4;

__device__ __forceinline__ unsigned short f2bf(float f) {
  unsigned int u = __float_as_uint(f);
  unsigned int r = (u + 0x7FFFu + ((u >> 16) & 1u)) >> 16;
  return (unsigned short)r;
}
__device__ __forceinline__ float bf2f(unsigned short u) {
  return __uint_as_float(((unsigned int)u) << 16);
}

// B-fragment (16 rows x 32 k) from row-major f32 weight matrix [R][128]
__device__ __forceinline__ bf16x8 load_wfrag(const float* __restrict__ W,
                                             int row0, int k0, int lane) {
  const float* p = W + (size_t)(row0 + (lane & 15)) * 128 + k0 + 8 * (lane >> 4);
  float4 x = *(const float4*)p;
  float4 y = *(const float4*)(p + 4);
  bf16x8 f;
  f[0] = (short)f2bf(x.x); f[1] = (short)f2bf(x.y);
  f[2] = (short)f2bf(x.z); f[3] = (short)f2bf(x.w);
  f[4] = (short)f2bf(y.x); f[5] = (short)f2bf(y.y);
  f[6] = (short)f2bf(y.z); f[7] = (short)f2bf(y.w);
  return f;
}

// A-fragment from XOR-swizzled bf16 LDS tile [32 rows][128 cols] (256 B/row)
__device__ __forceinline__ bf16x8 lds_afrag(const char* base, int row0, int k0, int lane) {
  int row = row0 + (lane & 15);
  int cb = (k0 + 8 * (lane >> 4)) * 2;
  int byte = row * 256 + ((((cb >> 4) ^ (row & 7))) << 4);
  return *(const bf16x8*)(base + byte);
}

__device__ __forceinline__ void lds_store4bf(char* base, int row, int cbyte,
                                             float a, float b, float c, float d) {
  int byte = row * 256 + ((((cbyte >> 4) ^ (row & 7))) << 4) + (cbyte & 15);
  ushort4 o4;
  o4.x = f2bf(a); o4.y = f2bf(b); o4.z = f2bf(c); o4.w = f2bf(d);
  *(ushort4*)(base + byte) = o4;
}

// ---------------- K0: mask dtype detection (parallel) ----------------
// Reads first 131072 bytes (safe for uint8 and int32 layouts) as 32768 uints.
__global__ __launch_bounds__(256) void k_maskpart(const unsigned int* __restrict__ m4,
                                                  int* __restrict__ part)
{
  __shared__ int red[4];
  const int tid = threadIdx.x;
  unsigned int v = m4[blockIdx.x * 256 + tid];
  int cnt = ((v & 0xFFu) != 0) + (((v >> 8) & 0xFFu) != 0) +
            (((v >> 16) & 0xFFu) != 0) + ((v >> 24) != 0);
  #pragma unroll
  for (int m = 1; m < 64; m <<= 1) cnt += __shfl_xor(cnt, m);
  if ((tid & 63) == 0) red[tid >> 6] = cnt;
  __syncthreads();
  if (tid == 0) part[blockIdx.x] = red[0] + red[1] + red[2] + red[3];
}

__global__ __launch_bounds__(128) void k_maskred(const int* __restrict__ part,
                                                 int* __restrict__ flag)
{
  const int tid = threadIdx.x;
  int v = part[tid];
  #pragma unroll
  for (int m = 1; m < 64; m <<= 1) v += __shfl_xor(v, m);
  __shared__ int red[2];
  if ((tid & 63) == 0) red[tid >> 6] = v;
  __syncthreads();
  if (tid == 0) *flag = ((red[0] + red[1]) > 7864) ? 1 : 0;  // 1 = uint8 layout
}

// ---------------- K1: fused projections via MFMA (v out = bf16) ----------------
__global__ __launch_bounds__(256) void k_proj_mfma(
    const float* __restrict__ h,
    const float* __restrict__ wa1, const float* __restrict__ wa2,
    const float* __restrict__ wv1, const float* __restrict__ wv2,
    float* __restrict__ a1, float* __restrict__ a2,
    unsigned short* __restrict__ v1, unsigned short* __restrict__ v2)
{
  __shared__ __align__(16) char hb[32 * 256];    // 8192  bf16 swizzled h tile
  __shared__ __align__(16) char st1[32 * 272];   // 8704  v1 bf16 stage [32][136]
  __shared__ __align__(16) char st2[32 * 272];   // 8704  v2 bf16 stage
  const int tid = threadIdx.x, lane = tid & 63, w = tid >> 6;
  const size_t pos0 = (size_t)blockIdx.x * 32;

  const float* wv = (w < 2) ? wv1 : wv2;
  const int colbase = (w & 1) * 64;
  bf16x8 bfr[4][4];
  #pragma unroll
  for (int cf = 0; cf < 4; ++cf)
    #pragma unroll
    for (int ks = 0; ks < 4; ++ks)
      bfr[cf][ks] = load_wfrag(wv, colbase + cf * 16, ks * 32, lane);

  bf16x8 af[4];
  if (w == 0) {
    int r = lane & 15;
    const float* ar = (r < 8) ? (wa1 + (size_t)r * 128) : (wa2 + (size_t)(r - 8) * 128);
    #pragma unroll
    for (int ks = 0; ks < 4; ++ks) {
      const float* p = ar + ks * 32 + 8 * (lane >> 4);
      float4 x = *(const float4*)p;
      float4 y = *(const float4*)(p + 4);
      bf16x8 f;
      f[0]=(short)f2bf(x.x); f[1]=(short)f2bf(x.y); f[2]=(short)f2bf(x.z); f[3]=(short)f2bf(x.w);
      f[4]=(short)f2bf(y.x); f[5]=(short)f2bf(y.y); f[6]=(short)f2bf(y.z); f[7]=(short)f2bf(y.w);
      af[ks] = f;
    }
  }

  {
    const float4* hg4 = (const float4*)(h + pos0 * 128);
    #pragma unroll
    for (int q = 0; q < 4; ++q) {
      int f4i = tid + 256 * q;
      float4 x = hg4[f4i];
      lds_store4bf(hb, f4i >> 5, (f4i & 31) * 8, x.x, x.y, x.z, x.w);
    }
  }
  __syncthreads();

  f32x4 acc[2][4];
  #pragma unroll
  for (int rf = 0; rf < 2; ++rf)
    #pragma unroll
    for (int cf = 0; cf < 4; ++cf) acc[rf][cf] = (f32x4){0.f,0.f,0.f,0.f};
  f32x4 acca[2]; acca[0] = (f32x4){0.f,0.f,0.f,0.f}; acca[1] = acca[0];

  #pragma unroll
  for (int ks = 0; ks < 4; ++ks) {
    bf16x8 a0 = lds_afrag(hb, 0, ks * 32, lane);
    bf16x8 a1f = lds_afrag(hb, 16, ks * 32, lane);
    #pragma unroll
    for (int cf = 0; cf < 4; ++cf) {
      acc[0][cf] = __builtin_amdgcn_mfma_f32_16x16x32_bf16(a0,  bfr[cf][ks], acc[0][cf], 0, 0, 0);
      acc[1][cf] = __builtin_amdgcn_mfma_f32_16x16x32_bf16(a1f, bfr[cf][ks], acc[1][cf], 0, 0, 0);
    }
    if (w == 0) {
      acca[0] = __builtin_amdgcn_mfma_f32_16x16x32_bf16(a0,  af[ks], acca[0], 0, 0, 0);
      acca[1] = __builtin_amdgcn_mfma_f32_16x16x32_bf16(a1f, af[ks], acca[1], 0, 0, 0);
    }
  }

  const int lg = lane >> 4, lc = lane & 15;
  {
    char* st = (w < 2) ? st1 : st2;
    #pragma unroll
    for (int rf = 0; rf < 2; ++rf)
      #pragma unroll
      for (int cf = 0; cf < 4; ++cf)
        #pragma unroll
        for (int r = 0; r < 4; ++r) {
          int row = rf*16 + 4*lg + r;
          int col = colbase + cf*16 + lc;
          *(unsigned short*)(st + row*272 + col*2) = f2bf(acc[rf][cf][r]);
        }
  }
  if (w == 0) {
    #pragma unroll
    for (int rf = 0; rf < 2; ++rf)
      #pragma unroll
      for (int r = 0; r < 4; ++r) {
        int row = rf*16 + 4*lg + r;
        float val = acca[rf][r];
        if (lc < 8) a1[(pos0 + row) * 8 + lc] = val;
        else        a2[(pos0 + row) * 8 + (lc - 8)] = val;
      }
  }
  __syncthreads();

  #pragma unroll
  for (int q = 0; q < 2; ++q) {
    int s = q*256 + tid;
    int row = s >> 4, seg = s & 15;
    int4 o1 = *(const int4*)(st1 + row*272 + seg*16);
    *(int4*)(v1 + (pos0 + row)*128 + seg*8) = o1;
    int4 o2 = *(const int4*)(st2 + row*272 + seg*16);
    *(int4*)(v2 + (pos0 + row)*128 + seg*8) = o2;
  }
}

// ---------------- K2a/K2b: row maxes ----------------
__global__ __launch_bounds__(64) void k_rowmax1(const float* __restrict__ a1,
                                                float* __restrict__ amax1)
{
  const int bi = blockIdx.x;
  const int t = threadIdx.x;
  const float* base = a1 + (size_t)bi * N_ * 8;
  float m = -1e30f;
  #pragma unroll 8
  for (int k = 0; k < 32; ++k) m = fmaxf(m, base[t + 64*k]);
  m = fmaxf(m, __shfl_xor(m, 8));
  m = fmaxf(m, __shfl_xor(m, 16));
  m = fmaxf(m, __shfl_xor(m, 32));
  if (t < 8) amax1[bi*8 + t] = m;
}

__global__ __launch_bounds__(64) void k_rowmax2(const float* __restrict__ a2,
                                                float* __restrict__ amax2)
{
  const int bj = blockIdx.x;
  const int b = bj >> 8, j = bj & 255;
  const int t = threadIdx.x;
  const int hh = t & 7, igrp = t >> 3;
  float m = -1e30f;
  for (int k = 0; k < 32; ++k) {
    int i = igrp + 8*k;
    m = fmaxf(m, a2[((size_t)(b*N_ + i)*N_ + j)*8 + hh]);
  }
  m = fmaxf(m, __shfl_xor(m, 8));
  m = fmaxf(m, __shfl_xor(m, 16));
  m = fmaxf(m, __shfl_xor(m, 32));
  if (t < 8) amax2[bj*8 + t] = m;
}

// ---------------- K3: exp (masked); e2 f32 natural; eb1 bf16 -> Abuf ch128+ ----------------
__global__ __launch_bounds__(256) void k_e(
    const void* __restrict__ maskraw, const int* __restrict__ modep,
    const float* __restrict__ a1, const float* __restrict__ a2,
    const float* __restrict__ am1, const float* __restrict__ am2,
    float* __restrict__ e2out, unsigned short* __restrict__ Abuf)
{
  __shared__ unsigned short eb[8 * 256];   // [h][p] bf16
  const int tid = threadIdx.x;
  const size_t pos0 = (size_t)blockIdx.x * 256;
  const size_t p = pos0 + tid;
  const int b = (int)(p >> 16), ij = (int)(p & 65535);
  const int i = ij >> 8, j = ij & 255;
  const int msk = modep[0] ? (int)((const unsigned char*)maskraw)[p]
                           : ((const int*)maskraw)[p];
  float4 x0 = *(const float4*)(a1 + p*8);
  float4 x1 = *(const float4*)(a1 + p*8 + 4);
  float4 m0 = *(const float4*)(am1 + ((size_t)(b*256 + i))*8);
  float4 m1 = *(const float4*)(am1 + ((size_t)(b*256 + i))*8 + 4);
  eb[0*256 + tid] = msk ? 0 : f2bf(__expf(x0.x - m0.x));
  eb[1*256 + tid] = msk ? 0 : f2bf(__expf(x0.y - m0.y));
  eb[2*256 + tid] = msk ? 0 : f2bf(__expf(x0.z - m0.z));
  eb[3*256 + tid] = msk ? 0 : f2bf(__expf(x0.w - m0.w));
  eb[4*256 + tid] = msk ? 0 : f2bf(__expf(x1.x - m1.x));
  eb[5*256 + tid] = msk ? 0 : f2bf(__expf(x1.y - m1.y));
  eb[6*256 + tid] = msk ? 0 : f2bf(__expf(x1.z - m1.z));
  eb[7*256 + tid] = msk ? 0 : f2bf(__expf(x1.w - m1.w));

  float4 y0 = *(const float4*)(a2 + p*8);
  float4 y1 = *(const float4*)(a2 + p*8 + 4);
  float4 n0 = *(const float4*)(am2 + ((size_t)(b*256 + j))*8);
  float4 n1 = *(const float4*)(am2 + ((size_t)(b*256 + j))*8 + 4);
  float4 o0, o1;
  o0.x = msk ? 0.f : __expf(y0.x - n0.x);
  o0.y = msk ? 0.f : __expf(y0.y - n0.y);
  o0.z = msk ? 0.f : __expf(y0.z - n0.z);
  o0.w = msk ? 0.f : __expf(y0.w - n0.w);
  o1.x = msk ? 0.f : __expf(y1.x - n1.x);
  o1.y = msk ? 0.f : __expf(y1.y - n1.y);
  o1.z = msk ? 0.f : __expf(y1.z - n1.z);
  o1.w = msk ? 0.f : __expf(y1.w - n1.w);
  *(float4*)(e2out + p*8) = o0;
  *(float4*)(e2out + p*8 + 4) = o1;

  __syncthreads();
  {
    int hh = tid >> 5, seg = tid & 31;
    int4 v = *(const int4*)((const char*)eb + hh*512 + seg*16);
    *(int4*)(Abuf + (((size_t)(b*136 + 128 + hh)) << 16) + (int)(pos0 & 65535) + seg*8) = v;
  }
}

// ---------------- K4a: pc1[c][i][l] = vb1[pos][c] * e1 (channel transpose) ----------------
__global__ __launch_bounds__(256) void k_prep1(
    const unsigned short* __restrict__ vb1, unsigned short* __restrict__ Abuf)
{
  __shared__ __align__(16) char lds[36864];  // xt [128][272B] + et [8][256B]
  char* xt = lds;
  unsigned short* et = (unsigned short*)(lds + 34816);
  const int tid = threadIdx.x;
  const size_t pos0 = (size_t)blockIdx.x * 128;
  const int b = (int)(pos0 >> 16);
  const int posl0 = (int)(pos0 & 65535);

  if (tid < 128) {
    int hh = tid >> 4, seg = tid & 15;
    int4 v = *(const int4*)(Abuf + (((size_t)(b*136 + 128 + hh)) << 16) + posl0 + seg*8);
    *(int4*)((char*)et + hh*256 + seg*16) = v;
  }
  #pragma unroll
  for (int q = 0; q < 8; ++q) {
    int s = q*256 + tid;
    int rec = s >> 4, g = s & 15;
    int4 v = *(const int4*)(vb1 + (pos0 + rec)*128 + g*8);
    *(int4*)(xt + rec*272 + g*16) = v;
  }
  __syncthreads();
  #pragma unroll
  for (int q = 0; q < 8; ++q) {
    int c = q*16 + (tid & 15);
    int pg = tid >> 4;
    int hh = c >> 4;
    u16x8 t;
    #pragma unroll
    for (int k = 0; k < 8; ++k) {
      int p = pg*8 + k;
      float xv = bf2f(*(const unsigned short*)(xt + p*272 + c*2));
      float ev = bf2f(et[hh*128 + p]);
      t[k] = f2bf(xv * ev);
    }
    *(int4*)(Abuf + (((size_t)(b*136 + c)) << 16) + posl0 + pg*8) = *(int4*)&t;
  }
}

// ---------------- K4b: pc2t[c][j][l] = vb2[(l,j)][c]*e2 ; eb2t[h][j][l] ----------------
__global__ __launch_bounds__(256) void k_prep2(
    const unsigned short* __restrict__ vb2, const float* __restrict__ e2,
    unsigned short* __restrict__ Bbuf)
{
  __shared__ __align__(16) char lds[49152];  // vt [512][80B] + et [512][16B]
  char* vt = lds;
  unsigned short* et = (unsigned short*)(lds + 40960);  // [rec][8 h] bf16
  const int tid = threadIdx.x;
  const int lt = blockIdx.x, jt = blockIdx.y, b = blockIdx.z;
  const int l0 = lt*32, j0 = jt*16;

  #pragma unroll
  for (int q = 0; q < 4; ++q) {
    int s = q*256 + tid;
    int rec = s >> 1, hf = (s & 1)*4;
    int l = rec >> 4, j = rec & 15;
    size_t pos = ((size_t)b << 16) + (size_t)(l0 + l)*256 + (j0 + j);
    float4 ev = *(const float4*)(e2 + pos*8 + hf);
    ushort4 o; o.x = f2bf(ev.x); o.y = f2bf(ev.y); o.z = f2bf(ev.z); o.w = f2bf(ev.w);
    *(ushort4*)(et + rec*8 + hf) = o;
  }

  for (int cw = 0; cw < 4; ++cw) {
    __syncthreads();
    #pragma unroll
    for (int q = 0; q < 8; ++q) {
      int s = q*256 + tid;
      int rec = s >> 2, g = s & 3;
      int l = rec >> 4, j = rec & 15;
      size_t pos = ((size_t)b << 16) + (size_t)(l0 + l)*256 + (j0 + j);
      int4 v = *(const int4*)(vb2 + pos*128 + cw*32 + g*8);
      *(int4*)(vt + rec*80 + g*16) = v;
    }
    __syncthreads();
    #pragma unroll
    for (int q = 0; q < 8; ++q) {
      int loff = tid & 3, j = (tid >> 2) & 15, cs = tid >> 6;
      int cl = q*4 + cs;
      int c = cw*32 + cl;
      int hh = c >> 4;
      u16x8 t;
      #pragma unroll
      for (int k = 0; k < 8; ++k) {
        int l = loff*8 + k;
        int rec = l*16 + j;
        float xv = bf2f(*(const unsigned short*)(vt + rec*80 + cl*2));
        float ev = bf2f(et[rec*8 + hh]);
        t[k] = f2bf(xv * ev);
      }
      *(int4*)(Bbuf + (((size_t)(b*136 + c)) << 16) + (size_t)(j0 + j)*256 + l0 + loff*8) = *(int4*)&t;
    }
  }
  __syncthreads();
  #pragma unroll
  for (int q = 0; q < 2; ++q) {
    int s = q*256 + tid;
    int loff = s & 3, j = (s >> 2) & 15, hh = s >> 6;
    u16x8 t;
    #pragma unroll
    for (int k = 0; k < 8; ++k) {
      int l = loff*8 + k;
      int rec = l*16 + j;
      t[k] = et[rec*8 + hh];
    }
    *(int4*)(Bbuf + (((size_t)(b*136 + 128 + hh)) << 16) + (size_t)(j0 + j)*256 + l0 + loff*8) = *(int4*)&t;
  }
}

// ---------------- K5: batched 256^3 GEMM over 272 channels (tri + denom) ----------------
__global__ __launch_bounds__(256) void k_tri_mfma(
    const unsigned short* __restrict__ Ab, const unsigned short* __restrict__ Bb,
    unsigned short* __restrict__ outT)
{
  __shared__ __align__(16) char lds[34816];
  char* lA = lds;
  char* lB = lds + 10240;
  const int tid = threadIdx.x, lane = tid & 63, w = tid >> 6;
  const int jt = blockIdx.x, it = blockIdx.y, z = blockIdx.z;
  const int b = z / 136, ch = z - b*136;
  const size_t mbase = ((size_t)(b*136 + ch)) << 16;
  const int i0 = it*128, j0 = jt*128;
  const int r4 = tid >> 2, g4 = tid & 3;

  const unsigned short* gA0 = Ab + mbase + (size_t)(i0 + r4)*256 + g4*8;
  const unsigned short* gA1 = gA0 + 64*256;
  const unsigned short* gB0 = Bb + mbase + (size_t)(j0 + r4)*256 + g4*8;
  const unsigned short* gB1 = gB0 + 64*256;
  char* sA0 = lA + r4*80 + g4*16;
  char* sA1 = sA0 + 64*80;
  char* sB0 = lB + r4*80 + g4*16;
  char* sB1 = sB0 + 64*80;

  const int wr = w >> 1, wc = w & 1;
  const char* fA = lA + (wr*64 + (lane & 15))*80 + (lane >> 4)*16;
  const char* fB = lB + (wc*64 + (lane & 15))*80 + (lane >> 4)*16;

  f32x4 acc[4][4];
  #pragma unroll
  for (int rf = 0; rf < 4; ++rf)
    #pragma unroll
    for (int cf = 0; cf < 4; ++cf) acc[rf][cf] = (f32x4){0.f,0.f,0.f,0.f};

  int4 ra0 = *(const int4*)gA0;
  int4 ra1 = *(const int4*)gA1;
  int4 rb0 = *(const int4*)gB0;
  int4 rb1 = *(const int4*)gB1;

  for (int ks = 0; ks < 8; ++ks) {
    __syncthreads();
    *(int4*)sA0 = ra0; *(int4*)sA1 = ra1;
    *(int4*)sB0 = rb0; *(int4*)sB1 = rb1;
    __syncthreads();
    if (ks < 7) {
      const int off = (ks + 1)*32;
      ra0 = *(const int4*)(gA0 + off);
      ra1 = *(const int4*)(gA1 + off);
      rb0 = *(const int4*)(gB0 + off);
      rb1 = *(const int4*)(gB1 + off);
    }
    bf16x8 af[4], bfv[4];
    #pragma unroll
    for (int rf = 0; rf < 4; ++rf) af[rf] = *(const bf16x8*)(fA + rf*16*80);
    #pragma unroll
    for (int cf = 0; cf < 4; ++cf) bfv[cf] = *(const bf16x8*)(fB + cf*16*80);
    #pragma unroll
    for (int rf = 0; rf < 4; ++rf)
      #pragma unroll
      for (int cf = 0; cf < 4; ++cf)
        acc[rf][cf] = __builtin_amdgcn_mfma_f32_16x16x32_bf16(af[rf], bfv[cf], acc[rf][cf], 0, 0, 0);
  }

  __syncthreads();
  #pragma unroll
  for (int rf = 0; rf < 4; ++rf)
    #pragma unroll
    for (int cf = 0; cf < 4; ++cf)
      #pragma unroll
      for (int r = 0; r < 4; ++r) {
        int il = wr*64 + rf*16 + 4*(lane >> 4) + r;
        int jl = wc*64 + cf*16 + (lane & 15);
        *(unsigned short*)(lds + il*272 + jl*2) = f2bf(acc[rf][cf][r]);
      }
  __syncthreads();
  #pragma unroll
  for (int q = 0; q < 8; ++q) {
    int row = q*16 + (tid >> 4), seg = tid & 15;
    int4 v = *(const int4*)(lds + row*272 + seg*16);
    *(int4*)(outT + mbase + (size_t)(i0 + row)*256 + j0 + seg*8) = v;
  }
}

// ---------------- K6: x = t/denom ; y = x@wo^T ; hn = bf16(LN1(h + y)) ----------------
__global__ __launch_bounds__(256) void k_wo_ln_mfma(
    const unsigned short* __restrict__ tT,
    const float* __restrict__ h, const float* __restrict__ wo,
    const float* __restrict__ g1, const float* __restrict__ bb1,
    unsigned short* __restrict__ hn)
{
  __shared__ __align__(16) char xb[32 * 256];
  __shared__ __align__(16) float stage[32 * 132];
  const int tid = threadIdx.x, lane = tid & 63, w = tid >> 6;
  const size_t pos0 = (size_t)blockIdx.x * 32;
  const int b = (int)(pos0 >> 16);
  const int posl0 = (int)(pos0 & 65535);

  bf16x8 bfr[2][4];
  #pragma unroll
  for (int cf = 0; cf < 2; ++cf)
    #pragma unroll
    for (int ks = 0; ks < 4; ++ks)
      bfr[cf][ks] = load_wfrag(wo, w * 32 + cf * 16, ks * 32, lane);

  #pragma unroll
  for (int it2 = 0; it2 < 2; ++it2) {
    int c = it2*64 + (tid >> 2);
    int poff = (tid & 3)*8;
    u16x8 tv = *(const u16x8*)(tT + (((size_t)(b*136 + c)) << 16) + posl0 + poff);
    u16x8 dv = *(const u16x8*)(tT + (((size_t)(b*136 + 128 + (c >> 4))) << 16) + posl0 + poff);
    int cb = c*2;
    #pragma unroll
    for (int k = 0; k < 8; ++k) {
      float x = bf2f(tv[k]) / (bf2f(dv[k]) + 1e-6f);
      int p = poff + k;
      int byte = p*256 + ((((cb >> 4) ^ (p & 7))) << 4) + (cb & 15);
      *(unsigned short*)(xb + byte) = f2bf(x);
    }
  }
  __syncthreads();

  f32x4 acc[2][2];
  #pragma unroll
  for (int rf = 0; rf < 2; ++rf)
    #pragma unroll
    for (int cf = 0; cf < 2; ++cf) acc[rf][cf] = (f32x4){0.f,0.f,0.f,0.f};

  #pragma unroll
  for (int ks = 0; ks < 4; ++ks) {
    bf16x8 a0 = lds_afrag(xb, 0, ks * 32, lane);
    bf16x8 a1f = lds_afrag(xb, 16, ks * 32, lane);
    #pragma unroll
    for (int cf = 0; cf < 2; ++cf) {
      acc[0][cf] = __builtin_amdgcn_mfma_f32_16x16x32_bf16(a0,  bfr[cf][ks], acc[0][cf], 0, 0, 0);
      acc[1][cf] = __builtin_amdgcn_mfma_f32_16x16x32_bf16(a1f, bfr[cf][ks], acc[1][cf], 0, 0, 0);
    }
  }

  const int lg = lane >> 4, lc = lane & 15;
  #pragma unroll
  for (int rf = 0; rf < 2; ++rf)
    #pragma unroll
    for (int cf = 0; cf < 2; ++cf)
      #pragma unroll
      for (int r = 0; r < 4; ++r)
        stage[(rf*16 + 4*lg + r) * 132 + w*32 + cf*16 + lc] = acc[rf][cf][r];
  __syncthreads();

  const float ga = g1[lane], gb = g1[64 + lane];
  const float ba = bb1[lane], bbv = bb1[64 + lane];
  for (int rr = 0; rr < 8; ++rr) {
    int row = w * 8 + rr;
    float y0 = stage[row * 132 + lane];
    float y1 = stage[row * 132 + 64 + lane];
    float r0 = h[(pos0 + row) * 128 + lane] + y0;
    float r1 = h[(pos0 + row) * 128 + 64 + lane] + y1;
    float s = r0 + r1, sq = r0*r0 + r1*r1;
    #pragma unroll
    for (int m = 1; m < 64; m <<= 1) { s += __shfl_xor(s, m); sq += __shfl_xor(sq, m); }
    float mu = s * (1.f/128.f);
    float var = sq * (1.f/128.f) - mu*mu;
    float rstd = rsqrtf(var + 1e-5f);
    hn[(pos0 + row) * 128 + lane]      = f2bf((r0 - mu) * rstd * ga + ba);
    hn[(pos0 + row) * 128 + 64 + lane] = f2bf((r1 - mu) * rstd * gb + bbv);
  }
}

// ---------------- K7: FFN(silu) + residual + LN2 -> out (hn bf16 in) ----------------
__global__ __launch_bounds__(256) void k_ffn_ln_mfma(
    const unsigned short* __restrict__ hnp,
    const float* __restrict__ w1, const float* __restrict__ bias1,
    const float* __restrict__ w2, const float* __restrict__ bias2,
    const float* __restrict__ g2, const float* __restrict__ b2v,
    float* __restrict__ out)
{
  __shared__ __align__(16) char xb[32 * 256];
  __shared__ __align__(16) float stage[32 * 132];
  const int tid = threadIdx.x, lane = tid & 63, w = tid >> 6;
  const size_t pos0 = (size_t)blockIdx.x * 32;

  bf16x8 bf1[2][4], bf2v[2][4];
  #pragma unroll
  for (int cf = 0; cf < 2; ++cf)
    #pragma unroll
    for (int ks = 0; ks < 4; ++ks) {
      bf1[cf][ks]  = load_wfrag(w1, w * 32 + cf * 16, ks * 32, lane);
      bf2v[cf][ks] = load_wfrag(w2, w * 32 + cf * 16, ks * 32, lane);
    }

  #pragma unroll
  for (int q = 0; q < 2; ++q) {
    int s = q*256 + tid;
    int row = s >> 4, g = s & 15;
    int4 v = *(const int4*)(hnp + (pos0 + row)*128 + g*8);
    *(int4*)(xb + row*256 + (((g ^ (row & 7))) << 4)) = v;
  }
  __syncthreads();

  f32x4 acc[2][2];
  #pragma unroll
  for (int rf = 0; rf < 2; ++rf)
    #pragma unroll
    for (int cf = 0; cf < 2; ++cf) acc[rf][cf] = (f32x4){0.f,0.f,0.f,0.f};

  #pragma unroll
  for (int ks = 0; ks < 4; ++ks) {
    bf16x8 a0 = lds_afrag(xb, 0, ks * 32, lane);
    bf16x8 a1f = lds_afrag(xb, 16, ks * 32, lane);
    #pragma unroll
    for (int cf = 0; cf < 2; ++cf) {
      acc[0][cf] = __builtin_amdgcn_mfma_f32_16x16x32_bf16(a0,  bf1[cf][ks], acc[0][cf], 0, 0, 0);
      acc[1][cf] = __builtin_amdgcn_mfma_f32_16x16x32_bf16(a1f, bf1[cf][ks], acc[1][cf], 0, 0, 0);
    }
  }
  __syncthreads();

  const int lg = lane >> 4, lc = lane & 15;
  {
    float bc0 = bias1[w*32 + lc];
    float bc1 = bias1[w*32 + 16 + lc];
    #pragma unroll
    for (int rf = 0; rf < 2; ++rf)
      #pragma unroll
      for (int cf = 0; cf < 2; ++cf) {
        float bc = cf ? bc1 : bc0;
        #pragma unroll
        for (int r = 0; r < 4; ++r) {
          int row = rf*16 + 4*lg + r;
          int col = w*32 + cf*16 + lc;
          float s = acc[rf][cf][r] + bc;
          float u = s / (1.f + __expf(-s));
          int cbyte = col * 2;
          int byte = row * 256 + ((((cbyte >> 4) ^ (row & 7))) << 4) + (cbyte & 15);
          *(unsigned short*)(xb + byte) = f2bf(u);
        }
      }
  }
  __syncthreads();

  f32x4 acc2[2][2];
  #pragma unroll
  for (int rf = 0; rf < 2; ++rf)
    #pragma unroll
    for (int cf = 0; cf < 2; ++cf) acc2[rf][cf] = (f32x4){0.f,0.f,0.f,0.f};

  #pragma unroll
  for (int ks = 0; ks < 4; ++ks) {
    bf16x8 a0 = lds_afrag(xb, 0, ks * 32, lane);
    bf16x8 a1f = lds_afrag(xb, 16, ks * 32, lane);
    #pragma unroll
    for (int cf = 0; cf < 2; ++cf) {
      acc2[0][cf] = __builtin_amdgcn_mfma_f32_16x16x32_bf16(a0,  bf2v[cf][ks], acc2[0][cf], 0, 0, 0);
      acc2[1][cf] = __builtin_amdgcn_mfma_f32_16x16x32_bf16(a1f, bf2v[cf][ks], acc2[1][cf], 0, 0, 0);
    }
  }

  {
    float bc0 = bias2[w*32 + lc];
    float bc1 = bias2[w*32 + 16 + lc];
    #pragma unroll
    for (int rf = 0; rf < 2; ++rf)
      #pragma unroll
      for (int cf = 0; cf < 2; ++cf) {
        float bc = cf ? bc1 : bc0;
        #pragma unroll
        for (int r = 0; r < 4; ++r)
          stage[(rf*16 + 4*lg + r) * 132 + w*32 + cf*16 + lc] = acc2[rf][cf][r] + bc;
      }
  }
  __syncthreads();

  const float ga = g2[lane], gb = g2[64 + lane];
  const float ba = b2v[lane], bbv = b2v[64 + lane];
  for (int rr = 0; rr < 8; ++rr) {
    int row = w * 8 + rr;
    float y0 = stage[row * 132 + lane];
    float y1 = stage[row * 132 + 64 + lane];
    float r0 = bf2f(hnp[(pos0 + row) * 128 + lane]) + y0;
    float r1 = bf2f(hnp[(pos0 + row) * 128 + 64 + lane]) + y1;
    float s = r0 + r1, sq = r0*r0 + r1*r1;
    #pragma unroll
    for (int m = 1; m < 64; m <<= 1) { s += __shfl_xor(s, m); sq += __shfl_xor(sq, m); }
    float mu = s * (1.f/128.f);
    float var = sq * (1.f/128.f) - mu*mu;
    float rstd = rsqrtf(var + 1e-5f);
    out[(pos0 + row) * 128 + lane]      = (r0 - mu) * rstd * ga + ba;
    out[(pos0 + row) * 128 + 64 + lane] = (r1 - mu) * rstd * gb + bbv;
  }
}

extern "C" void kernel_launch(void* const* d_in, const int* in_sizes, int n_in,
                              void* d_out, int out_size, void* d_ws, size_t ws_size,
                              hipStream_t stream)
{
  const float* h    = (const float*)d_in[0];
  const void*  mask = d_in[1];
  const float* wa1  = (const float*)d_in[2];
  const float* wa2  = (const float*)d_in[3];
  const float* wv1  = (const float*)d_in[4];
  const float* wv2  = (const float*)d_in[5];
  const float* wo   = (const float*)d_in[6];
  const float* ln1s = (const float*)d_in[7];
  const float* ln1b = (const float*)d_in[8];
  const float* ln2s = (const float*)d_in[9];
  const float* ln2b = (const float*)d_in[10];
  const float* wu1  = (const float*)d_in[11];
  const float* bu1  = (const float*)d_in[12];
  const float* wu2  = (const float*)d_in[13];
  const float* bu2  = (const float*)d_in[14];

  char* ws = (char*)d_ws;
  const size_t MB = 1024*1024;
  unsigned short* vb1   = (unsigned short*)(ws + 0);        // 32 MB
  unsigned short* tbufT = (unsigned short*)(ws + 0);        // 35.7 MB (aliases vb1)
  unsigned short* vb2   = (unsigned short*)(ws + 36*MB);    // 32 MB
  unsigned short* hn    = (unsigned short*)(ws + 36*MB);    // 32 MB (aliases vb2)
  unsigned short* Bbuf  = (unsigned short*)(ws + 68*MB);    // 35.7 MB
  float* a1  = (float*)(ws + 104*MB);                       // 4 MB
  float* a2  = (float*)(ws + 108*MB);                       // 4 MB
  float* e2  = (float*)(ws + 112*MB);                       // 4 MB
  float* am1 = (float*)(ws + 116*MB);
  float* am2 = (float*)(ws + 116*MB + 16384);
  int*   flg = (int*)  (ws + 116*MB + 32768);
  int*   part= (int*)  (ws + 116*MB + 65536);               // 128 ints
  unsigned short* Abuf = (unsigned short*)d_out;            // 35.7 MB in 64 MB out

  k_maskpart<<<128, 256, 0, stream>>>((const unsigned int*)mask, part);
  k_maskred<<<1, 128, 0, stream>>>(part, flg);
  k_proj_mfma<<<4096, 256, 0, stream>>>(h, wa1, wa2, wv1, wv2, a1, a2, vb1, vb2);
  k_rowmax1<<<512, 64, 0, stream>>>(a1, am1);
  k_rowmax2<<<512, 64, 0, stream>>>(a2, am2);
  k_e<<<512, 256, 0, stream>>>(mask, flg, a1, a2, am1, am2, e2, Abuf);
  k_prep1<<<1024, 256, 0, stream>>>(vb1, Abuf);
  k_prep2<<<dim3(8,16,2), 256, 0, stream>>>(vb2, e2, Bbuf);
  k_tri_mfma<<<dim3(2,2,272), 256, 0, stream>>>(Abuf, Bbuf, tbufT);
  k_wo_ln_mfma<<<4096, 256, 0, stream>>>(tbufT, h, wo, ln1s, ln1b, hn);
  k_ffn_ln_mfma<<<4096, 256, 0, stream>>>(hn, wu1, bu1, wu2, bu2, ln2s, ln2b, (float*)d_out);
}

// Round 5
// 268.664 us; speedup vs baseline: 14.2060x; 1.1781x over previous
//
#include <hip/hip_runtime.h>

#define B_ 2
#define N_ 256
#define C_ 128
#define H_ 8

typedef __attribute__((ext_vector_type(8))) short bf16x8;
typedef __attribute__((ext_vector_type(8))) unsigned short u16x8;
typedef __attribute__((ext_vector_type(4))) float f32x4;

__device__ __forceinline__ unsigned short f2bf(float f) {
  unsigned int u = __float_as_uint(f);
  unsigned int r = (u + 0x7FFFu + ((u >> 16) & 1u)) >> 16;
  return (unsigned short)r;
}
__device__ __forceinline__ float bf2f(unsigned short u) {
  return __uint_as_float(((unsigned int)u) << 16);
}

// B-fragment (16 rows x 32 k) from row-major f32 weight matrix [R][128]
__device__ __forceinline__ bf16x8 load_wfrag(const float* __restrict__ W,
                                             int row0, int k0, int lane) {
  const float* p = W + (size_t)(row0 + (lane & 15)) * 128 + k0 + 8 * (lane >> 4);
  float4 x = *(const float4*)p;
  float4 y = *(const float4*)(p + 4);
  bf16x8 f;
  f[0] = (short)f2bf(x.x); f[1] = (short)f2bf(x.y);
  f[2] = (short)f2bf(x.z); f[3] = (short)f2bf(x.w);
  f[4] = (short)f2bf(y.x); f[5] = (short)f2bf(y.y);
  f[6] = (short)f2bf(y.z); f[7] = (short)f2bf(y.w);
  return f;
}

// A-fragment from XOR-swizzled bf16 LDS tile [rows][128 cols] (256 B/row)
__device__ __forceinline__ bf16x8 lds_afrag(const char* base, int row0, int k0, int lane) {
  int row = row0 + (lane & 15);
  int cb = (k0 + 8 * (lane >> 4)) * 2;
  int byte = row * 256 + ((((cb >> 4) ^ (row & 7))) << 4);
  return *(const bf16x8*)(base + byte);
}

__device__ __forceinline__ void lds_store4bf(char* base, int row, int cbyte,
                                             float a, float b, float c, float d) {
  int byte = row * 256 + ((((cbyte >> 4) ^ (row & 7))) << 4) + (cbyte & 15);
  ushort4 o4;
  o4.x = f2bf(a); o4.y = f2bf(b); o4.z = f2bf(c); o4.w = f2bf(d);
  *(ushort4*)(base + byte) = o4;
}

// ---------------- K0: mask dtype detection (parallel) ----------------
__global__ __launch_bounds__(256) void k_maskpart(const unsigned int* __restrict__ m4,
                                                  int* __restrict__ part)
{
  __shared__ int red[4];
  const int tid = threadIdx.x;
  unsigned int v = m4[blockIdx.x * 256 + tid];
  int cnt = ((v & 0xFFu) != 0) + (((v >> 8) & 0xFFu) != 0) +
            (((v >> 16) & 0xFFu) != 0) + ((v >> 24) != 0);
  #pragma unroll
  for (int m = 1; m < 64; m <<= 1) cnt += __shfl_xor(cnt, m);
  if ((tid & 63) == 0) red[tid >> 6] = cnt;
  __syncthreads();
  if (tid == 0) part[blockIdx.x] = red[0] + red[1] + red[2] + red[3];
}

__global__ __launch_bounds__(128) void k_maskred(const int* __restrict__ part,
                                                 int* __restrict__ flag)
{
  const int tid = threadIdx.x;
  int v = part[tid];
  #pragma unroll
  for (int m = 1; m < 64; m <<= 1) v += __shfl_xor(v, m);
  __shared__ int red[2];
  if ((tid & 63) == 0) red[tid >> 6] = v;
  __syncthreads();
  if (tid == 0) *flag = ((red[0] + red[1]) > 7864) ? 1 : 0;  // 1 = uint8 layout
}

// ---------------- K1: fused projections via MFMA, 64-pos tile, 8 waves ----------------
__global__ __launch_bounds__(512) void k_proj_mfma(
    const float* __restrict__ h,
    const float* __restrict__ wa1, const float* __restrict__ wa2,
    const float* __restrict__ wv1, const float* __restrict__ wv2,
    float* __restrict__ a1, float* __restrict__ a2,
    unsigned short* __restrict__ v1, unsigned short* __restrict__ v2)
{
  __shared__ __align__(16) char lds[16384 + 17408];
  char* hb  = lds;                 // bf16 swizzled h tile [64][256B]
  char* st1 = lds + 16384;         // v1 stage [32][272B]
  char* st2 = lds + 16384 + 8704;  // v2 stage [32][272B]
  const int tid = threadIdx.x, lane = tid & 63, w = tid >> 6;
  const size_t pos0 = (size_t)blockIdx.x * 64;

  // weight fragments: wave w -> 32 cols of v1 (w<4) or v2 (w>=4)
  const float* wv = (w < 4) ? wv1 : wv2;
  const int colbase = (w & 3) * 32;
  bf16x8 bfr[2][4];
  #pragma unroll
  for (int cf = 0; cf < 2; ++cf)
    #pragma unroll
    for (int ks = 0; ks < 4; ++ks)
      bfr[cf][ks] = load_wfrag(wv, colbase + cf * 16, ks * 32, lane);

  bf16x8 af[4];
  if (w == 0) {
    int r = lane & 15;
    const float* ar = (r < 8) ? (wa1 + (size_t)r * 128) : (wa2 + (size_t)(r - 8) * 128);
    #pragma unroll
    for (int ks = 0; ks < 4; ++ks) {
      const float* p = ar + ks * 32 + 8 * (lane >> 4);
      float4 x = *(const float4*)p;
      float4 y = *(const float4*)(p + 4);
      bf16x8 f;
      f[0]=(short)f2bf(x.x); f[1]=(short)f2bf(x.y); f[2]=(short)f2bf(x.z); f[3]=(short)f2bf(x.w);
      f[4]=(short)f2bf(y.x); f[5]=(short)f2bf(y.y); f[6]=(short)f2bf(y.z); f[7]=(short)f2bf(y.w);
      af[ks] = f;
    }
  }

  // stage 64 rows of h -> bf16 swizzled
  {
    const float4* hg4 = (const float4*)(h + pos0 * 128);
    #pragma unroll
    for (int q = 0; q < 4; ++q) {
      int f4i = q * 512 + tid;
      float4 x = hg4[f4i];
      lds_store4bf(hb, f4i >> 5, (f4i & 31) * 8, x.x, x.y, x.z, x.w);
    }
  }
  __syncthreads();

  const int lg = lane >> 4, lc = lane & 15;
  for (int p = 0; p < 2; ++p) {
    const int R = p * 32;
    f32x4 acc[2][2];
    #pragma unroll
    for (int rf = 0; rf < 2; ++rf)
      #pragma unroll
      for (int cf = 0; cf < 2; ++cf) acc[rf][cf] = (f32x4){0.f,0.f,0.f,0.f};
    f32x4 acca[2]; acca[0] = (f32x4){0.f,0.f,0.f,0.f}; acca[1] = acca[0];

    #pragma unroll
    for (int ks = 0; ks < 4; ++ks) {
      bf16x8 a0  = lds_afrag(hb, R,      ks * 32, lane);
      bf16x8 a1f = lds_afrag(hb, R + 16, ks * 32, lane);
      #pragma unroll
      for (int cf = 0; cf < 2; ++cf) {
        acc[0][cf] = __builtin_amdgcn_mfma_f32_16x16x32_bf16(a0,  bfr[cf][ks], acc[0][cf], 0, 0, 0);
        acc[1][cf] = __builtin_amdgcn_mfma_f32_16x16x32_bf16(a1f, bfr[cf][ks], acc[1][cf], 0, 0, 0);
      }
      if (w == 0) {
        acca[0] = __builtin_amdgcn_mfma_f32_16x16x32_bf16(a0,  af[ks], acca[0], 0, 0, 0);
        acca[1] = __builtin_amdgcn_mfma_f32_16x16x32_bf16(a1f, af[ks], acca[1], 0, 0, 0);
      }
    }

    if (p) __syncthreads();   // previous pass's copy-out must be done
    {
      char* st = (w < 4) ? st1 : st2;
      #pragma unroll
      for (int rf = 0; rf < 2; ++rf)
        #pragma unroll
        for (int cf = 0; cf < 2; ++cf)
          #pragma unroll
          for (int r = 0; r < 4; ++r) {
            int row = rf*16 + 4*lg + r;
            int col = colbase + cf*16 + lc;
            *(unsigned short*)(st + row*272 + col*2) = f2bf(acc[rf][cf][r]);
          }
    }
    if (w == 0) {
      #pragma unroll
      for (int rf = 0; rf < 2; ++rf)
        #pragma unroll
        for (int r = 0; r < 4; ++r) {
          size_t row = pos0 + R + rf*16 + 4*lg + r;
          float val = acca[rf][r];
          if (lc < 8) a1[row * 8 + lc] = val;
          else        a2[row * 8 + (lc - 8)] = val;
        }
    }
    __syncthreads();
    #pragma unroll
    for (int q = 0; q < 2; ++q) {
      int s = q * 512 + tid;
      int bsel = s >> 9, idx = s & 511;
      int row = idx >> 4, seg = idx & 15;
      int4 v = *(const int4*)((bsel ? st2 : st1) + row*272 + seg*16);
      unsigned short* dst = bsel ? v2 : v1;
      *(int4*)(dst + (pos0 + R + row)*128 + seg*8) = v;
    }
  }
}

// ---------------- K2a/K2b: row maxes ----------------
__global__ __launch_bounds__(64) void k_rowmax1(const float* __restrict__ a1,
                                                float* __restrict__ amax1)
{
  const int bi = blockIdx.x;
  const int t = threadIdx.x;
  const float* base = a1 + (size_t)bi * N_ * 8;
  float m = -1e30f;
  #pragma unroll 8
  for (int k = 0; k < 32; ++k) m = fmaxf(m, base[t + 64*k]);
  m = fmaxf(m, __shfl_xor(m, 8));
  m = fmaxf(m, __shfl_xor(m, 16));
  m = fmaxf(m, __shfl_xor(m, 32));
  if (t < 8) amax1[bi*8 + t] = m;
}

__global__ __launch_bounds__(64) void k_rowmax2(const float* __restrict__ a2,
                                                float* __restrict__ amax2)
{
  const int bj = blockIdx.x;
  const int b = bj >> 8, j = bj & 255;
  const int t = threadIdx.x;
  const int hh = t & 7, igrp = t >> 3;
  float m = -1e30f;
  for (int k = 0; k < 32; ++k) {
    int i = igrp + 8*k;
    m = fmaxf(m, a2[((size_t)(b*N_ + i)*N_ + j)*8 + hh]);
  }
  m = fmaxf(m, __shfl_xor(m, 8));
  m = fmaxf(m, __shfl_xor(m, 16));
  m = fmaxf(m, __shfl_xor(m, 32));
  if (t < 8) amax2[bj*8 + t] = m;
}

// ---------------- K3: exp (masked); e2 f32 natural; eb1 bf16 -> Abuf ch128+ ----------------
__global__ __launch_bounds__(256) void k_e(
    const void* __restrict__ maskraw, const int* __restrict__ modep,
    const float* __restrict__ a1, const float* __restrict__ a2,
    const float* __restrict__ am1, const float* __restrict__ am2,
    float* __restrict__ e2out, unsigned short* __restrict__ Abuf)
{
  __shared__ unsigned short eb[8 * 256];   // [h][p] bf16
  const int tid = threadIdx.x;
  const size_t pos0 = (size_t)blockIdx.x * 256;
  const size_t p = pos0 + tid;
  const int b = (int)(p >> 16), ij = (int)(p & 65535);
  const int i = ij >> 8, j = ij & 255;
  const int msk = modep[0] ? (int)((const unsigned char*)maskraw)[p]
                           : ((const int*)maskraw)[p];
  float4 x0 = *(const float4*)(a1 + p*8);
  float4 x1 = *(const float4*)(a1 + p*8 + 4);
  float4 m0 = *(const float4*)(am1 + ((size_t)(b*256 + i))*8);
  float4 m1 = *(const float4*)(am1 + ((size_t)(b*256 + i))*8 + 4);
  eb[0*256 + tid] = msk ? 0 : f2bf(__expf(x0.x - m0.x));
  eb[1*256 + tid] = msk ? 0 : f2bf(__expf(x0.y - m0.y));
  eb[2*256 + tid] = msk ? 0 : f2bf(__expf(x0.z - m0.z));
  eb[3*256 + tid] = msk ? 0 : f2bf(__expf(x0.w - m0.w));
  eb[4*256 + tid] = msk ? 0 : f2bf(__expf(x1.x - m1.x));
  eb[5*256 + tid] = msk ? 0 : f2bf(__expf(x1.y - m1.y));
  eb[6*256 + tid] = msk ? 0 : f2bf(__expf(x1.z - m1.z));
  eb[7*256 + tid] = msk ? 0 : f2bf(__expf(x1.w - m1.w));

  float4 y0 = *(const float4*)(a2 + p*8);
  float4 y1 = *(const float4*)(a2 + p*8 + 4);
  float4 n0 = *(const float4*)(am2 + ((size_t)(b*256 + j))*8);
  float4 n1 = *(const float4*)(am2 + ((size_t)(b*256 + j))*8 + 4);
  float4 o0, o1;
  o0.x = msk ? 0.f : __expf(y0.x - n0.x);
  o0.y = msk ? 0.f : __expf(y0.y - n0.y);
  o0.z = msk ? 0.f : __expf(y0.z - n0.z);
  o0.w = msk ? 0.f : __expf(y0.w - n0.w);
  o1.x = msk ? 0.f : __expf(y1.x - n1.x);
  o1.y = msk ? 0.f : __expf(y1.y - n1.y);
  o1.z = msk ? 0.f : __expf(y1.z - n1.z);
  o1.w = msk ? 0.f : __expf(y1.w - n1.w);
  *(float4*)(e2out + p*8) = o0;
  *(float4*)(e2out + p*8 + 4) = o1;

  __syncthreads();
  {
    int hh = tid >> 5, seg = tid & 31;
    int4 v = *(const int4*)((const char*)eb + hh*512 + seg*16);
    *(int4*)(Abuf + (((size_t)(b*136 + 128 + hh)) << 16) + (int)(pos0 & 65535) + seg*8) = v;
  }
}

// ---------------- K4a: pc1[c][i][l] = vb1[pos][c] * e1 (channel transpose) ----------------
__global__ __launch_bounds__(256) void k_prep1(
    const unsigned short* __restrict__ vb1, unsigned short* __restrict__ Abuf)
{
  __shared__ __align__(16) char lds[36864];  // xt [128][272B] + et [8][256B]
  char* xt = lds;
  unsigned short* et = (unsigned short*)(lds + 34816);
  const int tid = threadIdx.x;
  const size_t pos0 = (size_t)blockIdx.x * 128;
  const int b = (int)(pos0 >> 16);
  const int posl0 = (int)(pos0 & 65535);

  if (tid < 128) {
    int hh = tid >> 4, seg = tid & 15;
    int4 v = *(const int4*)(Abuf + (((size_t)(b*136 + 128 + hh)) << 16) + posl0 + seg*8);
    *(int4*)((char*)et + hh*256 + seg*16) = v;
  }
  #pragma unroll
  for (int q = 0; q < 8; ++q) {
    int s = q*256 + tid;
    int rec = s >> 4, g = s & 15;
    int4 v = *(const int4*)(vb1 + (pos0 + rec)*128 + g*8);
    *(int4*)(xt + rec*272 + g*16) = v;
  }
  __syncthreads();
  #pragma unroll
  for (int q = 0; q < 8; ++q) {
    int c = q*16 + (tid & 15);
    int pg = tid >> 4;
    int hh = c >> 4;
    u16x8 t;
    #pragma unroll
    for (int k = 0; k < 8; ++k) {
      int p = pg*8 + k;
      float xv = bf2f(*(const unsigned short*)(xt + p*272 + c*2));
      float ev = bf2f(et[hh*128 + p]);
      t[k] = f2bf(xv * ev);
    }
    *(int4*)(Abuf + (((size_t)(b*136 + c)) << 16) + posl0 + pg*8) = *(int4*)&t;
  }
}

// ---------------- K4b: pc2t[c][j][l] = vb2[(l,j)][c]*e2 ; eb2t[h][j][l] ----------------
__global__ __launch_bounds__(256) void k_prep2(
    const unsigned short* __restrict__ vb2, const float* __restrict__ e2,
    unsigned short* __restrict__ Bbuf)
{
  __shared__ __align__(16) char lds[49152];  // vt [512][80B] + et [512][16B]
  char* vt = lds;
  unsigned short* et = (unsigned short*)(lds + 40960);  // [rec][8 h] bf16
  const int tid = threadIdx.x;
  const int lt = blockIdx.x, jt = blockIdx.y, b = blockIdx.z;
  const int l0 = lt*32, j0 = jt*16;

  #pragma unroll
  for (int q = 0; q < 4; ++q) {
    int s = q*256 + tid;
    int rec = s >> 1, hf = (s & 1)*4;
    int l = rec >> 4, j = rec & 15;
    size_t pos = ((size_t)b << 16) + (size_t)(l0 + l)*256 + (j0 + j);
    float4 ev = *(const float4*)(e2 + pos*8 + hf);
    ushort4 o; o.x = f2bf(ev.x); o.y = f2bf(ev.y); o.z = f2bf(ev.z); o.w = f2bf(ev.w);
    *(ushort4*)(et + rec*8 + hf) = o;
  }

  for (int cw = 0; cw < 4; ++cw) {
    __syncthreads();
    #pragma unroll
    for (int q = 0; q < 8; ++q) {
      int s = q*256 + tid;
      int rec = s >> 2, g = s & 3;
      int l = rec >> 4, j = rec & 15;
      size_t pos = ((size_t)b << 16) + (size_t)(l0 + l)*256 + (j0 + j);
      int4 v = *(const int4*)(vb2 + pos*128 + cw*32 + g*8);
      *(int4*)(vt + rec*80 + g*16) = v;
    }
    __syncthreads();
    #pragma unroll
    for (int q = 0; q < 8; ++q) {
      int loff = tid & 3, j = (tid >> 2) & 15, cs = tid >> 6;
      int cl = q*4 + cs;
      int c = cw*32 + cl;
      int hh = c >> 4;
      u16x8 t;
      #pragma unroll
      for (int k = 0; k < 8; ++k) {
        int l = loff*8 + k;
        int rec = l*16 + j;
        float xv = bf2f(*(const unsigned short*)(vt + rec*80 + cl*2));
        float ev = bf2f(et[rec*8 + hh]);
        t[k] = f2bf(xv * ev);
      }
      *(int4*)(Bbuf + (((size_t)(b*136 + c)) << 16) + (size_t)(j0 + j)*256 + l0 + loff*8) = *(int4*)&t;
    }
  }
  __syncthreads();
  #pragma unroll
  for (int q = 0; q < 2; ++q) {
    int s = q*256 + tid;
    int loff = s & 3, j = (s >> 2) & 15, hh = s >> 6;
    u16x8 t;
    #pragma unroll
    for (int k = 0; k < 8; ++k) {
      int l = loff*8 + k;
      int rec = l*16 + j;
      t[k] = et[rec*8 + hh];
    }
    *(int4*)(Bbuf + (((size_t)(b*136 + 128 + hh)) << 16) + (size_t)(j0 + j)*256 + l0 + loff*8) = *(int4*)&t;
  }
}

// ---------------- K5: batched 256^3 GEMM over 272 channels (tri + denom) ----------------
__global__ __launch_bounds__(256) void k_tri_mfma(
    const unsigned short* __restrict__ Ab, const unsigned short* __restrict__ Bb,
    unsigned short* __restrict__ outT)
{
  __shared__ __align__(16) char lds[34816];
  char* lA = lds;
  char* lB = lds + 10240;
  const int tid = threadIdx.x, lane = tid & 63, w = tid >> 6;
  const int jt = blockIdx.x, it = blockIdx.y, z = blockIdx.z;
  const int b = z / 136, ch = z - b*136;
  const size_t mbase = ((size_t)(b*136 + ch)) << 16;
  const int i0 = it*128, j0 = jt*128;
  const int r4 = tid >> 2, g4 = tid & 3;

  const unsigned short* gA0 = Ab + mbase + (size_t)(i0 + r4)*256 + g4*8;
  const unsigned short* gA1 = gA0 + 64*256;
  const unsigned short* gB0 = Bb + mbase + (size_t)(j0 + r4)*256 + g4*8;
  const unsigned short* gB1 = gB0 + 64*256;
  char* sA0 = lA + r4*80 + g4*16;
  char* sA1 = sA0 + 64*80;
  char* sB0 = lB + r4*80 + g4*16;
  char* sB1 = sB0 + 64*80;

  const int wr = w >> 1, wc = w & 1;
  const char* fA = lA + (wr*64 + (lane & 15))*80 + (lane >> 4)*16;
  const char* fB = lB + (wc*64 + (lane & 15))*80 + (lane >> 4)*16;

  f32x4 acc[4][4];
  #pragma unroll
  for (int rf = 0; rf < 4; ++rf)
    #pragma unroll
    for (int cf = 0; cf < 4; ++cf) acc[rf][cf] = (f32x4){0.f,0.f,0.f,0.f};

  int4 ra0 = *(const int4*)gA0;
  int4 ra1 = *(const int4*)gA1;
  int4 rb0 = *(const int4*)gB0;
  int4 rb1 = *(const int4*)gB1;

  for (int ks = 0; ks < 8; ++ks) {
    __syncthreads();
    *(int4*)sA0 = ra0; *(int4*)sA1 = ra1;
    *(int4*)sB0 = rb0; *(int4*)sB1 = rb1;
    __syncthreads();
    if (ks < 7) {
      const int off = (ks + 1)*32;
      ra0 = *(const int4*)(gA0 + off);
      ra1 = *(const int4*)(gA1 + off);
      rb0 = *(const int4*)(gB0 + off);
      rb1 = *(const int4*)(gB1 + off);
    }
    bf16x8 af[4], bfv[4];
    #pragma unroll
    for (int rf = 0; rf < 4; ++rf) af[rf] = *(const bf16x8*)(fA + rf*16*80);
    #pragma unroll
    for (int cf = 0; cf < 4; ++cf) bfv[cf] = *(const bf16x8*)(fB + cf*16*80);
    #pragma unroll
    for (int rf = 0; rf < 4; ++rf)
      #pragma unroll
      for (int cf = 0; cf < 4; ++cf)
        acc[rf][cf] = __builtin_amdgcn_mfma_f32_16x16x32_bf16(af[rf], bfv[cf], acc[rf][cf], 0, 0, 0);
  }

  __syncthreads();
  #pragma unroll
  for (int rf = 0; rf < 4; ++rf)
    #pragma unroll
    for (int cf = 0; cf < 4; ++cf)
      #pragma unroll
      for (int r = 0; r < 4; ++r) {
        int il = wr*64 + rf*16 + 4*(lane >> 4) + r;
        int jl = wc*64 + cf*16 + (lane & 15);
        *(unsigned short*)(lds + il*272 + jl*2) = f2bf(acc[rf][cf][r]);
      }
  __syncthreads();
  #pragma unroll
  for (int q = 0; q < 8; ++q) {
    int row = q*16 + (tid >> 4), seg = tid & 15;
    int4 v = *(const int4*)(lds + row*272 + seg*16);
    *(int4*)(outT + mbase + (size_t)(i0 + row)*256 + j0 + seg*8) = v;
  }
}

// ---------------- K6: x = t/denom ; y = x@wo^T ; hn = bf16(LN1(h + y)) ----------------
__global__ __launch_bounds__(256) void k_wo_ln_mfma(
    const unsigned short* __restrict__ tT,
    const float* __restrict__ h, const float* __restrict__ wo,
    const float* __restrict__ g1, const float* __restrict__ bb1,
    unsigned short* __restrict__ hn)
{
  __shared__ __align__(16) char xb[32 * 256];
  __shared__ __align__(16) float stage[32 * 132];
  const int tid = threadIdx.x, lane = tid & 63, w = tid >> 6;
  const size_t pos0 = (size_t)blockIdx.x * 32;
  const int b = (int)(pos0 >> 16);
  const int posl0 = (int)(pos0 & 65535);

  bf16x8 bfr[2][4];
  #pragma unroll
  for (int cf = 0; cf < 2; ++cf)
    #pragma unroll
    for (int ks = 0; ks < 4; ++ks)
      bfr[cf][ks] = load_wfrag(wo, w * 32 + cf * 16, ks * 32, lane);

  #pragma unroll
  for (int it2 = 0; it2 < 2; ++it2) {
    int c = it2*64 + (tid >> 2);
    int poff = (tid & 3)*8;
    u16x8 tv = *(const u16x8*)(tT + (((size_t)(b*136 + c)) << 16) + posl0 + poff);
    u16x8 dv = *(const u16x8*)(tT + (((size_t)(b*136 + 128 + (c >> 4))) << 16) + posl0 + poff);
    int cb = c*2;
    #pragma unroll
    for (int k = 0; k < 8; ++k) {
      float x = bf2f(tv[k]) / (bf2f(dv[k]) + 1e-6f);
      int p = poff + k;
      int byte = p*256 + ((((cb >> 4) ^ (p & 7))) << 4) + (cb & 15);
      *(unsigned short*)(xb + byte) = f2bf(x);
    }
  }
  __syncthreads();

  f32x4 acc[2][2];
  #pragma unroll
  for (int rf = 0; rf < 2; ++rf)
    #pragma unroll
    for (int cf = 0; cf < 2; ++cf) acc[rf][cf] = (f32x4){0.f,0.f,0.f,0.f};

  #pragma unroll
  for (int ks = 0; ks < 4; ++ks) {
    bf16x8 a0 = lds_afrag(xb, 0, ks * 32, lane);
    bf16x8 a1f = lds_afrag(xb, 16, ks * 32, lane);
    #pragma unroll
    for (int cf = 0; cf < 2; ++cf) {
      acc[0][cf] = __builtin_amdgcn_mfma_f32_16x16x32_bf16(a0,  bfr[cf][ks], acc[0][cf], 0, 0, 0);
      acc[1][cf] = __builtin_amdgcn_mfma_f32_16x16x32_bf16(a1f, bfr[cf][ks], acc[1][cf], 0, 0, 0);
    }
  }

  const int lg = lane >> 4, lc = lane & 15;
  #pragma unroll
  for (int rf = 0; rf < 2; ++rf)
    #pragma unroll
    for (int cf = 0; cf < 2; ++cf)
      #pragma unroll
      for (int r = 0; r < 4; ++r)
        stage[(rf*16 + 4*lg + r) * 132 + w*32 + cf*16 + lc] = acc[rf][cf][r];
  __syncthreads();

  const float ga = g1[lane], gb = g1[64 + lane];
  const float ba = bb1[lane], bbv = bb1[64 + lane];
  for (int rr = 0; rr < 8; ++rr) {
    int row = w * 8 + rr;
    float y0 = stage[row * 132 + lane];
    float y1 = stage[row * 132 + 64 + lane];
    float r0 = h[(pos0 + row) * 128 + lane] + y0;
    float r1 = h[(pos0 + row) * 128 + 64 + lane] + y1;
    float s = r0 + r1, sq = r0*r0 + r1*r1;
    #pragma unroll
    for (int m = 1; m < 64; m <<= 1) { s += __shfl_xor(s, m); sq += __shfl_xor(sq, m); }
    float mu = s * (1.f/128.f);
    float var = sq * (1.f/128.f) - mu*mu;
    float rstd = rsqrtf(var + 1e-5f);
    hn[(pos0 + row) * 128 + lane]      = f2bf((r0 - mu) * rstd * ga + ba);
    hn[(pos0 + row) * 128 + 64 + lane] = f2bf((r1 - mu) * rstd * gb + bbv);
  }
}

// ---------------- K7: FFN(silu) + residual + LN2 -> out (hn bf16 in) ----------------
__global__ __launch_bounds__(256) void k_ffn_ln_mfma(
    const unsigned short* __restrict__ hnp,
    const float* __restrict__ w1, const float* __restrict__ bias1,
    const float* __restrict__ w2, const float* __restrict__ bias2,
    const float* __restrict__ g2, const float* __restrict__ b2v,
    float* __restrict__ out)
{
  __shared__ __align__(16) char xb[32 * 256];
  __shared__ __align__(16) float stage[32 * 132];
  const int tid = threadIdx.x, lane = tid & 63, w = tid >> 6;
  const size_t pos0 = (size_t)blockIdx.x * 32;

  bf16x8 bf1[2][4], bf2v[2][4];
  #pragma unroll
  for (int cf = 0; cf < 2; ++cf)
    #pragma unroll
    for (int ks = 0; ks < 4; ++ks) {
      bf1[cf][ks]  = load_wfrag(w1, w * 32 + cf * 16, ks * 32, lane);
      bf2v[cf][ks] = load_wfrag(w2, w * 32 + cf * 16, ks * 32, lane);
    }

  #pragma unroll
  for (int q = 0; q < 2; ++q) {
    int s = q*256 + tid;
    int row = s >> 4, g = s & 15;
    int4 v = *(const int4*)(hnp + (pos0 + row)*128 + g*8);
    *(int4*)(xb + row*256 + (((g ^ (row & 7))) << 4)) = v;
  }
  __syncthreads();

  f32x4 acc[2][2];
  #pragma unroll
  for (int rf = 0; rf < 2; ++rf)
    #pragma unroll
    for (int cf = 0; cf < 2; ++cf) acc[rf][cf] = (f32x4){0.f,0.f,0.f,0.f};

  #pragma unroll
  for (int ks = 0; ks < 4; ++ks) {
    bf16x8 a0 = lds_afrag(xb, 0, ks * 32, lane);
    bf16x8 a1f = lds_afrag(xb, 16, ks * 32, lane);
    #pragma unroll
    for (int cf = 0; cf < 2; ++cf) {
      acc[0][cf] = __builtin_amdgcn_mfma_f32_16x16x32_bf16(a0,  bf1[cf][ks], acc[0][cf], 0, 0, 0);
      acc[1][cf] = __builtin_amdgcn_mfma_f32_16x16x32_bf16(a1f, bf1[cf][ks], acc[1][cf], 0, 0, 0);
    }
  }
  __syncthreads();

  const int lg = lane >> 4, lc = lane & 15;
  {
    float bc0 = bias1[w*32 + lc];
    float bc1 = bias1[w*32 + 16 + lc];
    #pragma unroll
    for (int rf = 0; rf < 2; ++rf)
      #pragma unroll
      for (int cf = 0; cf < 2; ++cf) {
        float bc = cf ? bc1 : bc0;
        #pragma unroll
        for (int r = 0; r < 4; ++r) {
          int row = rf*16 + 4*lg + r;
          int col = w*32 + cf*16 + lc;
          float s = acc[rf][cf][r] + bc;
          float u = s / (1.f + __expf(-s));
          int cbyte = col * 2;
          int byte = row * 256 + ((((cbyte >> 4) ^ (row & 7))) << 4) + (cbyte & 15);
          *(unsigned short*)(xb + byte) = f2bf(u);
        }
      }
  }
  __syncthreads();

  f32x4 acc2[2][2];
  #pragma unroll
  for (int rf = 0; rf < 2; ++rf)
    #pragma unroll
    for (int cf = 0; cf < 2; ++cf) acc2[rf][cf] = (f32x4){0.f,0.f,0.f,0.f};

  #pragma unroll
  for (int ks = 0; ks < 4; ++ks) {
    bf16x8 a0 = lds_afrag(xb, 0, ks * 32, lane);
    bf16x8 a1f = lds_afrag(xb, 16, ks * 32, lane);
    #pragma unroll
    for (int cf = 0; cf < 2; ++cf) {
      acc2[0][cf] = __builtin_amdgcn_mfma_f32_16x16x32_bf16(a0,  bf2v[cf][ks], acc2[0][cf], 0, 0, 0);
      acc2[1][cf] = __builtin_amdgcn_mfma_f32_16x16x32_bf16(a1f, bf2v[cf][ks], acc2[1][cf], 0, 0, 0);
    }
  }

  {
    float bc0 = bias2[w*32 + lc];
    float bc1 = bias2[w*32 + 16 + lc];
    #pragma unroll
    for (int rf = 0; rf < 2; ++rf)
      #pragma unroll
      for (int cf = 0; cf < 2; ++cf) {
        float bc = cf ? bc1 : bc0;
        #pragma unroll
        for (int r = 0; r < 4; ++r)
          stage[(rf*16 + 4*lg + r) * 132 + w*32 + cf*16 + lc] = acc2[rf][cf][r] + bc;
      }
  }
  __syncthreads();

  const float ga = g2[lane], gb = g2[64 + lane];
  const float ba = b2v[lane], bbv = b2v[64 + lane];
  for (int rr = 0; rr < 8; ++rr) {
    int row = w * 8 + rr;
    float y0 = stage[row * 132 + lane];
    float y1 = stage[row * 132 + 64 + lane];
    float r0 = bf2f(hnp[(pos0 + row) * 128 + lane]) + y0;
    float r1 = bf2f(hnp[(pos0 + row) * 128 + 64 + lane]) + y1;
    float s = r0 + r1, sq = r0*r0 + r1*r1;
    #pragma unroll
    for (int m = 1; m < 64; m <<= 1) { s += __shfl_xor(s, m); sq += __shfl_xor(sq, m); }
    float mu = s * (1.f/128.f);
    float var = sq * (1.f/128.f) - mu*mu;
    float rstd = rsqrtf(var + 1e-5f);
    out[(pos0 + row) * 128 + lane]      = (r0 - mu) * rstd * ga + ba;
    out[(pos0 + row) * 128 + 64 + lane] = (r1 - mu) * rstd * gb + bbv;
  }
}

extern "C" void kernel_launch(void* const* d_in, const int* in_sizes, int n_in,
                              void* d_out, int out_size, void* d_ws, size_t ws_size,
                              hipStream_t stream)
{
  const float* h    = (const float*)d_in[0];
  const void*  mask = d_in[1];
  const float* wa1  = (const float*)d_in[2];
  const float* wa2  = (const float*)d_in[3];
  const float* wv1  = (const float*)d_in[4];
  const float* wv2  = (const float*)d_in[5];
  const float* wo   = (const float*)d_in[6];
  const float* ln1s = (const float*)d_in[7];
  const float* ln1b = (const float*)d_in[8];
  const float* ln2s = (const float*)d_in[9];
  const float* ln2b = (const float*)d_in[10];
  const float* wu1  = (const float*)d_in[11];
  const float* bu1  = (const float*)d_in[12];
  const float* wu2  = (const float*)d_in[13];
  const float* bu2  = (const float*)d_in[14];

  char* ws = (char*)d_ws;
  const size_t MB = 1024*1024;
  unsigned short* vb1   = (unsigned short*)(ws + 0);        // 32 MB
  unsigned short* tbufT = (unsigned short*)(ws + 0);        // 35.7 MB (aliases vb1)
  unsigned short* vb2   = (unsigned short*)(ws + 36*MB);    // 32 MB
  unsigned short* hn    = (unsigned short*)(ws + 36*MB);    // 32 MB (aliases vb2)
  unsigned short* Bbuf  = (unsigned short*)(ws + 68*MB);    // 35.7 MB
  float* a1  = (float*)(ws + 104*MB);                       // 4 MB
  float* a2  = (float*)(ws + 108*MB);                       // 4 MB
  float* e2  = (float*)(ws + 112*MB);                       // 4 MB
  float* am1 = (float*)(ws + 116*MB);
  float* am2 = (float*)(ws + 116*MB + 16384);
  int*   flg = (int*)  (ws + 116*MB + 32768);
  int*   part= (int*)  (ws + 116*MB + 65536);               // 128 ints
  unsigned short* Abuf = (unsigned short*)d_out;            // 35.7 MB in 64 MB out

  k_maskpart<<<128, 256, 0, stream>>>((const unsigned int*)mask, part);
  k_maskred<<<1, 128, 0, stream>>>(part, flg);
  k_proj_mfma<<<2048, 512, 0, stream>>>(h, wa1, wa2, wv1, wv2, a1, a2, vb1, vb2);
  k_rowmax1<<<512, 64, 0, stream>>>(a1, am1);
  k_rowmax2<<<512, 64, 0, stream>>>(a2, am2);
  k_e<<<512, 256, 0, stream>>>(mask, flg, a1, a2, am1, am2, e2, Abuf);
  k_prep1<<<1024, 256, 0, stream>>>(vb1, Abuf);
  k_prep2<<<dim3(8,16,2), 256, 0, stream>>>(vb2, e2, Bbuf);
  k_tri_mfma<<<dim3(2,2,272), 256, 0, stream>>>(Abuf, Bbuf, tbufT);
  k_wo_ln_mfma<<<4096, 256, 0, stream>>>(tbufT, h, wo, ln1s, ln1b, hn);
  k_ffn_ln_mfma<<<4096, 256, 0, stream>>>(hn, wu1, bu1, wu2, bu2, ln2s, ln2b, (float*)d_out);
}

// Round 6
// 195.600 us; speedup vs baseline: 19.5125x; 1.3735x over previous
//
#include <hip/hip_runtime.h>

#define B_ 2
#define N_ 256
#define C_ 128
#define H_ 8

typedef __attribute__((ext_vector_type(8))) short bf16x8;
typedef __attribute__((ext_vector_type(8))) unsigned short u16x8;
typedef __attribute__((ext_vector_type(4))) float f32x4;

__device__ __forceinline__ unsigned short f2bf(float f) {
  unsigned int u = __float_as_uint(f);
  unsigned int r = (u + 0x7FFFu + ((u >> 16) & 1u)) >> 16;
  return (unsigned short)r;
}
__device__ __forceinline__ float bf2f(unsigned short u) {
  return __uint_as_float(((unsigned int)u) << 16);
}

// A-fragment from XOR-swizzled bf16 LDS tile [rows][128 cols] (256 B/row)
__device__ __forceinline__ bf16x8 lds_afrag(const char* base, int row0, int k0, int lane) {
  int row = row0 + (lane & 15);
  int cb = (k0 + 8 * (lane >> 4)) * 2;
  int byte = row * 256 + ((((cb >> 4) ^ (row & 7))) << 4);
  return *(const bf16x8*)(base + byte);
}

__device__ __forceinline__ void lds_store4bf(char* base, int row, int cbyte,
                                             float a, float b, float c, float d) {
  int byte = row * 256 + ((((cbyte >> 4) ^ (row & 7))) << 4) + (cbyte & 15);
  ushort4 o4;
  o4.x = f2bf(a); o4.y = f2bf(b); o4.z = f2bf(c); o4.w = f2bf(d);
  *(ushort4*)(base + byte) = o4;
}

// frag-major weight fetch: wbase -> [cfi][ks][lane][8] bf16
__device__ __forceinline__ bf16x8 wb_frag(const unsigned short* wbase,
                                          int cfi, int ks, int lane) {
  return *(const bf16x8*)(wbase + (((cfi * 4 + ks) * 64) + lane) * 8);
}

// ---------------- K0: mask dtype detection (parallel) ----------------
__global__ __launch_bounds__(256) void k_maskpart(const unsigned int* __restrict__ m4,
                                                  int* __restrict__ part)
{
  __shared__ int red[4];
  const int tid = threadIdx.x;
  unsigned int v = m4[blockIdx.x * 256 + tid];
  int cnt = ((v & 0xFFu) != 0) + (((v >> 8) & 0xFFu) != 0) +
            (((v >> 16) & 0xFFu) != 0) + ((v >> 24) != 0);
  #pragma unroll
  for (int m = 1; m < 64; m <<= 1) cnt += __shfl_xor(cnt, m);
  if ((tid & 63) == 0) red[tid >> 6] = cnt;
  __syncthreads();
  if (tid == 0) part[blockIdx.x] = red[0] + red[1] + red[2] + red[3];
}

__global__ __launch_bounds__(128) void k_maskred(const int* __restrict__ part,
                                                 int* __restrict__ flag)
{
  const int tid = threadIdx.x;
  int v = part[tid];
  #pragma unroll
  for (int m = 1; m < 64; m <<= 1) v += __shfl_xor(v, m);
  __shared__ int red[2];
  if ((tid & 63) == 0) red[tid >> 6] = v;
  __syncthreads();
  if (tid == 0) *flag = ((red[0] + red[1]) > 7864) ? 1 : 0;  // 1 = uint8 layout
}

// ---------------- K0b: weight conversion to fragment-major bf16 ----------------
// wb layout: [0]=wv1 [1]=wv2 [2]=wo [3]=w1 [4]=w2 (16384 each), +5*16384: wa (2048)
__global__ __launch_bounds__(256) void k_wconv(
    const float* __restrict__ wv1, const float* __restrict__ wv2,
    const float* __restrict__ wo, const float* __restrict__ w1,
    const float* __restrict__ w2,
    const float* __restrict__ wa1, const float* __restrict__ wa2,
    unsigned short* __restrict__ wb)
{
  const int m = blockIdx.x;
  const int tid = threadIdx.x;
  const int l = tid & 63;
  if (m < 5) {
    const float* W = (m == 0) ? wv1 : (m == 1) ? wv2 : (m == 2) ? wo : (m == 3) ? w1 : w2;
    unsigned short* o = wb + m * 16384;
    const int sub = tid >> 6;
    #pragma unroll
    for (int q = 0; q < 8; ++q) {
      int f = q * 4 + sub;              // fragment 0..31 (cf = f>>2, ks = f&3)
      int cf = f >> 2, ks = f & 3;
      int row = cf * 16 + (l & 15);
      int k = ks * 32 + 8 * (l >> 4);
      const float* p = W + row * 128 + k;
      float4 x = *(const float4*)p, y = *(const float4*)(p + 4);
      u16x8 t;
      t[0] = f2bf(x.x); t[1] = f2bf(x.y); t[2] = f2bf(x.z); t[3] = f2bf(x.w);
      t[4] = f2bf(y.x); t[5] = f2bf(y.y); t[6] = f2bf(y.z); t[7] = f2bf(y.w);
      *(u16x8*)(o + (f * 64 + l) * 8) = t;
    }
  } else {
    unsigned short* o = wb + 5 * 16384;
    const int ks = tid >> 6;
    int r = l & 15;
    const float* ar = (r < 8) ? (wa1 + r * 128) : (wa2 + (r - 8) * 128);
    const float* p = ar + ks * 32 + 8 * (l >> 4);
    float4 x = *(const float4*)p, y = *(const float4*)(p + 4);
    u16x8 t;
    t[0] = f2bf(x.x); t[1] = f2bf(x.y); t[2] = f2bf(x.z); t[3] = f2bf(x.w);
    t[4] = f2bf(y.x); t[5] = f2bf(y.y); t[6] = f2bf(y.z); t[7] = f2bf(y.w);
    *(u16x8*)(o + (ks * 64 + l) * 8) = t;
  }
}

// ---------------- K1: fused projections via MFMA, 64-pos tile, 8 waves ----------------
__global__ __launch_bounds__(512) void k_proj_mfma(
    const float* __restrict__ h, const unsigned short* __restrict__ wb,
    float* __restrict__ a1, float* __restrict__ a2,
    unsigned short* __restrict__ v1, unsigned short* __restrict__ v2)
{
  __shared__ __align__(16) char lds[16384 + 17408];
  char* hb  = lds;                 // bf16 swizzled h tile [64][256B]
  char* st1 = lds + 16384;         // v1 stage [32][272B]
  char* st2 = lds + 16384 + 8704;  // v2 stage [32][272B]
  const int tid = threadIdx.x, lane = tid & 63, w = tid >> 6;
  const size_t pos0 = (size_t)blockIdx.x * 64;

  const unsigned short* wbv = wb + ((w < 4) ? 0 : 16384);
  const unsigned short* wba = wb + 5 * 16384;
  const int colbase = (w & 3) * 32;
  bf16x8 bfr[2][4];
  #pragma unroll
  for (int cf = 0; cf < 2; ++cf)
    #pragma unroll
    for (int ks = 0; ks < 4; ++ks)
      bfr[cf][ks] = wb_frag(wbv, (w & 3) * 2 + cf, ks, lane);

  bf16x8 af[4];
  if (w == 0) {
    #pragma unroll
    for (int ks = 0; ks < 4; ++ks)
      af[ks] = *(const bf16x8*)(wba + (ks * 64 + lane) * 8);
  }

  // stage 64 rows of h -> bf16 swizzled
  {
    const float4* hg4 = (const float4*)(h + pos0 * 128);
    #pragma unroll
    for (int q = 0; q < 4; ++q) {
      int f4i = q * 512 + tid;
      float4 x = hg4[f4i];
      lds_store4bf(hb, f4i >> 5, (f4i & 31) * 8, x.x, x.y, x.z, x.w);
    }
  }
  __syncthreads();

  const int lg = lane >> 4, lc = lane & 15;
  for (int p = 0; p < 2; ++p) {
    const int R = p * 32;
    f32x4 acc[2][2];
    #pragma unroll
    for (int rf = 0; rf < 2; ++rf)
      #pragma unroll
      for (int cf = 0; cf < 2; ++cf) acc[rf][cf] = (f32x4){0.f,0.f,0.f,0.f};
    f32x4 acca[2]; acca[0] = (f32x4){0.f,0.f,0.f,0.f}; acca[1] = acca[0];

    #pragma unroll
    for (int ks = 0; ks < 4; ++ks) {
      bf16x8 a0  = lds_afrag(hb, R,      ks * 32, lane);
      bf16x8 a1f = lds_afrag(hb, R + 16, ks * 32, lane);
      #pragma unroll
      for (int cf = 0; cf < 2; ++cf) {
        acc[0][cf] = __builtin_amdgcn_mfma_f32_16x16x32_bf16(a0,  bfr[cf][ks], acc[0][cf], 0, 0, 0);
        acc[1][cf] = __builtin_amdgcn_mfma_f32_16x16x32_bf16(a1f, bfr[cf][ks], acc[1][cf], 0, 0, 0);
      }
      if (w == 0) {
        acca[0] = __builtin_amdgcn_mfma_f32_16x16x32_bf16(a0,  af[ks], acca[0], 0, 0, 0);
        acca[1] = __builtin_amdgcn_mfma_f32_16x16x32_bf16(a1f, af[ks], acca[1], 0, 0, 0);
      }
    }

    if (p) __syncthreads();
    {
      char* st = (w < 4) ? st1 : st2;
      #pragma unroll
      for (int rf = 0; rf < 2; ++rf)
        #pragma unroll
        for (int cf = 0; cf < 2; ++cf)
          #pragma unroll
          for (int r = 0; r < 4; ++r) {
            int row = rf*16 + 4*lg + r;
            int col = colbase + cf*16 + lc;
            *(unsigned short*)(st + row*272 + col*2) = f2bf(acc[rf][cf][r]);
          }
    }
    if (w == 0) {
      #pragma unroll
      for (int rf = 0; rf < 2; ++rf)
        #pragma unroll
        for (int r = 0; r < 4; ++r) {
          size_t row = pos0 + R + rf*16 + 4*lg + r;
          float val = acca[rf][r];
          if (lc < 8) a1[row * 8 + lc] = val;
          else        a2[row * 8 + (lc - 8)] = val;
        }
    }
    __syncthreads();
    #pragma unroll
    for (int q = 0; q < 2; ++q) {
      int s = q * 512 + tid;
      int bsel = s >> 9, idx = s & 511;
      int row = idx >> 4, seg = idx & 15;
      int4 v = *(const int4*)((bsel ? st2 : st1) + row*272 + seg*16);
      unsigned short* dst = bsel ? v2 : v1;
      *(int4*)(dst + (pos0 + R + row)*128 + seg*8) = v;
    }
  }
}

// ---------------- K2a/K2b: row maxes ----------------
__global__ __launch_bounds__(64) void k_rowmax1(const float* __restrict__ a1,
                                                float* __restrict__ amax1)
{
  const int bi = blockIdx.x;
  const int t = threadIdx.x;
  const float* base = a1 + (size_t)bi * N_ * 8;
  float m = -1e30f;
  #pragma unroll 8
  for (int k = 0; k < 32; ++k) m = fmaxf(m, base[t + 64*k]);
  m = fmaxf(m, __shfl_xor(m, 8));
  m = fmaxf(m, __shfl_xor(m, 16));
  m = fmaxf(m, __shfl_xor(m, 32));
  if (t < 8) amax1[bi*8 + t] = m;
}

__global__ __launch_bounds__(64) void k_rowmax2(const float* __restrict__ a2,
                                                float* __restrict__ amax2)
{
  const int bj = blockIdx.x;
  const int b = bj >> 8, j = bj & 255;
  const int t = threadIdx.x;
  const int hh = t & 7, igrp = t >> 3;
  float m = -1e30f;
  for (int k = 0; k < 32; ++k) {
    int i = igrp + 8*k;
    m = fmaxf(m, a2[((size_t)(b*N_ + i)*N_ + j)*8 + hh]);
  }
  m = fmaxf(m, __shfl_xor(m, 8));
  m = fmaxf(m, __shfl_xor(m, 16));
  m = fmaxf(m, __shfl_xor(m, 32));
  if (t < 8) amax2[bj*8 + t] = m;
}

// ---------------- K3: exp (masked); e2 f32 natural; eb1 bf16 -> Abuf ch128+ ----------------
__global__ __launch_bounds__(256) void k_e(
    const void* __restrict__ maskraw, const int* __restrict__ modep,
    const float* __restrict__ a1, const float* __restrict__ a2,
    const float* __restrict__ am1, const float* __restrict__ am2,
    float* __restrict__ e2out, unsigned short* __restrict__ Abuf)
{
  __shared__ unsigned short eb[8 * 256];   // [h][p] bf16
  const int tid = threadIdx.x;
  const size_t pos0 = (size_t)blockIdx.x * 256;
  const size_t p = pos0 + tid;
  const int b = (int)(p >> 16), ij = (int)(p & 65535);
  const int i = ij >> 8, j = ij & 255;
  const int msk = modep[0] ? (int)((const unsigned char*)maskraw)[p]
                           : ((const int*)maskraw)[p];
  float4 x0 = *(const float4*)(a1 + p*8);
  float4 x1 = *(const float4*)(a1 + p*8 + 4);
  float4 m0 = *(const float4*)(am1 + ((size_t)(b*256 + i))*8);
  float4 m1 = *(const float4*)(am1 + ((size_t)(b*256 + i))*8 + 4);
  eb[0*256 + tid] = msk ? 0 : f2bf(__expf(x0.x - m0.x));
  eb[1*256 + tid] = msk ? 0 : f2bf(__expf(x0.y - m0.y));
  eb[2*256 + tid] = msk ? 0 : f2bf(__expf(x0.z - m0.z));
  eb[3*256 + tid] = msk ? 0 : f2bf(__expf(x0.w - m0.w));
  eb[4*256 + tid] = msk ? 0 : f2bf(__expf(x1.x - m1.x));
  eb[5*256 + tid] = msk ? 0 : f2bf(__expf(x1.y - m1.y));
  eb[6*256 + tid] = msk ? 0 : f2bf(__expf(x1.z - m1.z));
  eb[7*256 + tid] = msk ? 0 : f2bf(__expf(x1.w - m1.w));

  float4 y0 = *(const float4*)(a2 + p*8);
  float4 y1 = *(const float4*)(a2 + p*8 + 4);
  float4 n0 = *(const float4*)(am2 + ((size_t)(b*256 + j))*8);
  float4 n1 = *(const float4*)(am2 + ((size_t)(b*256 + j))*8 + 4);
  float4 o0, o1;
  o0.x = msk ? 0.f : __expf(y0.x - n0.x);
  o0.y = msk ? 0.f : __expf(y0.y - n0.y);
  o0.z = msk ? 0.f : __expf(y0.z - n0.z);
  o0.w = msk ? 0.f : __expf(y0.w - n0.w);
  o1.x = msk ? 0.f : __expf(y1.x - n1.x);
  o1.y = msk ? 0.f : __expf(y1.y - n1.y);
  o1.z = msk ? 0.f : __expf(y1.z - n1.z);
  o1.w = msk ? 0.f : __expf(y1.w - n1.w);
  *(float4*)(e2out + p*8) = o0;
  *(float4*)(e2out + p*8 + 4) = o1;

  __syncthreads();
  {
    int hh = tid >> 5, seg = tid & 31;
    int4 v = *(const int4*)((const char*)eb + hh*512 + seg*16);
    *(int4*)(Abuf + (((size_t)(b*136 + 128 + hh)) << 16) + (int)(pos0 & 65535) + seg*8) = v;
  }
}

// ---------------- K4a: pc1[c][i][l] = vb1[pos][c] * e1 (channel transpose) ----------------
__global__ __launch_bounds__(256) void k_prep1(
    const unsigned short* __restrict__ vb1, unsigned short* __restrict__ Abuf)
{
  __shared__ __align__(16) char lds[36864];  // xt [128][272B] + et [8][256B]
  char* xt = lds;
  unsigned short* et = (unsigned short*)(lds + 34816);
  const int tid = threadIdx.x;
  const size_t pos0 = (size_t)blockIdx.x * 128;
  const int b = (int)(pos0 >> 16);
  const int posl0 = (int)(pos0 & 65535);

  if (tid < 128) {
    int hh = tid >> 4, seg = tid & 15;
    int4 v = *(const int4*)(Abuf + (((size_t)(b*136 + 128 + hh)) << 16) + posl0 + seg*8);
    *(int4*)((char*)et + hh*256 + seg*16) = v;
  }
  #pragma unroll
  for (int q = 0; q < 8; ++q) {
    int s = q*256 + tid;
    int rec = s >> 4, g = s & 15;
    int4 v = *(const int4*)(vb1 + (pos0 + rec)*128 + g*8);
    *(int4*)(xt + rec*272 + g*16) = v;
  }
  __syncthreads();
  #pragma unroll
  for (int q = 0; q < 8; ++q) {
    int c = q*16 + (tid & 15);
    int pg = tid >> 4;
    int hh = c >> 4;
    u16x8 t;
    #pragma unroll
    for (int k = 0; k < 8; ++k) {
      int p = pg*8 + k;
      float xv = bf2f(*(const unsigned short*)(xt + p*272 + c*2));
      float ev = bf2f(et[hh*128 + p]);
      t[k] = f2bf(xv * ev);
    }
    *(int4*)(Abuf + (((size_t)(b*136 + c)) << 16) + posl0 + pg*8) = *(int4*)&t;
  }
}

// ---------------- K4b: pc2t[c][j][l] = vb2[(l,j)][c]*e2 ; eb2t[h][j][l] ----------------
__global__ __launch_bounds__(256) void k_prep2(
    const unsigned short* __restrict__ vb2, const float* __restrict__ e2,
    unsigned short* __restrict__ Bbuf)
{
  __shared__ __align__(16) char lds[49152];  // vt [512][80B] + et [512][16B]
  char* vt = lds;
  unsigned short* et = (unsigned short*)(lds + 40960);  // [rec][8 h] bf16
  const int tid = threadIdx.x;
  const int lt = blockIdx.x, jt = blockIdx.y, b = blockIdx.z;
  const int l0 = lt*32, j0 = jt*16;

  #pragma unroll
  for (int q = 0; q < 4; ++q) {
    int s = q*256 + tid;
    int rec = s >> 1, hf = (s & 1)*4;
    int l = rec >> 4, j = rec & 15;
    size_t pos = ((size_t)b << 16) + (size_t)(l0 + l)*256 + (j0 + j);
    float4 ev = *(const float4*)(e2 + pos*8 + hf);
    ushort4 o; o.x = f2bf(ev.x); o.y = f2bf(ev.y); o.z = f2bf(ev.z); o.w = f2bf(ev.w);
    *(ushort4*)(et + rec*8 + hf) = o;
  }

  for (int cw = 0; cw < 4; ++cw) {
    __syncthreads();
    #pragma unroll
    for (int q = 0; q < 8; ++q) {
      int s = q*256 + tid;
      int rec = s >> 2, g = s & 3;
      int l = rec >> 4, j = rec & 15;
      size_t pos = ((size_t)b << 16) + (size_t)(l0 + l)*256 + (j0 + j);
      int4 v = *(const int4*)(vb2 + pos*128 + cw*32 + g*8);
      *(int4*)(vt + rec*80 + g*16) = v;
    }
    __syncthreads();
    #pragma unroll
    for (int q = 0; q < 8; ++q) {
      int loff = tid & 3, j = (tid >> 2) & 15, cs = tid >> 6;
      int cl = q*4 + cs;
      int c = cw*32 + cl;
      int hh = c >> 4;
      u16x8 t;
      #pragma unroll
      for (int k = 0; k < 8; ++k) {
        int l = loff*8 + k;
        int rec = l*16 + j;
        float xv = bf2f(*(const unsigned short*)(vt + rec*80 + cl*2));
        float ev = bf2f(et[rec*8 + hh]);
        t[k] = f2bf(xv * ev);
      }
      *(int4*)(Bbuf + (((size_t)(b*136 + c)) << 16) + (size_t)(j0 + j)*256 + l0 + loff*8) = *(int4*)&t;
    }
  }
  __syncthreads();
  #pragma unroll
  for (int q = 0; q < 2; ++q) {
    int s = q*256 + tid;
    int loff = s & 3, j = (s >> 2) & 15, hh = s >> 6;
    u16x8 t;
    #pragma unroll
    for (int k = 0; k < 8; ++k) {
      int l = loff*8 + k;
      int rec = l*16 + j;
      t[k] = et[rec*8 + hh];
    }
    *(int4*)(Bbuf + (((size_t)(b*136 + 128 + hh)) << 16) + (size_t)(j0 + j)*256 + l0 + loff*8) = *(int4*)&t;
  }
}

// ---------------- K5: batched 256^3 GEMM over 272 channels (tri + denom) ----------------
__global__ __launch_bounds__(256) void k_tri_mfma(
    const unsigned short* __restrict__ Ab, const unsigned short* __restrict__ Bb,
    unsigned short* __restrict__ outT)
{
  __shared__ __align__(16) char lds[34816];
  char* lA = lds;
  char* lB = lds + 10240;
  const int tid = threadIdx.x, lane = tid & 63, w = tid >> 6;
  const int jt = blockIdx.x, it = blockIdx.y, z = blockIdx.z;
  const int b = z / 136, ch = z - b*136;
  const size_t mbase = ((size_t)(b*136 + ch)) << 16;
  const int i0 = it*128, j0 = jt*128;
  const int r4 = tid >> 2, g4 = tid & 3;

  const unsigned short* gA0 = Ab + mbase + (size_t)(i0 + r4)*256 + g4*8;
  const unsigned short* gA1 = gA0 + 64*256;
  const unsigned short* gB0 = Bb + mbase + (size_t)(j0 + r4)*256 + g4*8;
  const unsigned short* gB1 = gB0 + 64*256;
  char* sA0 = lA + r4*80 + g4*16;
  char* sA1 = sA0 + 64*80;
  char* sB0 = lB + r4*80 + g4*16;
  char* sB1 = sB0 + 64*80;

  const int wr = w >> 1, wc = w & 1;
  const char* fA = lA + (wr*64 + (lane & 15))*80 + (lane >> 4)*16;
  const char* fB = lB + (wc*64 + (lane & 15))*80 + (lane >> 4)*16;

  f32x4 acc[4][4];
  #pragma unroll
  for (int rf = 0; rf < 4; ++rf)
    #pragma unroll
    for (int cf = 0; cf < 4; ++cf) acc[rf][cf] = (f32x4){0.f,0.f,0.f,0.f};

  int4 ra0 = *(const int4*)gA0;
  int4 ra1 = *(const int4*)gA1;
  int4 rb0 = *(const int4*)gB0;
  int4 rb1 = *(const int4*)gB1;

  for (int ks = 0; ks < 8; ++ks) {
    __syncthreads();
    *(int4*)sA0 = ra0; *(int4*)sA1 = ra1;
    *(int4*)sB0 = rb0; *(int4*)sB1 = rb1;
    __syncthreads();
    if (ks < 7) {
      const int off = (ks + 1)*32;
      ra0 = *(const int4*)(gA0 + off);
      ra1 = *(const int4*)(gA1 + off);
      rb0 = *(const int4*)(gB0 + off);
      rb1 = *(const int4*)(gB1 + off);
    }
    bf16x8 af[4], bfv[4];
    #pragma unroll
    for (int rf = 0; rf < 4; ++rf) af[rf] = *(const bf16x8*)(fA + rf*16*80);
    #pragma unroll
    for (int cf = 0; cf < 4; ++cf) bfv[cf] = *(const bf16x8*)(fB + cf*16*80);
    #pragma unroll
    for (int rf = 0; rf < 4; ++rf)
      #pragma unroll
      for (int cf = 0; cf < 4; ++cf)
        acc[rf][cf] = __builtin_amdgcn_mfma_f32_16x16x32_bf16(af[rf], bfv[cf], acc[rf][cf], 0, 0, 0);
  }

  __syncthreads();
  #pragma unroll
  for (int rf = 0; rf < 4; ++rf)
    #pragma unroll
    for (int cf = 0; cf < 4; ++cf)
      #pragma unroll
      for (int r = 0; r < 4; ++r) {
        int il = wr*64 + rf*16 + 4*(lane >> 4) + r;
        int jl = wc*64 + cf*16 + (lane & 15);
        *(unsigned short*)(lds + il*272 + jl*2) = f2bf(acc[rf][cf][r]);
      }
  __syncthreads();
  #pragma unroll
  for (int q = 0; q < 8; ++q) {
    int row = q*16 + (tid >> 4), seg = tid & 15;
    int4 v = *(const int4*)(lds + row*272 + seg*16);
    *(int4*)(outT + mbase + (size_t)(i0 + row)*256 + j0 + seg*8) = v;
  }
}

// ---------------- K6: x = t/denom ; y = x@wo^T ; hn = bf16(LN1(h + y)) ----------------
__global__ __launch_bounds__(256) void k_wo_ln_mfma(
    const unsigned short* __restrict__ tT, const unsigned short* __restrict__ wb,
    const float* __restrict__ h,
    const float* __restrict__ g1, const float* __restrict__ bb1,
    unsigned short* __restrict__ hn)
{
  __shared__ __align__(16) char xb[32 * 256];
  __shared__ __align__(16) float stage[32 * 132];
  const int tid = threadIdx.x, lane = tid & 63, w = tid >> 6;
  const size_t pos0 = (size_t)blockIdx.x * 32;
  const int b = (int)(pos0 >> 16);
  const int posl0 = (int)(pos0 & 65535);
  const unsigned short* wbo = wb + 2 * 16384;

  bf16x8 bfr[2][4];
  #pragma unroll
  for (int cf = 0; cf < 2; ++cf)
    #pragma unroll
    for (int ks = 0; ks < 4; ++ks)
      bfr[cf][ks] = wb_frag(wbo, w * 2 + cf, ks, lane);

  #pragma unroll
  for (int it2 = 0; it2 < 2; ++it2) {
    int c = it2*64 + (tid >> 2);
    int poff = (tid & 3)*8;
    u16x8 tv = *(const u16x8*)(tT + (((size_t)(b*136 + c)) << 16) + posl0 + poff);
    u16x8 dv = *(const u16x8*)(tT + (((size_t)(b*136 + 128 + (c >> 4))) << 16) + posl0 + poff);
    int cb = c*2;
    #pragma unroll
    for (int k = 0; k < 8; ++k) {
      float x = bf2f(tv[k]) / (bf2f(dv[k]) + 1e-6f);
      int p = poff + k;
      int byte = p*256 + ((((cb >> 4) ^ (p & 7))) << 4) + (cb & 15);
      *(unsigned short*)(xb + byte) = f2bf(x);
    }
  }
  __syncthreads();

  f32x4 acc[2][2];
  #pragma unroll
  for (int rf = 0; rf < 2; ++rf)
    #pragma unroll
    for (int cf = 0; cf < 2; ++cf) acc[rf][cf] = (f32x4){0.f,0.f,0.f,0.f};

  #pragma unroll
  for (int ks = 0; ks < 4; ++ks) {
    bf16x8 a0 = lds_afrag(xb, 0, ks * 32, lane);
    bf16x8 a1f = lds_afrag(xb, 16, ks * 32, lane);
    #pragma unroll
    for (int cf = 0; cf < 2; ++cf) {
      acc[0][cf] = __builtin_amdgcn_mfma_f32_16x16x32_bf16(a0,  bfr[cf][ks], acc[0][cf], 0, 0, 0);
      acc[1][cf] = __builtin_amdgcn_mfma_f32_16x16x32_bf16(a1f, bfr[cf][ks], acc[1][cf], 0, 0, 0);
    }
  }

  const int lg = lane >> 4, lc = lane & 15;
  #pragma unroll
  for (int rf = 0; rf < 2; ++rf)
    #pragma unroll
    for (int cf = 0; cf < 2; ++cf)
      #pragma unroll
      for (int r = 0; r < 4; ++r)
        stage[(rf*16 + 4*lg + r) * 132 + w*32 + cf*16 + lc] = acc[rf][cf][r];
  __syncthreads();

  const float ga = g1[lane], gb = g1[64 + lane];
  const float ba = bb1[lane], bbv = bb1[64 + lane];
  for (int rr = 0; rr < 8; ++rr) {
    int row = w * 8 + rr;
    float y0 = stage[row * 132 + lane];
    float y1 = stage[row * 132 + 64 + lane];
    float r0 = h[(pos0 + row) * 128 + lane] + y0;
    float r1 = h[(pos0 + row) * 128 + 64 + lane] + y1;
    float s = r0 + r1, sq = r0*r0 + r1*r1;
    #pragma unroll
    for (int m = 1; m < 64; m <<= 1) { s += __shfl_xor(s, m); sq += __shfl_xor(sq, m); }
    float mu = s * (1.f/128.f);
    float var = sq * (1.f/128.f) - mu*mu;
    float rstd = rsqrtf(var + 1e-5f);
    hn[(pos0 + row) * 128 + lane]      = f2bf((r0 - mu) * rstd * ga + ba);
    hn[(pos0 + row) * 128 + 64 + lane] = f2bf((r1 - mu) * rstd * gb + bbv);
  }
}

// ---------------- K7: FFN(silu) + residual + LN2 -> out (64-pos tile, 8 waves) ----------------
__global__ __launch_bounds__(512) void k_ffn_ln_mfma(
    const unsigned short* __restrict__ hnp, const unsigned short* __restrict__ wb,
    const float* __restrict__ bias1, const float* __restrict__ bias2,
    const float* __restrict__ g2, const float* __restrict__ b2v,
    float* __restrict__ out)
{
  __shared__ __align__(16) char xb[64 * 256];       // x then u (bf16 swizzled)
  __shared__ __align__(16) float stage[64 * 132];
  const int tid = threadIdx.x, lane = tid & 63, w = tid >> 6;
  const size_t pos0 = (size_t)blockIdx.x * 64;
  const int rh = w >> 2, cq = w & 3;
  const int R = rh * 32;
  const unsigned short* wb1 = wb + 3 * 16384;
  const unsigned short* wb2 = wb + 4 * 16384;

  bf16x8 bf1[2][4];
  #pragma unroll
  for (int cf = 0; cf < 2; ++cf)
    #pragma unroll
    for (int ks = 0; ks < 4; ++ks)
      bf1[cf][ks] = wb_frag(wb1, cq * 2 + cf, ks, lane);

  #pragma unroll
  for (int q = 0; q < 2; ++q) {
    int s = q*512 + tid;
    int row = s >> 4, g = s & 15;
    int4 v = *(const int4*)(hnp + (pos0 + row)*128 + g*8);
    *(int4*)(xb + row*256 + (((g ^ (row & 7))) << 4)) = v;
  }
  __syncthreads();

  f32x4 acc[2][2];
  #pragma unroll
  for (int rf = 0; rf < 2; ++rf)
    #pragma unroll
    for (int cf = 0; cf < 2; ++cf) acc[rf][cf] = (f32x4){0.f,0.f,0.f,0.f};

  #pragma unroll
  for (int ks = 0; ks < 4; ++ks) {
    bf16x8 a0  = lds_afrag(xb, R,      ks * 32, lane);
    bf16x8 a1f = lds_afrag(xb, R + 16, ks * 32, lane);
    #pragma unroll
    for (int cf = 0; cf < 2; ++cf) {
      acc[0][cf] = __builtin_amdgcn_mfma_f32_16x16x32_bf16(a0,  bf1[cf][ks], acc[0][cf], 0, 0, 0);
      acc[1][cf] = __builtin_amdgcn_mfma_f32_16x16x32_bf16(a1f, bf1[cf][ks], acc[1][cf], 0, 0, 0);
    }
  }
  __syncthreads();

  const int lg = lane >> 4, lc = lane & 15;
  {
    float bc0 = bias1[cq*32 + lc];
    float bc1 = bias1[cq*32 + 16 + lc];
    #pragma unroll
    for (int rf = 0; rf < 2; ++rf)
      #pragma unroll
      for (int cf = 0; cf < 2; ++cf) {
        float bc = cf ? bc1 : bc0;
        #pragma unroll
        for (int r = 0; r < 4; ++r) {
          int row = R + rf*16 + 4*lg + r;
          int col = cq*32 + cf*16 + lc;
          float s = acc[rf][cf][r] + bc;
          float u = s / (1.f + __expf(-s));
          int cbyte = col * 2;
          int byte = row * 256 + ((((cbyte >> 4) ^ (row & 7))) << 4) + (cbyte & 15);
          *(unsigned short*)(xb + byte) = f2bf(u);
        }
      }
  }
  __syncthreads();

  f32x4 acc2[2][2];
  #pragma unroll
  for (int rf = 0; rf < 2; ++rf)
    #pragma unroll
    for (int cf = 0; cf < 2; ++cf) acc2[rf][cf] = (f32x4){0.f,0.f,0.f,0.f};

  #pragma unroll
  for (int ks = 0; ks < 4; ++ks) {
    bf16x8 b0 = wb_frag(wb2, cq * 2,     ks, lane);
    bf16x8 b1 = wb_frag(wb2, cq * 2 + 1, ks, lane);
    bf16x8 a0  = lds_afrag(xb, R,      ks * 32, lane);
    bf16x8 a1f = lds_afrag(xb, R + 16, ks * 32, lane);
    acc2[0][0] = __builtin_amdgcn_mfma_f32_16x16x32_bf16(a0,  b0, acc2[0][0], 0, 0, 0);
    acc2[0][1] = __builtin_amdgcn_mfma_f32_16x16x32_bf16(a0,  b1, acc2[0][1], 0, 0, 0);
    acc2[1][0] = __builtin_amdgcn_mfma_f32_16x16x32_bf16(a1f, b0, acc2[1][0], 0, 0, 0);
    acc2[1][1] = __builtin_amdgcn_mfma_f32_16x16x32_bf16(a1f, b1, acc2[1][1], 0, 0, 0);
  }

  {
    float bc0 = bias2[cq*32 + lc];
    float bc1 = bias2[cq*32 + 16 + lc];
    #pragma unroll
    for (int rf = 0; rf < 2; ++rf)
      #pragma unroll
      for (int cf = 0; cf < 2; ++cf) {
        float bc = cf ? bc1 : bc0;
        #pragma unroll
        for (int r = 0; r < 4; ++r)
          stage[(R + rf*16 + 4*lg + r) * 132 + cq*32 + cf*16 + lc] = acc2[rf][cf][r] + bc;
      }
  }
  __syncthreads();

  const float ga = g2[lane], gb = g2[64 + lane];
  const float ba = b2v[lane], bbv = b2v[64 + lane];
  for (int rr = 0; rr < 8; ++rr) {
    int row = w * 8 + rr;
    float y0 = stage[row * 132 + lane];
    float y1 = stage[row * 132 + 64 + lane];
    float r0 = bf2f(hnp[(pos0 + row) * 128 + lane]) + y0;
    float r1 = bf2f(hnp[(pos0 + row) * 128 + 64 + lane]) + y1;
    float s = r0 + r1, sq = r0*r0 + r1*r1;
    #pragma unroll
    for (int m = 1; m < 64; m <<= 1) { s += __shfl_xor(s, m); sq += __shfl_xor(sq, m); }
    float mu = s * (1.f/128.f);
    float var = sq * (1.f/128.f) - mu*mu;
    float rstd = rsqrtf(var + 1e-5f);
    out[(pos0 + row) * 128 + lane]      = (r0 - mu) * rstd * ga + ba;
    out[(pos0 + row) * 128 + 64 + lane] = (r1 - mu) * rstd * gb + bbv;
  }
}

extern "C" void kernel_launch(void* const* d_in, const int* in_sizes, int n_in,
                              void* d_out, int out_size, void* d_ws, size_t ws_size,
                              hipStream_t stream)
{
  const float* h    = (const float*)d_in[0];
  const void*  mask = d_in[1];
  const float* wa1  = (const float*)d_in[2];
  const float* wa2  = (const float*)d_in[3];
  const float* wv1  = (const float*)d_in[4];
  const float* wv2  = (const float*)d_in[5];
  const float* wo   = (const float*)d_in[6];
  const float* ln1s = (const float*)d_in[7];
  const float* ln1b = (const float*)d_in[8];
  const float* ln2s = (const float*)d_in[9];
  const float* ln2b = (const float*)d_in[10];
  const float* wu1  = (const float*)d_in[11];
  const float* bu1  = (const float*)d_in[12];
  const float* wu2  = (const float*)d_in[13];
  const float* bu2  = (const float*)d_in[14];

  char* ws = (char*)d_ws;
  const size_t MB = 1024*1024;
  unsigned short* vb1   = (unsigned short*)(ws + 0);        // 32 MB
  unsigned short* tbufT = (unsigned short*)(ws + 0);        // 35.7 MB (aliases vb1)
  unsigned short* vb2   = (unsigned short*)(ws + 36*MB);    // 32 MB
  unsigned short* hn    = (unsigned short*)(ws + 36*MB);    // 32 MB (aliases vb2)
  unsigned short* Bbuf  = (unsigned short*)(ws + 68*MB);    // 35.7 MB
  float* a1  = (float*)(ws + 104*MB);                       // 4 MB
  float* a2  = (float*)(ws + 108*MB);                       // 4 MB
  float* e2  = (float*)(ws + 112*MB);                       // 4 MB
  float* am1 = (float*)(ws + 116*MB);
  float* am2 = (float*)(ws + 116*MB + 16384);
  int*   flg = (int*)  (ws + 116*MB + 32768);
  int*   part= (int*)  (ws + 116*MB + 65536);               // 128 ints
  unsigned short* wb = (unsigned short*)(ws + 117*MB);      // 84 KB frag-major weights
  unsigned short* Abuf = (unsigned short*)d_out;            // 35.7 MB in 64 MB out

  k_maskpart<<<128, 256, 0, stream>>>((const unsigned int*)mask, part);
  k_maskred<<<1, 128, 0, stream>>>(part, flg);
  k_wconv<<<6, 256, 0, stream>>>(wv1, wv2, wo, wu1, wu2, wa1, wa2, wb);
  k_proj_mfma<<<2048, 512, 0, stream>>>(h, wb, a1, a2, vb1, vb2);
  k_rowmax1<<<512, 64, 0, stream>>>(a1, am1);
  k_rowmax2<<<512, 64, 0, stream>>>(a2, am2);
  k_e<<<512, 256, 0, stream>>>(mask, flg, a1, a2, am1, am2, e2, Abuf);
  k_prep1<<<1024, 256, 0, stream>>>(vb1, Abuf);
  k_prep2<<<dim3(8,16,2), 256, 0, stream>>>(vb2, e2, Bbuf);
  k_tri_mfma<<<dim3(2,2,272), 256, 0, stream>>>(Abuf, Bbuf, tbufT);
  k_wo_ln_mfma<<<4096, 256, 0, stream>>>(tbufT, wb, h, ln1s, ln1b, hn);
  k_ffn_ln_mfma<<<2048, 512, 0, stream>>>(hn, wb, bu1, bu2, ln2s, ln2b, (float*)d_out);
}

// Round 8
// 192.442 us; speedup vs baseline: 19.8327x; 1.0164x over previous
//
#include <hip/hip_runtime.h>

#define B_ 2
#define N_ 256
#define C_ 128
#define H_ 8

typedef __attribute__((ext_vector_type(8))) short bf16x8;
typedef __attribute__((ext_vector_type(8))) unsigned short u16x8;
typedef __attribute__((ext_vector_type(4))) float f32x4;

__device__ __forceinline__ unsigned short f2bf(float f) {
  unsigned int u = __float_as_uint(f);
  unsigned int r = (u + 0x7FFFu + ((u >> 16) & 1u)) >> 16;
  return (unsigned short)r;
}
__device__ __forceinline__ float bf2f(unsigned short u) {
  return __uint_as_float(((unsigned int)u) << 16);
}

// A-fragment from XOR-swizzled bf16 LDS tile [rows][128 cols] (256 B/row)
__device__ __forceinline__ bf16x8 lds_afrag(const char* base, int row0, int k0, int lane) {
  int row = row0 + (lane & 15);
  int cb = (k0 + 8 * (lane >> 4)) * 2;
  int byte = row * 256 + ((((cb >> 4) ^ (row & 7))) << 4);
  return *(const bf16x8*)(base + byte);
}

__device__ __forceinline__ void lds_store4bf(char* base, int row, int cbyte,
                                             float a, float b, float c, float d) {
  int byte = row * 256 + ((((cbyte >> 4) ^ (row & 7))) << 4) + (cbyte & 15);
  ushort4 o4;
  o4.x = f2bf(a); o4.y = f2bf(b); o4.z = f2bf(c); o4.w = f2bf(d);
  *(ushort4*)(base + byte) = o4;
}

// frag-major weight fetch: wbase -> [cfi][ks][lane][8] bf16
__device__ __forceinline__ bf16x8 wb_frag(const unsigned short* wbase,
                                          int cfi, int ks, int lane) {
  return *(const bf16x8*)(wbase + (((cfi * 4 + ks) * 64) + lane) * 8);
}

// ---------------- K0: mask dtype detection (parallel) ----------------
__global__ __launch_bounds__(256) void k_maskpart(const unsigned int* __restrict__ m4,
                                                  int* __restrict__ part)
{
  __shared__ int red[4];
  const int tid = threadIdx.x;
  unsigned int v = m4[blockIdx.x * 256 + tid];
  int cnt = ((v & 0xFFu) != 0) + (((v >> 8) & 0xFFu) != 0) +
            (((v >> 16) & 0xFFu) != 0) + ((v >> 24) != 0);
  #pragma unroll
  for (int m = 1; m < 64; m <<= 1) cnt += __shfl_xor(cnt, m);
  if ((tid & 63) == 0) red[tid >> 6] = cnt;
  __syncthreads();
  if (tid == 0) part[blockIdx.x] = red[0] + red[1] + red[2] + red[3];
}

__global__ __launch_bounds__(128) void k_maskred(const int* __restrict__ part,
                                                 int* __restrict__ flag)
{
  const int tid = threadIdx.x;
  int v = part[tid];
  #pragma unroll
  for (int m = 1; m < 64; m <<= 1) v += __shfl_xor(v, m);
  __shared__ int red[2];
  if ((tid & 63) == 0) red[tid >> 6] = v;
  __syncthreads();
  if (tid == 0) *flag = ((red[0] + red[1]) > 7864) ? 1 : 0;  // 1 = uint8 layout
}

// ---------------- K0b: weight conversion to fragment-major bf16 ----------------
// wb layout: [0]=wv1 [1]=wv2 [2]=wo [3]=w1 [4]=w2 (16384 each), +5*16384: wa (2048)
__global__ __launch_bounds__(256) void k_wconv(
    const float* __restrict__ wv1, const float* __restrict__ wv2,
    const float* __restrict__ wo, const float* __restrict__ w1,
    const float* __restrict__ w2,
    const float* __restrict__ wa1, const float* __restrict__ wa2,
    unsigned short* __restrict__ wb)
{
  const int m = blockIdx.x;
  const int tid = threadIdx.x;
  const int l = tid & 63;
  if (m < 5) {
    const float* W = (m == 0) ? wv1 : (m == 1) ? wv2 : (m == 2) ? wo : (m == 3) ? w1 : w2;
    unsigned short* o = wb + m * 16384;
    const int sub = tid >> 6;
    #pragma unroll
    for (int q = 0; q < 8; ++q) {
      int f = q * 4 + sub;              // fragment 0..31 (cf = f>>2, ks = f&3)
      int cf = f >> 2, ks = f & 3;
      int row = cf * 16 + (l & 15);
      int k = ks * 32 + 8 * (l >> 4);
      const float* p = W + row * 128 + k;
      float4 x = *(const float4*)p, y = *(const float4*)(p + 4);
      u16x8 t;
      t[0] = f2bf(x.x); t[1] = f2bf(x.y); t[2] = f2bf(x.z); t[3] = f2bf(x.w);
      t[4] = f2bf(y.x); t[5] = f2bf(y.y); t[6] = f2bf(y.z); t[7] = f2bf(y.w);
      *(u16x8*)(o + (f * 64 + l) * 8) = t;
    }
  } else {
    unsigned short* o = wb + 5 * 16384;
    const int ks = tid >> 6;
    int r = l & 15;
    const float* ar = (r < 8) ? (wa1 + r * 128) : (wa2 + (r - 8) * 128);
    const float* p = ar + ks * 32 + 8 * (l >> 4);
    float4 x = *(const float4*)p, y = *(const float4*)(p + 4);
    u16x8 t;
    t[0] = f2bf(x.x); t[1] = f2bf(x.y); t[2] = f2bf(x.z); t[3] = f2bf(x.w);
    t[4] = f2bf(y.x); t[5] = f2bf(y.y); t[6] = f2bf(y.z); t[7] = f2bf(y.w);
    *(u16x8*)(o + (ks * 64 + l) * 8) = t;
  }
}

// ---------------- K1: fused projections via MFMA, 64-pos tile, 8 waves ----------------
__global__ __launch_bounds__(512) void k_proj_mfma(
    const float* __restrict__ h, const unsigned short* __restrict__ wb,
    float* __restrict__ a1, float* __restrict__ a2,
    unsigned short* __restrict__ v1, unsigned short* __restrict__ v2)
{
  __shared__ __align__(16) char lds[16384 + 17408];
  char* hb  = lds;                 // bf16 swizzled h tile [64][256B]
  char* st1 = lds + 16384;         // v1 stage [32][272B]
  char* st2 = lds + 16384 + 8704;  // v2 stage [32][272B]
  const int tid = threadIdx.x, lane = tid & 63, w = tid >> 6;
  const size_t pos0 = (size_t)blockIdx.x * 64;

  const unsigned short* wbv = wb + ((w < 4) ? 0 : 16384);
  const unsigned short* wba = wb + 5 * 16384;
  const int colbase = (w & 3) * 32;
  bf16x8 bfr[2][4];
  #pragma unroll
  for (int cf = 0; cf < 2; ++cf)
    #pragma unroll
    for (int ks = 0; ks < 4; ++ks)
      bfr[cf][ks] = wb_frag(wbv, (w & 3) * 2 + cf, ks, lane);

  bf16x8 af[4];
  if (w == 0) {
    #pragma unroll
    for (int ks = 0; ks < 4; ++ks)
      af[ks] = *(const bf16x8*)(wba + (ks * 64 + lane) * 8);
  }

  {
    const float4* hg4 = (const float4*)(h + pos0 * 128);
    #pragma unroll
    for (int q = 0; q < 4; ++q) {
      int f4i = q * 512 + tid;
      float4 x = hg4[f4i];
      lds_store4bf(hb, f4i >> 5, (f4i & 31) * 8, x.x, x.y, x.z, x.w);
    }
  }
  __syncthreads();

  const int lg = lane >> 4, lc = lane & 15;
  for (int p = 0; p < 2; ++p) {
    const int R = p * 32;
    f32x4 acc[2][2];
    #pragma unroll
    for (int rf = 0; rf < 2; ++rf)
      #pragma unroll
      for (int cf = 0; cf < 2; ++cf) acc[rf][cf] = (f32x4){0.f,0.f,0.f,0.f};
    f32x4 acca[2]; acca[0] = (f32x4){0.f,0.f,0.f,0.f}; acca[1] = acca[0];

    #pragma unroll
    for (int ks = 0; ks < 4; ++ks) {
      bf16x8 a0  = lds_afrag(hb, R,      ks * 32, lane);
      bf16x8 a1f = lds_afrag(hb, R + 16, ks * 32, lane);
      #pragma unroll
      for (int cf = 0; cf < 2; ++cf) {
        acc[0][cf] = __builtin_amdgcn_mfma_f32_16x16x32_bf16(a0,  bfr[cf][ks], acc[0][cf], 0, 0, 0);
        acc[1][cf] = __builtin_amdgcn_mfma_f32_16x16x32_bf16(a1f, bfr[cf][ks], acc[1][cf], 0, 0, 0);
      }
      if (w == 0) {
        acca[0] = __builtin_amdgcn_mfma_f32_16x16x32_bf16(a0,  af[ks], acca[0], 0, 0, 0);
        acca[1] = __builtin_amdgcn_mfma_f32_16x16x32_bf16(a1f, af[ks], acca[1], 0, 0, 0);
      }
    }

    if (p) __syncthreads();
    {
      char* st = (w < 4) ? st1 : st2;
      #pragma unroll
      for (int rf = 0; rf < 2; ++rf)
        #pragma unroll
        for (int cf = 0; cf < 2; ++cf)
          #pragma unroll
          for (int r = 0; r < 4; ++r) {
            int row = rf*16 + 4*lg + r;
            int col = colbase + cf*16 + lc;
            *(unsigned short*)(st + row*272 + col*2) = f2bf(acc[rf][cf][r]);
          }
    }
    if (w == 0) {
      #pragma unroll
      for (int rf = 0; rf < 2; ++rf)
        #pragma unroll
        for (int r = 0; r < 4; ++r) {
          size_t row = pos0 + R + rf*16 + 4*lg + r;
          float val = acca[rf][r];
          if (lc < 8) a1[row * 8 + lc] = val;
          else        a2[row * 8 + (lc - 8)] = val;
        }
    }
    __syncthreads();
    #pragma unroll
    for (int q = 0; q < 2; ++q) {
      int s = q * 512 + tid;
      int bsel = s >> 9, idx = s & 511;
      int row = idx >> 4, seg = idx & 15;
      int4 v = *(const int4*)((bsel ? st2 : st1) + row*272 + seg*16);
      unsigned short* dst = bsel ? v2 : v1;
      *(int4*)(dst + (pos0 + R + row)*128 + seg*8) = v;
    }
  }
}

// ---------------- K2a/K2b: row maxes ----------------
__global__ __launch_bounds__(64) void k_rowmax1(const float* __restrict__ a1,
                                                float* __restrict__ amax1)
{
  const int bi = blockIdx.x;
  const int t = threadIdx.x;
  const float* base = a1 + (size_t)bi * N_ * 8;
  float m = -1e30f;
  #pragma unroll 8
  for (int k = 0; k < 32; ++k) m = fmaxf(m, base[t + 64*k]);
  m = fmaxf(m, __shfl_xor(m, 8));
  m = fmaxf(m, __shfl_xor(m, 16));
  m = fmaxf(m, __shfl_xor(m, 32));
  if (t < 8) amax1[bi*8 + t] = m;
}

__global__ __launch_bounds__(64) void k_rowmax2(const float* __restrict__ a2,
                                                float* __restrict__ amax2)
{
  const int bj = blockIdx.x;
  const int b = bj >> 8, j = bj & 255;
  const int t = threadIdx.x;
  const int hh = t & 7, igrp = t >> 3;
  float m = -1e30f;
  for (int k = 0; k < 32; ++k) {
    int i = igrp + 8*k;
    m = fmaxf(m, a2[((size_t)(b*N_ + i)*N_ + j)*8 + hh]);
  }
  m = fmaxf(m, __shfl_xor(m, 8));
  m = fmaxf(m, __shfl_xor(m, 16));
  m = fmaxf(m, __shfl_xor(m, 32));
  if (t < 8) amax2[bj*8 + t] = m;
}

// ---------------- K3: exp (masked); e2 f32 natural; eb1 bf16 -> Abuf ch128+ ----------------
__global__ __launch_bounds__(256) void k_e(
    const void* __restrict__ maskraw, const int* __restrict__ modep,
    const float* __restrict__ a1, const float* __restrict__ a2,
    const float* __restrict__ am1, const float* __restrict__ am2,
    float* __restrict__ e2out, unsigned short* __restrict__ Abuf)
{
  __shared__ unsigned short eb[8 * 256];   // [h][p] bf16
  const int tid = threadIdx.x;
  const size_t pos0 = (size_t)blockIdx.x * 256;
  const size_t p = pos0 + tid;
  const int b = (int)(p >> 16), ij = (int)(p & 65535);
  const int i = ij >> 8, j = ij & 255;
  const int msk = modep[0] ? (int)((const unsigned char*)maskraw)[p]
                           : ((const int*)maskraw)[p];
  float4 x0 = *(const float4*)(a1 + p*8);
  float4 x1 = *(const float4*)(a1 + p*8 + 4);
  float4 m0 = *(const float4*)(am1 + ((size_t)(b*256 + i))*8);
  float4 m1 = *(const float4*)(am1 + ((size_t)(b*256 + i))*8 + 4);
  eb[0*256 + tid] = msk ? 0 : f2bf(__expf(x0.x - m0.x));
  eb[1*256 + tid] = msk ? 0 : f2bf(__expf(x0.y - m0.y));
  eb[2*256 + tid] = msk ? 0 : f2bf(__expf(x0.z - m0.z));
  eb[3*256 + tid] = msk ? 0 : f2bf(__expf(x0.w - m0.w));
  eb[4*256 + tid] = msk ? 0 : f2bf(__expf(x1.x - m1.x));
  eb[5*256 + tid] = msk ? 0 : f2bf(__expf(x1.y - m1.y));
  eb[6*256 + tid] = msk ? 0 : f2bf(__expf(x1.z - m1.z));
  eb[7*256 + tid] = msk ? 0 : f2bf(__expf(x1.w - m1.w));

  float4 y0 = *(const float4*)(a2 + p*8);
  float4 y1 = *(const float4*)(a2 + p*8 + 4);
  float4 n0 = *(const float4*)(am2 + ((size_t)(b*256 + j))*8);
  float4 n1 = *(const float4*)(am2 + ((size_t)(b*256 + j))*8 + 4);
  float4 o0, o1;
  o0.x = msk ? 0.f : __expf(y0.x - n0.x);
  o0.y = msk ? 0.f : __expf(y0.y - n0.y);
  o0.z = msk ? 0.f : __expf(y0.z - n0.z);
  o0.w = msk ? 0.f : __expf(y0.w - n0.w);
  o1.x = msk ? 0.f : __expf(y1.x - n1.x);
  o1.y = msk ? 0.f : __expf(y1.y - n1.y);
  o1.z = msk ? 0.f : __expf(y1.z - n1.z);
  o1.w = msk ? 0.f : __expf(y1.w - n1.w);
  *(float4*)(e2out + p*8) = o0;
  *(float4*)(e2out + p*8 + 4) = o1;

  __syncthreads();
  {
    int hh = tid >> 5, seg = tid & 31;
    int4 v = *(const int4*)((const char*)eb + hh*512 + seg*16);
    *(int4*)(Abuf + (((size_t)(b*136 + 128 + hh)) << 16) + (int)(pos0 & 65535) + seg*8) = v;
  }
}

// ---------------- K4a: pc1[c][i][l] = vb1[pos][c] * e1 (channel transpose) ----------------
__global__ __launch_bounds__(256) void k_prep1(
    const unsigned short* __restrict__ vb1, unsigned short* __restrict__ Abuf)
{
  __shared__ __align__(16) char lds[36864];  // xt [128][272B] + et [8][256B]
  char* xt = lds;
  unsigned short* et = (unsigned short*)(lds + 34816);
  const int tid = threadIdx.x;
  const size_t pos0 = (size_t)blockIdx.x * 128;
  const int b = (int)(pos0 >> 16);
  const int posl0 = (int)(pos0 & 65535);

  if (tid < 128) {
    int hh = tid >> 4, seg = tid & 15;
    int4 v = *(const int4*)(Abuf + (((size_t)(b*136 + 128 + hh)) << 16) + posl0 + seg*8);
    *(int4*)((char*)et + hh*256 + seg*16) = v;
  }
  #pragma unroll
  for (int q = 0; q < 8; ++q) {
    int s = q*256 + tid;
    int rec = s >> 4, g = s & 15;
    int4 v = *(const int4*)(vb1 + (pos0 + rec)*128 + g*8);
    *(int4*)(xt + rec*272 + g*16) = v;
  }
  __syncthreads();
  #pragma unroll
  for (int q = 0; q < 8; ++q) {
    int c = q*16 + (tid & 15);
    int pg = tid >> 4;
    int hh = c >> 4;
    u16x8 t;
    #pragma unroll
    for (int k = 0; k < 8; ++k) {
      int p = pg*8 + k;
      float xv = bf2f(*(const unsigned short*)(xt + p*272 + c*2));
      float ev = bf2f(et[hh*128 + p]);
      t[k] = f2bf(xv * ev);
    }
    *(int4*)(Abuf + (((size_t)(b*136 + c)) << 16) + posl0 + pg*8) = *(int4*)&t;
  }
}

// ---------------- K4b: pc2t[c][j][l] = vb2[(l,j)][c]*e2 ; eb2t[h][j][l] ----------------
__global__ __launch_bounds__(256) void k_prep2(
    const unsigned short* __restrict__ vb2, const float* __restrict__ e2,
    unsigned short* __restrict__ Bbuf)
{
  __shared__ __align__(16) char lds[49152];  // vt [512][80B] + et [512][16B]
  char* vt = lds;
  unsigned short* et = (unsigned short*)(lds + 40960);  // [rec][8 h] bf16
  const int tid = threadIdx.x;
  const int lt = blockIdx.x, jt = blockIdx.y, b = blockIdx.z;
  const int l0 = lt*32, j0 = jt*16;

  #pragma unroll
  for (int q = 0; q < 4; ++q) {
    int s = q*256 + tid;
    int rec = s >> 1, hf = (s & 1)*4;
    int l = rec >> 4, j = rec & 15;
    size_t pos = ((size_t)b << 16) + (size_t)(l0 + l)*256 + (j0 + j);
    float4 ev = *(const float4*)(e2 + pos*8 + hf);
    ushort4 o; o.x = f2bf(ev.x); o.y = f2bf(ev.y); o.z = f2bf(ev.z); o.w = f2bf(ev.w);
    *(ushort4*)(et + rec*8 + hf) = o;
  }

  for (int cw = 0; cw < 4; ++cw) {
    __syncthreads();
    #pragma unroll
    for (int q = 0; q < 8; ++q) {
      int s = q*256 + tid;
      int rec = s >> 2, g = s & 3;
      int l = rec >> 4, j = rec & 15;
      size_t pos = ((size_t)b << 16) + (size_t)(l0 + l)*256 + (j0 + j);
      int4 v = *(const int4*)(vb2 + pos*128 + cw*32 + g*8);
      *(int4*)(vt + rec*80 + g*16) = v;
    }
    __syncthreads();
    #pragma unroll
    for (int q = 0; q < 8; ++q) {
      int loff = tid & 3, j = (tid >> 2) & 15, cs = tid >> 6;
      int cl = q*4 + cs;
      int c = cw*32 + cl;
      int hh = c >> 4;
      u16x8 t;
      #pragma unroll
      for (int k = 0; k < 8; ++k) {
        int l = loff*8 + k;
        int rec = l*16 + j;
        float xv = bf2f(*(const unsigned short*)(vt + rec*80 + cl*2));
        float ev = bf2f(et[rec*8 + hh]);
        t[k] = f2bf(xv * ev);
      }
      *(int4*)(Bbuf + (((size_t)(b*136 + c)) << 16) + (size_t)(j0 + j)*256 + l0 + loff*8) = *(int4*)&t;
    }
  }
  __syncthreads();
  #pragma unroll
  for (int q = 0; q < 2; ++q) {
    int s = q*256 + tid;
    int loff = s & 3, j = (s >> 2) & 15, hh = s >> 6;
    u16x8 t;
    #pragma unroll
    for (int k = 0; k < 8; ++k) {
      int l = loff*8 + k;
      int rec = l*16 + j;
      t[k] = et[rec*8 + hh];
    }
    *(int4*)(Bbuf + (((size_t)(b*136 + 128 + hh)) << 16) + (size_t)(j0 + j)*256 + l0 + loff*8) = *(int4*)&t;
  }
}

// ---------------- K5: batched 256^3 GEMM over 272 channels (tri + denom) ----------------
__global__ __launch_bounds__(256) void k_tri_mfma(
    const unsigned short* __restrict__ Ab, const unsigned short* __restrict__ Bb,
    unsigned short* __restrict__ outT)
{
  __shared__ __align__(16) char lds[34816];
  char* lA = lds;
  char* lB = lds + 10240;
  const int tid = threadIdx.x, lane = tid & 63, w = tid >> 6;
  const int jt = blockIdx.x, it = blockIdx.y, z = blockIdx.z;
  const int b = z / 136, ch = z - b*136;
  const size_t mbase = ((size_t)(b*136 + ch)) << 16;
  const int i0 = it*128, j0 = jt*128;
  const int r4 = tid >> 2, g4 = tid & 3;

  const unsigned short* gA0 = Ab + mbase + (size_t)(i0 + r4)*256 + g4*8;
  const unsigned short* gA1 = gA0 + 64*256;
  const unsigned short* gB0 = Bb + mbase + (size_t)(j0 + r4)*256 + g4*8;
  const unsigned short* gB1 = gB0 + 64*256;
  char* sA0 = lA + r4*80 + g4*16;
  char* sA1 = sA0 + 64*80;
  char* sB0 = lB + r4*80 + g4*16;
  char* sB1 = sB0 + 64*80;

  const int wr = w >> 1, wc = w & 1;
  const char* fA = lA + (wr*64 + (lane & 15))*80 + (lane >> 4)*16;
  const char* fB = lB + (wc*64 + (lane & 15))*80 + (lane >> 4)*16;

  f32x4 acc[4][4];
  #pragma unroll
  for (int rf = 0; rf < 4; ++rf)
    #pragma unroll
    for (int cf = 0; cf < 4; ++cf) acc[rf][cf] = (f32x4){0.f,0.f,0.f,0.f};

  int4 ra0 = *(const int4*)gA0;
  int4 ra1 = *(const int4*)gA1;
  int4 rb0 = *(const int4*)gB0;
  int4 rb1 = *(const int4*)gB1;

  for (int ks = 0; ks < 8; ++ks) {
    __syncthreads();
    *(int4*)sA0 = ra0; *(int4*)sA1 = ra1;
    *(int4*)sB0 = rb0; *(int4*)sB1 = rb1;
    __syncthreads();
    if (ks < 7) {
      const int off = (ks + 1)*32;
      ra0 = *(const int4*)(gA0 + off);
      ra1 = *(const int4*)(gA1 + off);
      rb0 = *(const int4*)(gB0 + off);
      rb1 = *(const int4*)(gB1 + off);
    }
    bf16x8 af[4], bfv[4];
    #pragma unroll
    for (int rf = 0; rf < 4; ++rf) af[rf] = *(const bf16x8*)(fA + rf*16*80);
    #pragma unroll
    for (int cf = 0; cf < 4; ++cf) bfv[cf] = *(const bf16x8*)(fB + cf*16*80);
    #pragma unroll
    for (int rf = 0; rf < 4; ++rf)
      #pragma unroll
      for (int cf = 0; cf < 4; ++cf)
        acc[rf][cf] = __builtin_amdgcn_mfma_f32_16x16x32_bf16(af[rf], bfv[cf], acc[rf][cf], 0, 0, 0);
  }

  __syncthreads();
  #pragma unroll
  for (int rf = 0; rf < 4; ++rf)
    #pragma unroll
    for (int cf = 0; cf < 4; ++cf)
      #pragma unroll
      for (int r = 0; r < 4; ++r) {
        int il = wr*64 + rf*16 + 4*(lane >> 4) + r;
        int jl = wc*64 + cf*16 + (lane & 15);
        *(unsigned short*)(lds + il*272 + jl*2) = f2bf(acc[rf][cf][r]);
      }
  __syncthreads();
  #pragma unroll
  for (int q = 0; q < 8; ++q) {
    int row = q*16 + (tid >> 4), seg = tid & 15;
    int4 v = *(const int4*)(lds + row*272 + seg*16);
    *(int4*)(outT + mbase + (size_t)(i0 + row)*256 + j0 + seg*8) = v;
  }
}

// ---------------- K6: fused tail (de-risked): x=t/dn ; y1=x@wo^T ; hn=LN1(h+y1) ;
//                  u=silu(hn@w1^T+b1) ; y2=u@w2^T+b2 ; out=LN2(hn+y2) ----------------
__global__ __launch_bounds__(512) void k_tail_mfma(
    const unsigned short* __restrict__ tT, const unsigned short* __restrict__ wb,
    const float* __restrict__ h,
    const float* __restrict__ g1, const float* __restrict__ bb1,
    const float* __restrict__ bias1, const float* __restrict__ bias2,
    const float* __restrict__ g2, const float* __restrict__ b2v,
    float* __restrict__ out)
{
  __shared__ __align__(16) char xb[64 * 256];          // bf16 swizzled x / hn / u
  __shared__ __align__(16) float stage[64 * 132];      // f32 GEMM outputs
  __shared__ __align__(16) unsigned short hnb[64 * 128]; // linear bf16 hn (LN2 residual)
  const int tid = threadIdx.x, lane = tid & 63, w = tid >> 6;
  const size_t pos0 = (size_t)blockIdx.x * 64;
  const int b = (int)(pos0 >> 16);
  const int posl0 = (int)(pos0 & 65535);
  const int rh = w >> 2, cq = w & 3;
  const int R = rh * 32;
  const int lg = lane >> 4, lc = lane & 15;
  const int g8 = lane >> 3, l8 = lane & 7;
  const int lrow = w * 8 + g8;                    // LN row owned by this lane group

  // ---- stage-in: x = t/denom -> xb ----
  #pragma unroll
  for (int it2 = 0; it2 < 2; ++it2) {
    int c = it2*64 + (tid >> 3);
    int poff = (tid & 7)*8;
    u16x8 tv = *(const u16x8*)(tT + (((size_t)(b*136 + c)) << 16) + posl0 + poff);
    u16x8 dv = *(const u16x8*)(tT + (((size_t)(b*136 + 128 + (c >> 4))) << 16) + posl0 + poff);
    int cb = c*2;
    #pragma unroll
    for (int k = 0; k < 8; ++k) {
      float x = bf2f(tv[k]) / (bf2f(dv[k]) + 1e-6f);
      int p = poff + k;
      int byte = p*256 + ((((cb >> 4) ^ (p & 7))) << 4) + (cb & 15);
      *(unsigned short*)(xb + byte) = f2bf(x);
    }
  }
  __syncthreads();

  // ---- GEMM1: y1 = x @ wo^T -> stage ----
  {
    const unsigned short* wbo = wb + 2 * 16384;
    f32x4 acc[2][2];
    #pragma unroll
    for (int rf = 0; rf < 2; ++rf)
      #pragma unroll
      for (int cf = 0; cf < 2; ++cf) acc[rf][cf] = (f32x4){0.f,0.f,0.f,0.f};
    #pragma unroll
    for (int ks = 0; ks < 4; ++ks) {
      bf16x8 a0  = lds_afrag(xb, R,      ks * 32, lane);
      bf16x8 a1f = lds_afrag(xb, R + 16, ks * 32, lane);
      #pragma unroll
      for (int cf = 0; cf < 2; ++cf) {
        bf16x8 bf = wb_frag(wbo, cq * 2 + cf, ks, lane);
        acc[0][cf] = __builtin_amdgcn_mfma_f32_16x16x32_bf16(a0,  bf, acc[0][cf], 0, 0, 0);
        acc[1][cf] = __builtin_amdgcn_mfma_f32_16x16x32_bf16(a1f, bf, acc[1][cf], 0, 0, 0);
      }
    }
    #pragma unroll
    for (int rf = 0; rf < 2; ++rf)
      #pragma unroll
      for (int cf = 0; cf < 2; ++cf)
        #pragma unroll
        for (int r = 0; r < 4; ++r)
          stage[(R + rf*16 + 4*lg + r) * 132 + cq*32 + cf*16 + lc] = acc[rf][cf][r];
  }
  __syncthreads();

  // ---- LN1: hn = LN(h + y1) -> xb (swizzled, proven scalar-store path) + hnb (linear) ----
  {
    float rv[16];
    float s = 0.f, sq = 0.f;
    #pragma unroll
    for (int q = 0; q < 4; ++q) {
      float4 y = *(const float4*)&stage[lrow*132 + l8*16 + q*4];
      float4 hv = *(const float4*)&h[(pos0 + lrow)*128 + l8*16 + q*4];
      float r0 = hv.x + y.x, r1 = hv.y + y.y, r2 = hv.z + y.z, r3 = hv.w + y.w;
      rv[q*4+0] = r0; rv[q*4+1] = r1; rv[q*4+2] = r2; rv[q*4+3] = r3;
      s += r0 + r1 + r2 + r3;
      sq += r0*r0 + r1*r1 + r2*r2 + r3*r3;
    }
    #pragma unroll
    for (int m = 1; m < 8; m <<= 1) { s += __shfl_xor(s, m); sq += __shfl_xor(sq, m); }
    float mu = s * (1.f/128.f);
    float var = sq * (1.f/128.f) - mu*mu;
    float rstd = rsqrtf(var + 1e-5f);
    #pragma unroll
    for (int k = 0; k < 16; ++k) {
      int col = l8*16 + k;
      float hnv = (rv[k] - mu)*rstd*g1[col] + bb1[col];
      unsigned short hb16 = f2bf(hnv);
      int cbyte = col * 2;
      int byte = lrow*256 + ((((cbyte >> 4) ^ (lrow & 7))) << 4) + (cbyte & 15);
      *(unsigned short*)(xb + byte) = hb16;
      hnb[lrow*128 + col] = hb16;
    }
  }
  __syncthreads();

  // ---- GEMM2: u = silu(hn @ w1^T + b1) ----
  f32x4 acc[2][2];
  {
    const unsigned short* wb1 = wb + 3 * 16384;
    #pragma unroll
    for (int rf = 0; rf < 2; ++rf)
      #pragma unroll
      for (int cf = 0; cf < 2; ++cf) acc[rf][cf] = (f32x4){0.f,0.f,0.f,0.f};
    #pragma unroll
    for (int ks = 0; ks < 4; ++ks) {
      bf16x8 a0  = lds_afrag(xb, R,      ks * 32, lane);
      bf16x8 a1f = lds_afrag(xb, R + 16, ks * 32, lane);
      #pragma unroll
      for (int cf = 0; cf < 2; ++cf) {
        bf16x8 bf = wb_frag(wb1, cq * 2 + cf, ks, lane);
        acc[0][cf] = __builtin_amdgcn_mfma_f32_16x16x32_bf16(a0,  bf, acc[0][cf], 0, 0, 0);
        acc[1][cf] = __builtin_amdgcn_mfma_f32_16x16x32_bf16(a1f, bf, acc[1][cf], 0, 0, 0);
      }
    }
  }
  __syncthreads();   // all hn reads done before u overwrite

  {
    float bc0 = bias1[cq*32 + lc];
    float bc1 = bias1[cq*32 + 16 + lc];
    #pragma unroll
    for (int rf = 0; rf < 2; ++rf)
      #pragma unroll
      for (int cf = 0; cf < 2; ++cf) {
        float bc = cf ? bc1 : bc0;
        #pragma unroll
        for (int r = 0; r < 4; ++r) {
          int row = R + rf*16 + 4*lg + r;
          int col = cq*32 + cf*16 + lc;
          float s = acc[rf][cf][r] + bc;
          float u = s / (1.f + __expf(-s));
          int cbyte = col * 2;
          int byte = row * 256 + ((((cbyte >> 4) ^ (row & 7))) << 4) + (cbyte & 15);
          *(unsigned short*)(xb + byte) = f2bf(u);
        }
      }
  }
  __syncthreads();

  // ---- GEMM3: y2 = u @ w2^T + b2 -> stage ----
  {
    const unsigned short* wb2 = wb + 4 * 16384;
    f32x4 acc2[2][2];
    #pragma unroll
    for (int rf = 0; rf < 2; ++rf)
      #pragma unroll
      for (int cf = 0; cf < 2; ++cf) acc2[rf][cf] = (f32x4){0.f,0.f,0.f,0.f};
    #pragma unroll
    for (int ks = 0; ks < 4; ++ks) {
      bf16x8 b0 = wb_frag(wb2, cq * 2,     ks, lane);
      bf16x8 b1 = wb_frag(wb2, cq * 2 + 1, ks, lane);
      bf16x8 a0  = lds_afrag(xb, R,      ks * 32, lane);
      bf16x8 a1f = lds_afrag(xb, R + 16, ks * 32, lane);
      acc2[0][0] = __builtin_amdgcn_mfma_f32_16x16x32_bf16(a0,  b0, acc2[0][0], 0, 0, 0);
      acc2[0][1] = __builtin_amdgcn_mfma_f32_16x16x32_bf16(a0,  b1, acc2[0][1], 0, 0, 0);
      acc2[1][0] = __builtin_amdgcn_mfma_f32_16x16x32_bf16(a1f, b0, acc2[1][0], 0, 0, 0);
      acc2[1][1] = __builtin_amdgcn_mfma_f32_16x16x32_bf16(a1f, b1, acc2[1][1], 0, 0, 0);
    }
    float bc0 = bias2[cq*32 + lc];
    float bc1 = bias2[cq*32 + 16 + lc];
    #pragma unroll
    for (int rf = 0; rf < 2; ++rf)
      #pragma unroll
      for (int cf = 0; cf < 2; ++cf) {
        float bc = cf ? bc1 : bc0;
        #pragma unroll
        for (int r = 0; r < 4; ++r)
          stage[(R + rf*16 + 4*lg + r) * 132 + cq*32 + cf*16 + lc] = acc2[rf][cf][r] + bc;
      }
  }
  __syncthreads();

  // ---- LN2: out = LN(hn + y2), hn from linear hnb ----
  {
    float rv[16];
    float s = 0.f, sq = 0.f;
    #pragma unroll
    for (int q = 0; q < 4; ++q) {
      float4 y = *(const float4*)&stage[lrow*132 + l8*16 + q*4];
      int cb = l8*16 + q*4;
      float h0 = bf2f(hnb[lrow*128 + cb + 0]);
      float h1 = bf2f(hnb[lrow*128 + cb + 1]);
      float h2 = bf2f(hnb[lrow*128 + cb + 2]);
      float h3 = bf2f(hnb[lrow*128 + cb + 3]);
      float r0 = h0 + y.x, r1 = h1 + y.y, r2 = h2 + y.z, r3 = h3 + y.w;
      rv[q*4+0] = r0; rv[q*4+1] = r1; rv[q*4+2] = r2; rv[q*4+3] = r3;
      s += r0 + r1 + r2 + r3;
      sq += r0*r0 + r1*r1 + r2*r2 + r3*r3;
    }
    #pragma unroll
    for (int m = 1; m < 8; m <<= 1) { s += __shfl_xor(s, m); sq += __shfl_xor(sq, m); }
    float mu = s * (1.f/128.f);
    float var = sq * (1.f/128.f) - mu*mu;
    float rstd = rsqrtf(var + 1e-5f);
    #pragma unroll
    for (int q = 0; q < 4; ++q) {
      float4 gv = *(const float4*)&g2[l8*16 + q*4];
      float4 bv = *(const float4*)&b2v[l8*16 + q*4];
      float4 ov;
      ov.x = (rv[q*4+0] - mu)*rstd*gv.x + bv.x;
      ov.y = (rv[q*4+1] - mu)*rstd*gv.y + bv.y;
      ov.z = (rv[q*4+2] - mu)*rstd*gv.z + bv.z;
      ov.w = (rv[q*4+3] - mu)*rstd*gv.w + bv.w;
      *(float4*)(out + (pos0 + lrow)*128 + l8*16 + q*4) = ov;
    }
  }
}

extern "C" void kernel_launch(void* const* d_in, const int* in_sizes, int n_in,
                              void* d_out, int out_size, void* d_ws, size_t ws_size,
                              hipStream_t stream)
{
  const float* h    = (const float*)d_in[0];
  const void*  mask = d_in[1];
  const float* wa1  = (const float*)d_in[2];
  const float* wa2  = (const float*)d_in[3];
  const float* wv1  = (const float*)d_in[4];
  const float* wv2  = (const float*)d_in[5];
  const float* wo   = (const float*)d_in[6];
  const float* ln1s = (const float*)d_in[7];
  const float* ln1b = (const float*)d_in[8];
  const float* ln2s = (const float*)d_in[9];
  const float* ln2b = (const float*)d_in[10];
  const float* wu1  = (const float*)d_in[11];
  const float* bu1  = (const float*)d_in[12];
  const float* wu2  = (const float*)d_in[13];
  const float* bu2  = (const float*)d_in[14];

  char* ws = (char*)d_ws;
  const size_t MB = 1024*1024;
  unsigned short* vb1   = (unsigned short*)(ws + 0);        // 32 MB
  unsigned short* tbufT = (unsigned short*)(ws + 0);        // 35.7 MB (aliases vb1)
  unsigned short* vb2   = (unsigned short*)(ws + 36*MB);    // 32 MB
  unsigned short* Bbuf  = (unsigned short*)(ws + 68*MB);    // 35.7 MB
  float* a1  = (float*)(ws + 104*MB);                       // 4 MB
  float* a2  = (float*)(ws + 108*MB);                       // 4 MB
  float* e2  = (float*)(ws + 112*MB);                       // 4 MB
  float* am1 = (float*)(ws + 116*MB);
  float* am2 = (float*)(ws + 116*MB + 16384);
  int*   flg = (int*)  (ws + 116*MB + 32768);
  int*   part= (int*)  (ws + 116*MB + 65536);               // 128 ints
  unsigned short* wb = (unsigned short*)(ws + 117*MB);      // 84 KB frag-major weights
  unsigned short* Abuf = (unsigned short*)d_out;            // 35.7 MB in 64 MB out

  k_maskpart<<<128, 256, 0, stream>>>((const unsigned int*)mask, part);
  k_maskred<<<1, 128, 0, stream>>>(part, flg);
  k_wconv<<<6, 256, 0, stream>>>(wv1, wv2, wo, wu1, wu2, wa1, wa2, wb);
  k_proj_mfma<<<2048, 512, 0, stream>>>(h, wb, a1, a2, vb1, vb2);
  k_rowmax1<<<512, 64, 0, stream>>>(a1, am1);
  k_rowmax2<<<512, 64, 0, stream>>>(a2, am2);
  k_e<<<512, 256, 0, stream>>>(mask, flg, a1, a2, am1, am2, e2, Abuf);
  k_prep1<<<1024, 256, 0, stream>>>(vb1, Abuf);
  k_prep2<<<dim3(8,16,2), 256, 0, stream>>>(vb2, e2, Bbuf);
  k_tri_mfma<<<dim3(2,2,272), 256, 0, stream>>>(Abuf, Bbuf, tbufT);
  k_tail_mfma<<<2048, 512, 0, stream>>>(tbufT, wb, h, ln1s, ln1b, bu1, bu2, ln2s, ln2b, (float*)d_out);
}